// Round 1
// baseline (730.388 us; speedup 1.0000x reference)
//
#include <hip/hip_runtime.h>
#include <hip/hip_bf16.h>

// Problem constants
#define NB 8
#define LL 1024        // H*W tokens per batch
#define CIN 512
#define DIN 1024       // d_inner
#define DXBC 1152      // d_inner + 2*d_state
#define DPROJ 2192     // actual in_proj rows
#define NPADW 2304     // padded to 18*128 for GEMM tiles
#define NHH 16
#define HDD 64
#define DST 64

typedef unsigned short u16;
typedef unsigned int u32;
typedef __bf16 bf16x8 __attribute__((ext_vector_type(8)));
typedef float f32x4 __attribute__((ext_vector_type(4)));

__device__ __forceinline__ float bf2f(u16 u) {
    u32 x = ((u32)u) << 16; float f; __builtin_memcpy(&f, &x, 4); return f;
}
__device__ __forceinline__ u16 f2bf(float f) {
    u32 x; __builtin_memcpy(&x, &f, 4);
    u32 r = x + 0x7fff + ((x >> 16) & 1);
    return (u16)(r >> 16);
}

__device__ __forceinline__ void gload16(const u16* g, u16* l) {
    __builtin_amdgcn_global_load_lds((__attribute__((address_space(1))) void*)(g),
                                     (__attribute__((address_space(3))) void*)(l), 16, 0, 0);
}

// ---------- weight converts ----------
__global__ void f2bf_kernel(const float* __restrict__ s, u16* __restrict__ d, int n) {
    int i = blockIdx.x * 256 + threadIdx.x;
    if (i < n) d[i] = f2bf(s[i]);
}
__global__ void f2bf_pad(const float* __restrict__ s, u16* __restrict__ d, int nsrc, int ndst) {
    int i = blockIdx.x * 256 + threadIdx.x;
    if (i < ndst) d[i] = (i < nsrc) ? f2bf(s[i]) : (u16)0;
}
__global__ void bn_prep(const float* __restrict__ cb, const float* __restrict__ g,
                        const float* __restrict__ bb, const float* __restrict__ mean,
                        const float* __restrict__ var, float* __restrict__ scale,
                        float* __restrict__ shift) {
    int i = blockIdx.x * 256 + threadIdx.x;
    if (i < CIN) {
        float rs = rsqrtf(var[i] + 1e-5f);
        float sc = g[i] * rs;
        scale[i] = sc;
        shift[i] = (cb[i] - mean[i]) * sc + bb[i];
    }
}

// ---------- LayerNorm over channels + transpose (B,C,HW) -> (tok, C), bf16 + f32 out ----------
// grid: 256 blocks (b, hw-chunk of 32); 256 threads.
__global__ __launch_bounds__(256) void ln_kernel(const float* __restrict__ x,
                                                 const float* __restrict__ lw,
                                                 const float* __restrict__ lb,
                                                 u16* __restrict__ xn,
                                                 float* __restrict__ xnf) {
    __shared__ u16 tile[CIN * 33];  // stride 33: conflict-free both directions
    __shared__ float psum[8][32], psq[8][32], muA[32], rsA[32];
    int bid = blockIdx.x;
    int b = bid >> 5, hw0 = (bid & 31) * 32;
    int t = threadIdx.x;
    int hw = t & 31, cg = t >> 5;  // 8 c-groups
    const float* xb = x + (size_t)b * CIN * LL + hw0 + hw;
    float s = 0.f, sq = 0.f;
    for (int r = 0; r < CIN / 8; ++r) {
        int c = r * 8 + cg;
        float v = xb[(size_t)c * LL];
        s += v; sq += v * v;
        tile[c * 33 + hw] = f2bf(v);
    }
    psum[cg][hw] = s; psq[cg][hw] = sq;
    __syncthreads();
    if (t < 32) {
        float ss = 0.f, qq = 0.f;
        for (int g = 0; g < 8; ++g) { ss += psum[g][t]; qq += psq[g][t]; }
        float mu = ss * (1.f / CIN);
        float var = qq * (1.f / CIN) - mu * mu;
        muA[t] = mu; rsA[t] = rsqrtf(var + 1e-5f);
    }
    __syncthreads();
    for (int r = 0; r < 64; ++r) {   // 32 hw * 512 c / 256 threads
        int idx = r * 256 + t;
        int c = idx & (CIN - 1);
        int hh = idx >> 9;
        float v = (bf2f(tile[c * 33 + hh]) - muA[hh]) * rsA[hh] * lw[c] + lb[c];
        size_t o = ((size_t)(b * LL + hw0 + hh)) * CIN + c;
        xn[o] = f2bf(v);
        xnf[o] = v;
    }
}

// ---------- bf16 MFMA GEMM: C[m][n] = sum_k A[m][k]*B[n][k]  (m97 structure) ----------
// EPI 0: store bf16 row-major ldc. EPI 1: conv2d+BN+ReLU epilogue, remapped f32 store.
template <int EPI>
__global__ __launch_bounds__(256) void gemm_bt(const u16* __restrict__ A, const u16* __restrict__ Bw,
                                               void* __restrict__ Cout, int M, int N, int K, int ldc,
                                               const float* __restrict__ scale,
                                               const float* __restrict__ shift) {
    __shared__ u16 As[128 * 32], Bs[128 * 32];
    int t = threadIdx.x;
    int lane = t & 63, wave = t >> 6;
    int m0 = blockIdx.y * 128, n0 = blockIdx.x * 128;
    int wr = wave >> 1, wc = wave & 1;
    f32x4 acc[4][4];
    for (int m = 0; m < 4; ++m)
        for (int n = 0; n < 4; ++n)
            for (int q = 0; q < 4; ++q) acc[m][n][q] = 0.f;

    const u16* Arow = A + (size_t)m0 * K;
    const u16* Brow = Bw + (size_t)n0 * K;
    for (int k0 = 0; k0 < K; k0 += 32) {
#pragma unroll
        for (int j = 0; j < 2; ++j) {
            int e = j * 2048 + t * 8;
            int r = e >> 5, c = e & 31;
            gload16(Arow + (size_t)r * K + k0 + c, As + e);
            gload16(Brow + (size_t)r * K + k0 + c, Bs + e);
        }
        __syncthreads();
        bf16x8 af[4], bfr[4];
        int seg = (lane >> 4) * 8;
        int rr = lane & 15;
#pragma unroll
        for (int m = 0; m < 4; ++m) af[m] = *(const bf16x8*)&As[(wr * 64 + m * 16 + rr) * 32 + seg];
#pragma unroll
        for (int n = 0; n < 4; ++n) bfr[n] = *(const bf16x8*)&Bs[(wc * 64 + n * 16 + rr) * 32 + seg];
#pragma unroll
        for (int m = 0; m < 4; ++m)
#pragma unroll
            for (int n = 0; n < 4; ++n)
                acc[m][n] = __builtin_amdgcn_mfma_f32_16x16x32_bf16(af[m], bfr[n], acc[m][n], 0, 0, 0);
        __syncthreads();
    }
    int fq = lane >> 4, fr = lane & 15;
#pragma unroll
    for (int m = 0; m < 4; ++m) {
#pragma unroll
        for (int n = 0; n < 4; ++n) {
            int col = n0 + wc * 64 + n * 16 + fr;
#pragma unroll
            for (int q = 0; q < 4; ++q) {
                int row = m0 + wr * 64 + m * 16 + fq * 4 + q;
                float v = acc[m][n][q];
                if (EPI == 0) {
                    ((u16*)Cout)[(size_t)row * ldc + col] = f2bf(v);
                } else {
                    v = v * scale[row] + shift[row];
                    v = v > 0.f ? v : 0.f;
                    // row = out-channel o, col = token (b*1024+hw)
                    ((float*)Cout)[((size_t)(col >> 10)) * (CIN * LL) + (size_t)row * LL + (col & 1023)] = v;
                }
            }
        }
    }
}

// ---------- depthwise causal conv1d over L + SiLU; also emit B/C as f32 ----------
__global__ __launch_bounds__(256) void conv1d_silu(const u16* __restrict__ zx,
                                                   const float* __restrict__ w,
                                                   const float* __restrict__ bias,
                                                   u16* __restrict__ xbc,
                                                   float* __restrict__ Bc, float* __restrict__ Cc) {
    int tok = blockIdx.x;
    int b = tok >> 10, l = tok & 1023;
    for (int ch = threadIdx.x; ch < DXBC; ch += 256) {
        float acc = bias[ch];
#pragma unroll
        for (int j = 0; j < 4; ++j) {
            int l2 = l - 3 + j;
            if (l2 >= 0) acc += bf2f(zx[((size_t)(b * LL + l2)) * NPADW + DIN + ch]) * w[ch * 4 + j];
        }
        float sv = acc / (1.f + __expf(-acc));
        xbc[(size_t)tok * DXBC + ch] = f2bf(sv);
        int s = ch - DIN;
        if (s >= 0) {
            if (s < DST) Bc[(size_t)tok * DST + s] = sv;
            else Cc[(size_t)tok * DST + (s - DST)] = sv;
        }
    }
}

// ---------- fp32 GEMV for dt (16 heads) from fp32 LN output ----------
__global__ __launch_bounds__(256) void dt_gemv(const float* __restrict__ xnf,
                                               const float* __restrict__ wproj,
                                               float* __restrict__ dtf) {
    int tok = blockIdx.x;
    int t = threadIdx.x;
    int h = t >> 4, part = t & 15;
    const float* xr = xnf + (size_t)tok * CIN;
    const float* wr = wproj + (size_t)(DIN + DXBC + h) * CIN;
    float s = 0.f;
    for (int c = part * 32; c < part * 32 + 32; c += 4) {
        float4 xv = *(const float4*)&xr[c];
        float4 wv = *(const float4*)&wr[c];
        s += xv.x * wv.x + xv.y * wv.y + xv.z * wv.z + xv.w * wv.w;
    }
    s += __shfl_xor(s, 1, 64);
    s += __shfl_xor(s, 2, 64);
    s += __shfl_xor(s, 4, 64);
    s += __shfl_xor(s, 8, 64);
    if (part == 0) dtf[(size_t)tok * NHH + h] = s;
}

// ---------- SSM selective scan + D*x + SiLU(z) gating ----------
// grid 256 blocks (b, h, p-half), 256 threads = 4 waves; wave handles 8 p-rows.
// lane: p = phalf*32 + wave*8 + (lane&7); s-block = lane>>3 (8 s each).
__global__ __launch_bounds__(256) void ssm_scan(const u16* __restrict__ zx,
                                                const u16* __restrict__ xbc,
                                                const float* __restrict__ Bc,
                                                const float* __restrict__ Cc,
                                                const float* __restrict__ dtf,
                                                const float* __restrict__ dt_bias,
                                                const float* __restrict__ A_log,
                                                const float* __restrict__ Dp,
                                                float* __restrict__ yraw) {
    int bid = blockIdx.x;
    int b = bid >> 5, h = (bid >> 1) & 15, ph = bid & 1;
    int t = threadIdx.x, lane = t & 63, wave = t >> 6;
    int p = ph * 32 + wave * 8 + (lane & 7);
    int sb = lane >> 3;
    float dtb = dt_bias[h];
    float An = -__expf(A_log[h]);
    float Dh = Dp[h];
    size_t tok0 = (size_t)b * LL;
    const float* Bp = Bc + tok0 * DST + sb * 8;
    const float* Cp = Cc + tok0 * DST + sb * 8;
    const u16* xp = xbc + tok0 * DXBC + h * HDD + p;
    const u16* zp = zx + tok0 * NPADW + h * HDD + p;
    const float* dtp = dtf + tok0 * NHH + h;
    float* yp = yraw + tok0 * DIN + h * HDD + p;

    float4 ba = *(const float4*)Bp, bb = *(const float4*)(Bp + 4);
    float4 ca = *(const float4*)Cp, cb = *(const float4*)(Cp + 4);
    float xv = bf2f(*xp), zf = bf2f(*zp), dtr = *dtp;
    float hs[8] = {0.f, 0.f, 0.f, 0.f, 0.f, 0.f, 0.f, 0.f};
    for (int tt = 0; tt < LL; ++tt) {
        int tn = (tt + 1 < LL) ? tt + 1 : tt;
        float4 nba = *(const float4*)(Bp + (size_t)tn * DST);
        float4 nbb = *(const float4*)(Bp + (size_t)tn * DST + 4);
        float4 nca = *(const float4*)(Cp + (size_t)tn * DST);
        float4 ncb = *(const float4*)(Cp + (size_t)tn * DST + 4);
        float nxv = bf2f(xp[(size_t)tn * DXBC]);
        float nzf = bf2f(zp[(size_t)tn * NPADW]);
        float ndtr = dtp[(size_t)tn * NHH];

        float si = dtr + dtb;
        float dtv = si > 15.f ? si : __logf(1.f + __expf(si));
        float dA = __expf(dtv * An);
        float tmp = dtv * xv;
        hs[0] = hs[0] * dA + tmp * ba.x;
        hs[1] = hs[1] * dA + tmp * ba.y;
        hs[2] = hs[2] * dA + tmp * ba.z;
        hs[3] = hs[3] * dA + tmp * ba.w;
        hs[4] = hs[4] * dA + tmp * bb.x;
        hs[5] = hs[5] * dA + tmp * bb.y;
        hs[6] = hs[6] * dA + tmp * bb.z;
        hs[7] = hs[7] * dA + tmp * bb.w;
        float ys = ((hs[0] * ca.x + hs[1] * ca.y) + (hs[2] * ca.z + hs[3] * ca.w)) +
                   ((hs[4] * cb.x + hs[5] * cb.y) + (hs[6] * cb.z + hs[7] * cb.w));
        ys += __shfl_xor(ys, 8, 64);
        ys += __shfl_xor(ys, 16, 64);
        ys += __shfl_xor(ys, 32, 64);
        float yo = ys + Dh * xv;
        float sg = 1.f / (1.f + __expf(-zf));
        yo *= zf * sg;
        if (sb == 0) yp[(size_t)tt * DIN] = yo;
        ba = nba; bb = nbb; ca = nca; cb = ncb;
        xv = nxv; zf = nzf; dtr = ndtr;
    }
}

// ---------- RMSNorm over d_inner, write bf16 ----------
__global__ __launch_bounds__(256) void rms_kernel(const float* __restrict__ y,
                                                  const float* __restrict__ w,
                                                  u16* __restrict__ y2) {
    int row = blockIdx.x, t = threadIdx.x;
    const float4 v = *(const float4*)&y[(size_t)row * DIN + t * 4];
    float ss = v.x * v.x + v.y * v.y + v.z * v.z + v.w * v.w;
#pragma unroll
    for (int o = 1; o < 64; o <<= 1) ss += __shfl_xor(ss, o, 64);
    __shared__ float ps[4];
    if ((t & 63) == 0) ps[t >> 6] = ss;
    __syncthreads();
    float tot = ps[0] + ps[1] + ps[2] + ps[3];
    float rs = rsqrtf(tot * (1.f / DIN) + 1e-5f);
    int c = t * 4;
    ushort4 o4;
    o4.x = f2bf(v.x * rs * w[c]);
    o4.y = f2bf(v.y * rs * w[c + 1]);
    o4.z = f2bf(v.z * rs * w[c + 2]);
    o4.w = f2bf(v.w * rs * w[c + 3]);
    *(ushort4*)&y2[(size_t)row * DIN + c] = o4;
}

extern "C" void kernel_launch(void* const* d_in, const int* in_sizes, int n_in,
                              void* d_out, int out_size, void* d_ws, size_t ws_size,
                              hipStream_t stream) {
    const float* x         = (const float*)d_in[0];
    const float* ln_w      = (const float*)d_in[1];
    const float* ln_b      = (const float*)d_in[2];
    const float* in_proj_w = (const float*)d_in[3];
    const float* conv1d_w  = (const float*)d_in[4];
    const float* conv1d_b  = (const float*)d_in[5];
    const float* dt_bias   = (const float*)d_in[6];
    const float* A_log     = (const float*)d_in[7];
    const float* Dp        = (const float*)d_in[8];
    const float* rms_w     = (const float*)d_in[9];
    const float* out_proj_w= (const float*)d_in[10];
    const float* conv2d_w  = (const float*)d_in[11];
    const float* conv2d_b  = (const float*)d_in[12];
    const float* bn_g      = (const float*)d_in[13];
    const float* bn_b      = (const float*)d_in[14];
    const float* bn_mean   = (const float*)d_in[15];
    const float* bn_var    = (const float*)d_in[16];

    const int TOK = NB * LL;  // 8192
    char* ws = (char*)d_ws;
    size_t off = 0;
    auto alloc = [&](size_t bytes) {
        void* p = ws + off;
        off += (bytes + 255) & ~(size_t)255;
        return p;
    };
    u16*   Win   = (u16*)alloc((size_t)NPADW * CIN * 2);
    u16*   Wout  = (u16*)alloc((size_t)CIN * DIN * 2);
    u16*   Wc2   = (u16*)alloc((size_t)CIN * CIN * 2);
    u16*   XN    = (u16*)alloc((size_t)TOK * CIN * 2);
    float* XNF   = (float*)alloc((size_t)TOK * CIN * 4);
    u16*   ZX    = (u16*)alloc((size_t)TOK * NPADW * 2);
    u16*   XBC   = (u16*)alloc((size_t)TOK * DXBC * 2);
    float* Bcb   = (float*)alloc((size_t)TOK * DST * 4);
    float* Ccb   = (float*)alloc((size_t)TOK * DST * 4);
    float* DTF   = (float*)alloc((size_t)TOK * NHH * 4);
    float* YRAW  = (float*)alloc((size_t)TOK * DIN * 4);
    u16*   Y2    = (u16*)alloc((size_t)TOK * DIN * 2);
    u16*   OUT1  = (u16*)alloc((size_t)TOK * CIN * 2);
    float* BNSC  = (float*)alloc(CIN * 4);
    float* BNSH  = (float*)alloc(CIN * 4);

    f2bf_pad<<<(NPADW * CIN + 255) / 256, 256, 0, stream>>>(in_proj_w, Win, DPROJ * CIN, NPADW * CIN);
    f2bf_kernel<<<(CIN * DIN + 255) / 256, 256, 0, stream>>>(out_proj_w, Wout, CIN * DIN);
    f2bf_kernel<<<(CIN * CIN + 255) / 256, 256, 0, stream>>>(conv2d_w, Wc2, CIN * CIN);
    bn_prep<<<2, 256, 0, stream>>>(conv2d_b, bn_g, bn_b, bn_mean, bn_var, BNSC, BNSH);

    ln_kernel<<<256, 256, 0, stream>>>(x, ln_w, ln_b, XN, XNF);

    gemm_bt<0><<<dim3(NPADW / 128, TOK / 128), 256, 0, stream>>>(XN, Win, ZX, TOK, NPADW, CIN, NPADW,
                                                                 nullptr, nullptr);

    conv1d_silu<<<TOK, 256, 0, stream>>>(ZX, conv1d_w, conv1d_b, XBC, Bcb, Ccb);
    dt_gemv<<<TOK, 256, 0, stream>>>(XNF, in_proj_w, DTF);

    ssm_scan<<<256, 256, 0, stream>>>(ZX, XBC, Bcb, Ccb, DTF, dt_bias, A_log, Dp, YRAW);

    rms_kernel<<<TOK, 256, 0, stream>>>(YRAW, rms_w, Y2);

    gemm_bt<0><<<dim3(CIN / 128, TOK / 128), 256, 0, stream>>>(Y2, Wout, OUT1, TOK, CIN, DIN, CIN,
                                                               nullptr, nullptr);

    gemm_bt<1><<<dim3(TOK / 128, CIN / 128), 256, 0, stream>>>(Wc2, OUT1, d_out, CIN, TOK, CIN, 0,
                                                               BNSC, BNSH);
}

// Round 2
// 621.898 us; speedup vs baseline: 1.1745x; 1.1745x over previous
//
#include <hip/hip_runtime.h>
#include <hip/hip_bf16.h>

// Problem constants
#define NB 8
#define LL 1024        // H*W tokens per batch
#define CIN 512
#define DIN 1024       // d_inner
#define DXBC 1152      // d_inner + 2*d_state
#define DPROJ 2192     // actual in_proj rows
#define NPADW 2304     // padded to 18*128 for GEMM tiles
#define NHH 16
#define HDD 64
#define DST 64

typedef unsigned short u16;
typedef unsigned int u32;
typedef __bf16 bf16x8 __attribute__((ext_vector_type(8)));
typedef float f32x4 __attribute__((ext_vector_type(4)));

__device__ __forceinline__ float bf2f(u16 u) {
    u32 x = ((u32)u) << 16; float f; __builtin_memcpy(&f, &x, 4); return f;
}
__device__ __forceinline__ u16 f2bf(float f) {
    u32 x; __builtin_memcpy(&x, &f, 4);
    u32 r = x + 0x7fff + ((x >> 16) & 1);
    return (u16)(r >> 16);
}

__device__ __forceinline__ void gload16(const u16* g, u16* l) {
    __builtin_amdgcn_global_load_lds((__attribute__((address_space(1))) void*)(g),
                                     (__attribute__((address_space(3))) void*)(l), 16, 0, 0);
}

// ---------- weight converts ----------
__global__ void f2bf_kernel(const float* __restrict__ s, u16* __restrict__ d, int n) {
    int i = blockIdx.x * 256 + threadIdx.x;
    if (i < n) d[i] = f2bf(s[i]);
}
__global__ void f2bf_pad(const float* __restrict__ s, u16* __restrict__ d, int nsrc, int ndst) {
    int i = blockIdx.x * 256 + threadIdx.x;
    if (i < ndst) d[i] = (i < nsrc) ? f2bf(s[i]) : (u16)0;
}
__global__ void bn_prep(const float* __restrict__ cb, const float* __restrict__ g,
                        const float* __restrict__ bb, const float* __restrict__ mean,
                        const float* __restrict__ var, float* __restrict__ scale,
                        float* __restrict__ shift) {
    int i = blockIdx.x * 256 + threadIdx.x;
    if (i < CIN) {
        float rs = rsqrtf(var[i] + 1e-5f);
        float sc = g[i] * rs;
        scale[i] = sc;
        shift[i] = (cb[i] - mean[i]) * sc + bb[i];
    }
}

// ---------- LayerNorm over channels + transpose (B,C,HW) -> (tok, C), bf16 + f32 out ----------
__global__ __launch_bounds__(256) void ln_kernel(const float* __restrict__ x,
                                                 const float* __restrict__ lw,
                                                 const float* __restrict__ lb,
                                                 u16* __restrict__ xn,
                                                 float* __restrict__ xnf) {
    __shared__ u16 tile[CIN * 33];
    __shared__ float psum[8][32], psq[8][32], muA[32], rsA[32];
    int bid = blockIdx.x;
    int b = bid >> 5, hw0 = (bid & 31) * 32;
    int t = threadIdx.x;
    int hw = t & 31, cg = t >> 5;
    const float* xb = x + (size_t)b * CIN * LL + hw0 + hw;
    float s = 0.f, sq = 0.f;
    for (int r = 0; r < CIN / 8; ++r) {
        int c = r * 8 + cg;
        float v = xb[(size_t)c * LL];
        s += v; sq += v * v;
        tile[c * 33 + hw] = f2bf(v);
    }
    psum[cg][hw] = s; psq[cg][hw] = sq;
    __syncthreads();
    if (t < 32) {
        float ss = 0.f, qq = 0.f;
        for (int g = 0; g < 8; ++g) { ss += psum[g][t]; qq += psq[g][t]; }
        float mu = ss * (1.f / CIN);
        float var = qq * (1.f / CIN) - mu * mu;
        muA[t] = mu; rsA[t] = rsqrtf(var + 1e-5f);
    }
    __syncthreads();
    for (int r = 0; r < 64; ++r) {
        int idx = r * 256 + t;
        int c = idx & (CIN - 1);
        int hh = idx >> 9;
        float v = (bf2f(tile[c * 33 + hh]) - muA[hh]) * rsA[hh] * lw[c] + lb[c];
        size_t o = ((size_t)(b * LL + hw0 + hh)) * CIN + c;
        xn[o] = f2bf(v);
        xnf[o] = v;
    }
}

// ---------- bf16 MFMA GEMM (m97 structure) ----------
template <int EPI>
__global__ __launch_bounds__(256) void gemm_bt(const u16* __restrict__ A, const u16* __restrict__ Bw,
                                               void* __restrict__ Cout, int M, int N, int K, int ldc,
                                               const float* __restrict__ scale,
                                               const float* __restrict__ shift) {
    __shared__ u16 As[128 * 32], Bs[128 * 32];
    int t = threadIdx.x;
    int lane = t & 63, wave = t >> 6;
    int m0 = blockIdx.y * 128, n0 = blockIdx.x * 128;
    int wr = wave >> 1, wc = wave & 1;
    f32x4 acc[4][4];
    for (int m = 0; m < 4; ++m)
        for (int n = 0; n < 4; ++n)
            for (int q = 0; q < 4; ++q) acc[m][n][q] = 0.f;

    const u16* Arow = A + (size_t)m0 * K;
    const u16* Brow = Bw + (size_t)n0 * K;
    for (int k0 = 0; k0 < K; k0 += 32) {
#pragma unroll
        for (int j = 0; j < 2; ++j) {
            int e = j * 2048 + t * 8;
            int r = e >> 5, c = e & 31;
            gload16(Arow + (size_t)r * K + k0 + c, As + e);
            gload16(Brow + (size_t)r * K + k0 + c, Bs + e);
        }
        __syncthreads();
        bf16x8 af[4], bfr[4];
        int seg = (lane >> 4) * 8;
        int rr = lane & 15;
#pragma unroll
        for (int m = 0; m < 4; ++m) af[m] = *(const bf16x8*)&As[(wr * 64 + m * 16 + rr) * 32 + seg];
#pragma unroll
        for (int n = 0; n < 4; ++n) bfr[n] = *(const bf16x8*)&Bs[(wc * 64 + n * 16 + rr) * 32 + seg];
#pragma unroll
        for (int m = 0; m < 4; ++m)
#pragma unroll
            for (int n = 0; n < 4; ++n)
                acc[m][n] = __builtin_amdgcn_mfma_f32_16x16x32_bf16(af[m], bfr[n], acc[m][n], 0, 0, 0);
        __syncthreads();
    }
    int fq = lane >> 4, fr = lane & 15;
#pragma unroll
    for (int m = 0; m < 4; ++m) {
#pragma unroll
        for (int n = 0; n < 4; ++n) {
            int col = n0 + wc * 64 + n * 16 + fr;
#pragma unroll
            for (int q = 0; q < 4; ++q) {
                int row = m0 + wr * 64 + m * 16 + fq * 4 + q;
                float v = acc[m][n][q];
                if (EPI == 0) {
                    ((u16*)Cout)[(size_t)row * ldc + col] = f2bf(v);
                } else {
                    v = v * scale[row] + shift[row];
                    v = v > 0.f ? v : 0.f;
                    ((float*)Cout)[((size_t)(col >> 10)) * (CIN * LL) + (size_t)row * LL + (col & 1023)] = v;
                }
            }
        }
    }
}

// ---------- depthwise causal conv1d over L + SiLU; also emit B/C as f32 ----------
__global__ __launch_bounds__(256) void conv1d_silu(const u16* __restrict__ zx,
                                                   const float* __restrict__ w,
                                                   const float* __restrict__ bias,
                                                   u16* __restrict__ xbc,
                                                   float* __restrict__ Bc, float* __restrict__ Cc) {
    int tok = blockIdx.x;
    int b = tok >> 10, l = tok & 1023;
    for (int ch = threadIdx.x; ch < DXBC; ch += 256) {
        float acc = bias[ch];
#pragma unroll
        for (int j = 0; j < 4; ++j) {
            int l2 = l - 3 + j;
            if (l2 >= 0) acc += bf2f(zx[((size_t)(b * LL + l2)) * NPADW + DIN + ch]) * w[ch * 4 + j];
        }
        float sv = acc / (1.f + __expf(-acc));
        xbc[(size_t)tok * DXBC + ch] = f2bf(sv);
        int s = ch - DIN;
        if (s >= 0) {
            if (s < DST) Bc[(size_t)tok * DST + s] = sv;
            else Cc[(size_t)tok * DST + (s - DST)] = sv;
        }
    }
}

// ---------- fp32 GEMV for dt + precompute (dtv, dA) + z-gate ----------
__global__ __launch_bounds__(256) void dt_gemv(const float* __restrict__ xnf,
                                               const float* __restrict__ wproj,
                                               const float* __restrict__ dt_bias,
                                               const float* __restrict__ A_log,
                                               const u16* __restrict__ zx,
                                               float2* __restrict__ dtda,
                                               u16* __restrict__ zg) {
    int tok = blockIdx.x;
    int t = threadIdx.x;
    int h = t >> 4, part = t & 15;
    const float* xr = xnf + (size_t)tok * CIN;
    const float* wr = wproj + (size_t)(DIN + DXBC + h) * CIN;
    float s = 0.f;
    for (int c = part * 32; c < part * 32 + 32; c += 4) {
        float4 xv = *(const float4*)&xr[c];
        float4 wv = *(const float4*)&wr[c];
        s += xv.x * wv.x + xv.y * wv.y + xv.z * wv.z + xv.w * wv.w;
    }
    s += __shfl_xor(s, 1, 64);
    s += __shfl_xor(s, 2, 64);
    s += __shfl_xor(s, 4, 64);
    s += __shfl_xor(s, 8, 64);
    if (part == 0) {
        float si = s + dt_bias[h];
        float dtv = si > 15.f ? si : __logf(1.f + __expf(si));
        float An = -__expf(A_log[h]);
        float2 dd; dd.x = dtv; dd.y = __expf(dtv * An);
        dtda[(size_t)tok * NHH + h] = dd;
    }
    // z-gate: z * sigmoid(z), 4 elems per thread
    const u16* zr = zx + (size_t)tok * NPADW;
    ushort4 zv = *(const ushort4*)(zr + t * 4);
    float z0 = bf2f(zv.x), z1 = bf2f(zv.y), z2 = bf2f(zv.z), z3 = bf2f(zv.w);
    ushort4 o;
    o.x = f2bf(z0 / (1.f + __expf(-z0)));
    o.y = f2bf(z1 / (1.f + __expf(-z1)));
    o.z = f2bf(z2 / (1.f + __expf(-z2)));
    o.w = f2bf(z3 / (1.f + __expf(-z3)));
    *(ushort4*)(zg + (size_t)tok * DIN + t * 4) = o;
}

// ---------- SSM selective scan: 8-deep pipelined, transcendental-free ----------
// grid 256 blocks (b, h, p-half), 256 threads = 4 waves; wave: 8 p × 8 s-blocks.
#define SDEPTH 8
__global__ __launch_bounds__(256) void ssm_scan(const u16* __restrict__ xbc,
                                                const u16* __restrict__ zg,
                                                const float* __restrict__ Bc,
                                                const float* __restrict__ Cc,
                                                const float2* __restrict__ dtda,
                                                const float* __restrict__ Dp,
                                                float* __restrict__ yraw) {
    int bid = blockIdx.x;
    int b = bid >> 5, h = (bid >> 1) & 15, ph = bid & 1;
    int t = threadIdx.x, lane = t & 63, wave = t >> 6;
    int p = ph * 32 + wave * 8 + (lane & 7);
    int sb = lane >> 3;
    float Dh = Dp[h];
    size_t tok0 = (size_t)b * LL;
    const float* Bp = Bc + tok0 * DST + sb * 8;
    const float* Cp = Cc + tok0 * DST + sb * 8;
    const u16* xp = xbc + tok0 * DXBC + h * HDD + p;
    const u16* zp = zg + tok0 * DIN + h * HDD + p;
    const float2* dtp = dtda + tok0 * NHH + h;
    float* yp = yraw + tok0 * DIN + h * HDD + p;

    float4 Ba[SDEPTH], Bb[SDEPTH], Ca[SDEPTH], Cb[SDEPTH];
    float xv[SDEPTH], zf[SDEPTH], dtv[SDEPTH], da[SDEPTH];
#pragma unroll
    for (int j = 0; j < SDEPTH; ++j) {
        Ba[j] = *(const float4*)(Bp + (size_t)j * DST);
        Bb[j] = *(const float4*)(Bp + (size_t)j * DST + 4);
        Ca[j] = *(const float4*)(Cp + (size_t)j * DST);
        Cb[j] = *(const float4*)(Cp + (size_t)j * DST + 4);
        xv[j] = bf2f(xp[(size_t)j * DXBC]);
        zf[j] = bf2f(zp[(size_t)j * DIN]);
        float2 dd = dtp[(size_t)j * NHH];
        dtv[j] = dd.x; da[j] = dd.y;
    }
    float hs[8] = {0.f, 0.f, 0.f, 0.f, 0.f, 0.f, 0.f, 0.f};
    for (int tt = 0; tt < LL; tt += SDEPTH) {
#pragma unroll
        for (int j = 0; j < SDEPTH; ++j) {
            int tc = tt + j;
            int tn = tc + SDEPTH;
            int ta = tn < LL ? tn : LL - 1;
            // issue prefetch (consumed SDEPTH tokens later)
            float4 nBa = *(const float4*)(Bp + (size_t)ta * DST);
            float4 nBb = *(const float4*)(Bp + (size_t)ta * DST + 4);
            float4 nCa = *(const float4*)(Cp + (size_t)ta * DST);
            float4 nCb = *(const float4*)(Cp + (size_t)ta * DST + 4);
            float nxv = bf2f(xp[(size_t)ta * DXBC]);
            float nzf = bf2f(zp[(size_t)ta * DIN]);
            float2 ndd = dtp[(size_t)ta * NHH];
            // compute token tc from slot j
            float tmp = dtv[j] * xv[j];
            float dA = da[j];
            hs[0] = hs[0] * dA + tmp * Ba[j].x;
            hs[1] = hs[1] * dA + tmp * Ba[j].y;
            hs[2] = hs[2] * dA + tmp * Ba[j].z;
            hs[3] = hs[3] * dA + tmp * Ba[j].w;
            hs[4] = hs[4] * dA + tmp * Bb[j].x;
            hs[5] = hs[5] * dA + tmp * Bb[j].y;
            hs[6] = hs[6] * dA + tmp * Bb[j].z;
            hs[7] = hs[7] * dA + tmp * Bb[j].w;
            float ys = ((hs[0] * Ca[j].x + hs[1] * Ca[j].y) + (hs[2] * Ca[j].z + hs[3] * Ca[j].w)) +
                       ((hs[4] * Cb[j].x + hs[5] * Cb[j].y) + (hs[6] * Cb[j].z + hs[7] * Cb[j].w));
            ys += __shfl_xor(ys, 8, 64);
            ys += __shfl_xor(ys, 16, 64);
            ys += __shfl_xor(ys, 32, 64);
            float yo = (ys + Dh * xv[j]) * zf[j];
            if (sb == 0) yp[(size_t)tc * DIN] = yo;
            // rotate slot j
            Ba[j] = nBa; Bb[j] = nBb; Ca[j] = nCa; Cb[j] = nCb;
            xv[j] = nxv; zf[j] = nzf; dtv[j] = ndd.x; da[j] = ndd.y;
        }
    }
}

// ---------- RMSNorm over d_inner, write bf16 ----------
__global__ __launch_bounds__(256) void rms_kernel(const float* __restrict__ y,
                                                  const float* __restrict__ w,
                                                  u16* __restrict__ y2) {
    int row = blockIdx.x, t = threadIdx.x;
    const float4 v = *(const float4*)&y[(size_t)row * DIN + t * 4];
    float ss = v.x * v.x + v.y * v.y + v.z * v.z + v.w * v.w;
#pragma unroll
    for (int o = 1; o < 64; o <<= 1) ss += __shfl_xor(ss, o, 64);
    __shared__ float ps[4];
    if ((t & 63) == 0) ps[t >> 6] = ss;
    __syncthreads();
    float tot = ps[0] + ps[1] + ps[2] + ps[3];
    float rs = rsqrtf(tot * (1.f / DIN) + 1e-5f);
    int c = t * 4;
    ushort4 o4;
    o4.x = f2bf(v.x * rs * w[c]);
    o4.y = f2bf(v.y * rs * w[c + 1]);
    o4.z = f2bf(v.z * rs * w[c + 2]);
    o4.w = f2bf(v.w * rs * w[c + 3]);
    *(ushort4*)&y2[(size_t)row * DIN + c] = o4;
}

extern "C" void kernel_launch(void* const* d_in, const int* in_sizes, int n_in,
                              void* d_out, int out_size, void* d_ws, size_t ws_size,
                              hipStream_t stream) {
    const float* x         = (const float*)d_in[0];
    const float* ln_w      = (const float*)d_in[1];
    const float* ln_b      = (const float*)d_in[2];
    const float* in_proj_w = (const float*)d_in[3];
    const float* conv1d_w  = (const float*)d_in[4];
    const float* conv1d_b  = (const float*)d_in[5];
    const float* dt_bias   = (const float*)d_in[6];
    const float* A_log     = (const float*)d_in[7];
    const float* Dp        = (const float*)d_in[8];
    const float* rms_w     = (const float*)d_in[9];
    const float* out_proj_w= (const float*)d_in[10];
    const float* conv2d_w  = (const float*)d_in[11];
    const float* conv2d_b  = (const float*)d_in[12];
    const float* bn_g      = (const float*)d_in[13];
    const float* bn_b      = (const float*)d_in[14];
    const float* bn_mean   = (const float*)d_in[15];
    const float* bn_var    = (const float*)d_in[16];

    const int TOK = NB * LL;  // 8192
    char* ws = (char*)d_ws;
    size_t off = 0;
    auto alloc = [&](size_t bytes) {
        void* p = ws + off;
        off += (bytes + 255) & ~(size_t)255;
        return p;
    };
    u16*   Win   = (u16*)alloc((size_t)NPADW * CIN * 2);
    u16*   Wout  = (u16*)alloc((size_t)CIN * DIN * 2);
    u16*   Wc2   = (u16*)alloc((size_t)CIN * CIN * 2);
    u16*   XN    = (u16*)alloc((size_t)TOK * CIN * 2);
    float* XNF   = (float*)alloc((size_t)TOK * CIN * 4);
    u16*   ZX    = (u16*)alloc((size_t)TOK * NPADW * 2);
    u16*   XBC   = (u16*)alloc((size_t)TOK * DXBC * 2);
    float* Bcb   = (float*)alloc((size_t)TOK * DST * 4);
    float* Ccb   = (float*)alloc((size_t)TOK * DST * 4);
    float2* DTDA = (float2*)alloc((size_t)TOK * NHH * 8);
    u16*   ZG    = (u16*)alloc((size_t)TOK * DIN * 2);
    float* YRAW  = (float*)alloc((size_t)TOK * DIN * 4);
    u16*   Y2    = (u16*)alloc((size_t)TOK * DIN * 2);
    u16*   OUT1  = (u16*)alloc((size_t)TOK * CIN * 2);
    float* BNSC  = (float*)alloc(CIN * 4);
    float* BNSH  = (float*)alloc(CIN * 4);

    f2bf_pad<<<(NPADW * CIN + 255) / 256, 256, 0, stream>>>(in_proj_w, Win, DPROJ * CIN, NPADW * CIN);
    f2bf_kernel<<<(CIN * DIN + 255) / 256, 256, 0, stream>>>(out_proj_w, Wout, CIN * DIN);
    f2bf_kernel<<<(CIN * CIN + 255) / 256, 256, 0, stream>>>(conv2d_w, Wc2, CIN * CIN);
    bn_prep<<<2, 256, 0, stream>>>(conv2d_b, bn_g, bn_b, bn_mean, bn_var, BNSC, BNSH);

    ln_kernel<<<256, 256, 0, stream>>>(x, ln_w, ln_b, XN, XNF);

    gemm_bt<0><<<dim3(NPADW / 128, TOK / 128), 256, 0, stream>>>(XN, Win, ZX, TOK, NPADW, CIN, NPADW,
                                                                 nullptr, nullptr);

    conv1d_silu<<<TOK, 256, 0, stream>>>(ZX, conv1d_w, conv1d_b, XBC, Bcb, Ccb);
    dt_gemv<<<TOK, 256, 0, stream>>>(XNF, in_proj_w, dt_bias, A_log, ZX, DTDA, ZG);

    ssm_scan<<<256, 256, 0, stream>>>(XBC, ZG, Bcb, Ccb, DTDA, Dp, YRAW);

    rms_kernel<<<TOK, 256, 0, stream>>>(YRAW, rms_w, Y2);

    gemm_bt<0><<<dim3(CIN / 128, TOK / 128), 256, 0, stream>>>(Y2, Wout, OUT1, TOK, CIN, DIN, CIN,
                                                               nullptr, nullptr);

    gemm_bt<1><<<dim3(TOK / 128, CIN / 128), 256, 0, stream>>>(Wc2, OUT1, d_out, CIN, TOK, CIN, 0,
                                                               BNSC, BNSH);
}

// Round 3
// 245.298 us; speedup vs baseline: 2.9776x; 2.5353x over previous
//
#include <hip/hip_runtime.h>
#include <hip/hip_bf16.h>

// Problem constants
#define NB 8
#define LL 1024        // H*W tokens per batch
#define CIN 512
#define DIN 1024       // d_inner
#define DXBC 1152      // d_inner + 2*d_state
#define DPROJ 2192     // actual in_proj rows
#define NPADW 2304     // padded to 18*128 for GEMM tiles
#define NHH 16
#define HDD 64
#define DST 64
#define NCHUNK 16
#define QCH 64         // chunk length

typedef unsigned short u16;
typedef unsigned int u32;
typedef __bf16 bf16x8 __attribute__((ext_vector_type(8)));
typedef float f32x4 __attribute__((ext_vector_type(4)));
typedef u16 u16x8 __attribute__((ext_vector_type(8)));

__device__ __forceinline__ float bf2f(u16 u) {
    u32 x = ((u32)u) << 16; float f; __builtin_memcpy(&f, &x, 4); return f;
}
__device__ __forceinline__ u16 f2bf(float f) {
    u32 x; __builtin_memcpy(&x, &f, 4);
    u32 r = x + 0x7fff + ((x >> 16) & 1);
    return (u16)(r >> 16);
}

__device__ __forceinline__ void gload16(const u16* g, u16* l) {
    __builtin_amdgcn_global_load_lds((__attribute__((address_space(1))) void*)(g),
                                     (__attribute__((address_space(3))) void*)(l), 16, 0, 0);
}

// swizzled u16 index into a [64][64] bf16 LDS tile (128B rows, 16B-slot XOR swizzle)
__device__ __forceinline__ int swz(int row, int cb) {
    return row * 64 + ((cb ^ ((row & 7) << 4)) >> 1);
}

// ---------- weight converts ----------
__global__ void f2bf_kernel(const float* __restrict__ s, u16* __restrict__ d, int n) {
    int i = blockIdx.x * 256 + threadIdx.x;
    if (i < n) d[i] = f2bf(s[i]);
}
__global__ void f2bf_pad(const float* __restrict__ s, u16* __restrict__ d, int nsrc, int ndst) {
    int i = blockIdx.x * 256 + threadIdx.x;
    if (i < ndst) d[i] = (i < nsrc) ? f2bf(s[i]) : (u16)0;
}
__global__ void bn_prep(const float* __restrict__ cb, const float* __restrict__ g,
                        const float* __restrict__ bb, const float* __restrict__ mean,
                        const float* __restrict__ var, float* __restrict__ scale,
                        float* __restrict__ shift) {
    int i = blockIdx.x * 256 + threadIdx.x;
    if (i < CIN) {
        float rs = rsqrtf(var[i] + 1e-5f);
        float sc = g[i] * rs;
        scale[i] = sc;
        shift[i] = (cb[i] - mean[i]) * sc + bb[i];
    }
}

// ---------- LayerNorm over channels + transpose (B,C,HW) -> (tok, C) bf16 ----------
__global__ __launch_bounds__(256) void ln_kernel(const float* __restrict__ x,
                                                 const float* __restrict__ lw,
                                                 const float* __restrict__ lb,
                                                 u16* __restrict__ xn) {
    __shared__ u16 tile[CIN * 33];
    __shared__ float psum[8][32], psq[8][32], muA[32], rsA[32];
    int bid = blockIdx.x;
    int b = bid >> 5, hw0 = (bid & 31) * 32;
    int t = threadIdx.x;
    int hw = t & 31, cg = t >> 5;
    const float* xb = x + (size_t)b * CIN * LL + hw0 + hw;
    float s = 0.f, sq = 0.f;
    for (int r = 0; r < CIN / 8; ++r) {
        int c = r * 8 + cg;
        float v = xb[(size_t)c * LL];
        s += v; sq += v * v;
        tile[c * 33 + hw] = f2bf(v);
    }
    psum[cg][hw] = s; psq[cg][hw] = sq;
    __syncthreads();
    if (t < 32) {
        float ss = 0.f, qq = 0.f;
        for (int g = 0; g < 8; ++g) { ss += psum[g][t]; qq += psq[g][t]; }
        float mu = ss * (1.f / CIN);
        float var = qq * (1.f / CIN) - mu * mu;
        muA[t] = mu; rsA[t] = rsqrtf(var + 1e-5f);
    }
    __syncthreads();
    for (int r = 0; r < 64; ++r) {
        int idx = r * 256 + t;
        int c = idx & (CIN - 1);
        int hh = idx >> 9;
        float v = (bf2f(tile[c * 33 + hh]) - muA[hh]) * rsA[hh] * lw[c] + lb[c];
        xn[((size_t)(b * LL + hw0 + hh)) * CIN + c] = f2bf(v);
    }
}

// ---------- bf16 MFMA GEMM (m97 structure) ----------
template <int EPI>
__global__ __launch_bounds__(256) void gemm_bt(const u16* __restrict__ A, const u16* __restrict__ Bw,
                                               void* __restrict__ Cout, int M, int N, int K, int ldc,
                                               const float* __restrict__ scale,
                                               const float* __restrict__ shift) {
    __shared__ u16 As[128 * 32], Bs[128 * 32];
    int t = threadIdx.x;
    int lane = t & 63, wave = t >> 6;
    int m0 = blockIdx.y * 128, n0 = blockIdx.x * 128;
    int wr = wave >> 1, wc = wave & 1;
    f32x4 acc[4][4];
    for (int m = 0; m < 4; ++m)
        for (int n = 0; n < 4; ++n)
            for (int q = 0; q < 4; ++q) acc[m][n][q] = 0.f;

    const u16* Arow = A + (size_t)m0 * K;
    const u16* Brow = Bw + (size_t)n0 * K;
    for (int k0 = 0; k0 < K; k0 += 32) {
#pragma unroll
        for (int j = 0; j < 2; ++j) {
            int e = j * 2048 + t * 8;
            int r = e >> 5, c = e & 31;
            gload16(Arow + (size_t)r * K + k0 + c, As + e);
            gload16(Brow + (size_t)r * K + k0 + c, Bs + e);
        }
        __syncthreads();
        bf16x8 af[4], bfr[4];
        int seg = (lane >> 4) * 8;
        int rr = lane & 15;
#pragma unroll
        for (int m = 0; m < 4; ++m) af[m] = *(const bf16x8*)&As[(wr * 64 + m * 16 + rr) * 32 + seg];
#pragma unroll
        for (int n = 0; n < 4; ++n) bfr[n] = *(const bf16x8*)&Bs[(wc * 64 + n * 16 + rr) * 32 + seg];
#pragma unroll
        for (int m = 0; m < 4; ++m)
#pragma unroll
            for (int n = 0; n < 4; ++n)
                acc[m][n] = __builtin_amdgcn_mfma_f32_16x16x32_bf16(af[m], bfr[n], acc[m][n], 0, 0, 0);
        __syncthreads();
    }
    int fq = lane >> 4, fr = lane & 15;
#pragma unroll
    for (int m = 0; m < 4; ++m) {
#pragma unroll
        for (int n = 0; n < 4; ++n) {
            int col = n0 + wc * 64 + n * 16 + fr;
#pragma unroll
            for (int q = 0; q < 4; ++q) {
                int row = m0 + wr * 64 + m * 16 + fq * 4 + q;
                float v = acc[m][n][q];
                if (EPI == 0) {
                    ((u16*)Cout)[(size_t)row * ldc + col] = f2bf(v);
                } else {
                    v = v * scale[row] + shift[row];
                    v = v > 0.f ? v : 0.f;
                    ((float*)Cout)[((size_t)(col >> 10)) * (CIN * LL) + (size_t)row * LL + (col & 1023)] = v;
                }
            }
        }
    }
}

// ---------- depthwise causal conv1d over L + SiLU; also emit B/C as f32 ----------
__global__ __launch_bounds__(256) void conv1d_silu(const u16* __restrict__ zx,
                                                   const float* __restrict__ w,
                                                   const float* __restrict__ bias,
                                                   u16* __restrict__ xbc,
                                                   float* __restrict__ Bc, float* __restrict__ Cc) {
    int tok = blockIdx.x;
    int b = tok >> 10, l = tok & 1023;
    for (int ch = threadIdx.x; ch < DXBC; ch += 256) {
        float acc = bias[ch];
#pragma unroll
        for (int j = 0; j < 4; ++j) {
            int l2 = l - 3 + j;
            if (l2 >= 0) acc += bf2f(zx[((size_t)(b * LL + l2)) * NPADW + DIN + ch]) * w[ch * 4 + j];
        }
        float sv = acc / (1.f + __expf(-acc));
        xbc[(size_t)tok * DXBC + ch] = f2bf(sv);
        int s = ch - DIN;
        if (s >= 0) {
            if (s < DST) Bc[(size_t)tok * DST + s] = sv;
            else Cc[(size_t)tok * DST + (s - DST)] = sv;
        }
    }
}

// ---------- dt GEMV: compute dtv = softplus(dt+bias), a = dtv*(-exp(A_log)) ----------
__global__ __launch_bounds__(256) void dt_gemv(const u16* __restrict__ xn,
                                               const float* __restrict__ wproj,
                                               const float* __restrict__ dt_bias,
                                               const float* __restrict__ A_log,
                                               float2* __restrict__ dtda) {
    int tok = blockIdx.x;
    int t = threadIdx.x;
    int h = t >> 4, part = t & 15;
    const u16* xr = xn + (size_t)tok * CIN;
    const float* wr = wproj + (size_t)(DIN + DXBC + h) * CIN;
    float s = 0.f;
    for (int c0 = part * 32; c0 < part * 32 + 32; c0 += 8) {
        u16x8 xv = *(const u16x8*)&xr[c0];
        float4 w0 = *(const float4*)&wr[c0];
        float4 w1 = *(const float4*)&wr[c0 + 4];
        s += bf2f(xv[0]) * w0.x + bf2f(xv[1]) * w0.y + bf2f(xv[2]) * w0.z + bf2f(xv[3]) * w0.w;
        s += bf2f(xv[4]) * w1.x + bf2f(xv[5]) * w1.y + bf2f(xv[6]) * w1.z + bf2f(xv[7]) * w1.w;
    }
    s += __shfl_xor(s, 1, 64);
    s += __shfl_xor(s, 2, 64);
    s += __shfl_xor(s, 4, 64);
    s += __shfl_xor(s, 8, 64);
    if (part == 0) {
        float si = s + dt_bias[h];
        float dtv = si > 15.f ? si : __logf(1.f + __expf(si));
        float An = -__expf(A_log[h]);
        float2 dd; dd.x = dtv; dd.y = dtv * An;
        dtda[(size_t)tok * NHH + h] = dd;
    }
}

// ---------- SSD K1: per-(b,h,chunk) — G̃, Y_intra, ΔH, C2, d_c ----------
__global__ __launch_bounds__(256) void ssd_chunk(const float* __restrict__ Bcb,
                                                 const float* __restrict__ Ccb,
                                                 const u16* __restrict__ xbc,
                                                 const float2* __restrict__ dtda,
                                                 float* __restrict__ yraw,
                                                 float* __restrict__ DHb,
                                                 u16* __restrict__ C2G,
                                                 float* __restrict__ DC) {
    __shared__ u16 Bt[4096], Ct[4096], XT[4096], BTt[4096], Gt[4096];
    __shared__ float Sar[64], dtvA[64], wA[64], eSA[64];
    int tau = blockIdx.x;
    int b = tau >> 8, h = (tau >> 4) & 15, c = tau & 15;
    int t0g = b * LL + c * QCH;
    int t = threadIdx.x, lane = t & 63, wave = t >> 6;
    int row = t >> 2, q = t & 3;

    // ---- phase A: stage B, C (fp32->bf16), X (transposed), dt scan ----
    {
        const float* bp = Bcb + (size_t)(t0g + row) * DST + q * 16;
        const float* cp = Ccb + (size_t)(t0g + row) * DST + q * 16;
#pragma unroll
        for (int half = 0; half < 2; ++half) {
            float4 v0 = *(const float4*)(bp + half * 8);
            float4 v1 = *(const float4*)(bp + half * 8 + 4);
            u16x8 o;
            o[0] = f2bf(v0.x); o[1] = f2bf(v0.y); o[2] = f2bf(v0.z); o[3] = f2bf(v0.w);
            o[4] = f2bf(v1.x); o[5] = f2bf(v1.y); o[6] = f2bf(v1.z); o[7] = f2bf(v1.w);
            *(u16x8*)&Bt[swz(row, q * 32 + half * 16)] = o;
            float4 c0 = *(const float4*)(cp + half * 8);
            float4 c1 = *(const float4*)(cp + half * 8 + 4);
            u16x8 oc;
            oc[0] = f2bf(c0.x); oc[1] = f2bf(c0.y); oc[2] = f2bf(c0.z); oc[3] = f2bf(c0.w);
            oc[4] = f2bf(c1.x); oc[5] = f2bf(c1.y); oc[6] = f2bf(c1.z); oc[7] = f2bf(c1.w);
            *(u16x8*)&Ct[swz(row, q * 32 + half * 16)] = oc;
        }
        const u16* xp = xbc + (size_t)(t0g + row) * DXBC + h * HDD + q * 16;
        u16x8 x0 = *(const u16x8*)xp;
        u16x8 x1 = *(const u16x8*)(xp + 8);
#pragma unroll
        for (int e = 0; e < 8; ++e) XT[swz(q * 16 + e, row * 2)] = x0[e];
#pragma unroll
        for (int e = 0; e < 8; ++e) XT[swz(q * 16 + 8 + e, row * 2)] = x1[e];
    }
    if (t < 64) {
        float2 dd = dtda[(size_t)(t0g + t) * NHH + h];
        float s = dd.y;  // a_t
#pragma unroll
        for (int off = 1; off < 64; off <<= 1) {
            float u = __shfl_up(s, off, 64);
            if (t >= off) s += u;
        }
        float SQ = __shfl(s, 63, 64);
        Sar[t] = s; dtvA[t] = dd.x;
        wA[t] = __expf(SQ - s) * dd.x;
        eSA[t] = __expf(s);
        if (t == 0) DC[tau] = __expf(SQ);
    }
    __syncthreads();

    int R = wave >> 1, Cq = wave & 1, rr = lane & 15, sg = lane >> 4;
    // ---- phase B: G = C·B^T, scale/mask -> Gt; also C2 + B~T ----
    f32x4 g[2][2];
#pragma unroll
    for (int mi = 0; mi < 2; ++mi)
#pragma unroll
        for (int ni = 0; ni < 2; ++ni)
#pragma unroll
            for (int r = 0; r < 4; ++r) g[mi][ni][r] = 0.f;
#pragma unroll
    for (int kt = 0; kt < 2; ++kt) {
        int cb = kt * 64 + sg * 16;
        bf16x8 a0 = *(const bf16x8*)&Ct[swz(R * 32 + rr, cb)];
        bf16x8 a1 = *(const bf16x8*)&Ct[swz(R * 32 + 16 + rr, cb)];
        bf16x8 b0 = *(const bf16x8*)&Bt[swz(Cq * 32 + rr, cb)];
        bf16x8 b1 = *(const bf16x8*)&Bt[swz(Cq * 32 + 16 + rr, cb)];
        g[0][0] = __builtin_amdgcn_mfma_f32_16x16x32_bf16(a0, b0, g[0][0], 0, 0, 0);
        g[0][1] = __builtin_amdgcn_mfma_f32_16x16x32_bf16(a0, b1, g[0][1], 0, 0, 0);
        g[1][0] = __builtin_amdgcn_mfma_f32_16x16x32_bf16(a1, b0, g[1][0], 0, 0, 0);
        g[1][1] = __builtin_amdgcn_mfma_f32_16x16x32_bf16(a1, b1, g[1][1], 0, 0, 0);
    }
#pragma unroll
    for (int mi = 0; mi < 2; ++mi)
#pragma unroll
        for (int ni = 0; ni < 2; ++ni)
#pragma unroll
            for (int r = 0; r < 4; ++r) {
                int i = R * 32 + mi * 16 + sg * 4 + r;
                int j = Cq * 32 + ni * 16 + rr;
                float v = (i >= j) ? g[mi][ni][r] * __expf(Sar[i] - Sar[j]) * dtvA[j] : 0.f;
                Gt[swz(i, j * 2)] = f2bf(v);
            }
    // C2 (global) and B~T (LDS, transposed)
#pragma unroll
    for (int half = 0; half < 2; ++half) {
        u16x8 cv = *(const u16x8*)&Ct[swz(row, q * 32 + half * 16)];
        u16x8 ov;
#pragma unroll
        for (int e = 0; e < 8; ++e) ov[e] = f2bf(bf2f(cv[e]) * eSA[row]);
        *(u16x8*)&C2G[(size_t)tau * 4096 + row * 64 + q * 16 + half * 8] = ov;
        u16x8 bv = *(const u16x8*)&Bt[swz(row, q * 32 + half * 16)];
#pragma unroll
        for (int e = 0; e < 8; ++e)
            BTt[swz(q * 16 + half * 8 + e, row * 2)] = f2bf(bf2f(bv[e]) * wA[row]);
    }
    __syncthreads();

    // ---- phase C: Y_intra = G~·X and ΔH = B~T·X ----
    f32x4 y[2][2], dh[2][2];
#pragma unroll
    for (int mi = 0; mi < 2; ++mi)
#pragma unroll
        for (int ni = 0; ni < 2; ++ni)
#pragma unroll
            for (int r = 0; r < 4; ++r) { y[mi][ni][r] = 0.f; dh[mi][ni][r] = 0.f; }
#pragma unroll
    for (int kt = 0; kt < 2; ++kt) {
        int cb = kt * 64 + sg * 16;
        bf16x8 xb0 = *(const bf16x8*)&XT[swz(Cq * 32 + rr, cb)];
        bf16x8 xb1 = *(const bf16x8*)&XT[swz(Cq * 32 + 16 + rr, cb)];
        bf16x8 ga0 = *(const bf16x8*)&Gt[swz(R * 32 + rr, cb)];
        bf16x8 ga1 = *(const bf16x8*)&Gt[swz(R * 32 + 16 + rr, cb)];
        bf16x8 ba0 = *(const bf16x8*)&BTt[swz(R * 32 + rr, cb)];
        bf16x8 ba1 = *(const bf16x8*)&BTt[swz(R * 32 + 16 + rr, cb)];
        y[0][0] = __builtin_amdgcn_mfma_f32_16x16x32_bf16(ga0, xb0, y[0][0], 0, 0, 0);
        y[0][1] = __builtin_amdgcn_mfma_f32_16x16x32_bf16(ga0, xb1, y[0][1], 0, 0, 0);
        y[1][0] = __builtin_amdgcn_mfma_f32_16x16x32_bf16(ga1, xb0, y[1][0], 0, 0, 0);
        y[1][1] = __builtin_amdgcn_mfma_f32_16x16x32_bf16(ga1, xb1, y[1][1], 0, 0, 0);
        dh[0][0] = __builtin_amdgcn_mfma_f32_16x16x32_bf16(ba0, xb0, dh[0][0], 0, 0, 0);
        dh[0][1] = __builtin_amdgcn_mfma_f32_16x16x32_bf16(ba0, xb1, dh[0][1], 0, 0, 0);
        dh[1][0] = __builtin_amdgcn_mfma_f32_16x16x32_bf16(ba1, xb0, dh[1][0], 0, 0, 0);
        dh[1][1] = __builtin_amdgcn_mfma_f32_16x16x32_bf16(ba1, xb1, dh[1][1], 0, 0, 0);
    }
#pragma unroll
    for (int mi = 0; mi < 2; ++mi)
#pragma unroll
        for (int ni = 0; ni < 2; ++ni)
#pragma unroll
            for (int r = 0; r < 4; ++r) {
                int i = R * 32 + mi * 16 + sg * 4 + r;
                int p = Cq * 32 + ni * 16 + rr;
                yraw[(size_t)(t0g + i) * DIN + h * HDD + p] = y[mi][ni][r];
                DHb[(size_t)tau * 4096 + i * 64 + p] = dh[mi][ni][r];
            }
}

// ---------- SSD K2: sequential chunk-state carry ----------
__global__ __launch_bounds__(256) void ssd_carry(const float* __restrict__ DHb,
                                                 const float* __restrict__ DC,
                                                 u16* __restrict__ HPREV) {
    int bid = blockIdx.x;
    int bh = bid >> 1, ph = bid & 1;
    int t = threadIdx.x;
    int s = t >> 2, p0 = ph * 32 + (t & 3) * 8;
    size_t base = (size_t)bh * NCHUNK * 4096 + s * 64 + p0;
    float Hv[8] = {0.f, 0.f, 0.f, 0.f, 0.f, 0.f, 0.f, 0.f};
    for (int c = 0; c < NCHUNK; ++c) {
        size_t off = base + (size_t)c * 4096;
        u16x8 hp;
#pragma unroll
        for (int e = 0; e < 8; ++e) hp[e] = f2bf(Hv[e]);
        *(u16x8*)&HPREV[off] = hp;
        float d = DC[bh * NCHUNK + c];
        float4 d0 = *(const float4*)&DHb[off];
        float4 d1 = *(const float4*)&DHb[off + 4];
        Hv[0] = d * Hv[0] + d0.x; Hv[1] = d * Hv[1] + d0.y;
        Hv[2] = d * Hv[2] + d0.z; Hv[3] = d * Hv[3] + d0.w;
        Hv[4] = d * Hv[4] + d1.x; Hv[5] = d * Hv[5] + d1.y;
        Hv[6] = d * Hv[6] + d1.z; Hv[7] = d * Hv[7] + d1.w;
    }
}

// ---------- SSD K3: Y += C2·Hprev; fuse D·x and z-gate ----------
__global__ __launch_bounds__(256) void ssd_final(const u16* __restrict__ C2G,
                                                 const u16* __restrict__ HPREV,
                                                 const u16* __restrict__ xbc,
                                                 const u16* __restrict__ zx,
                                                 const float* __restrict__ Dp,
                                                 float* __restrict__ yraw) {
    __shared__ u16 C2t[4096], HT[4096];
    int tau = blockIdx.x;
    int b = tau >> 8, h = (tau >> 4) & 15, c = tau & 15;
    int t0g = b * LL + c * QCH;
    int t = threadIdx.x, lane = t & 63, wave = t >> 6;
    int row = t >> 2, q = t & 3;
#pragma unroll
    for (int half = 0; half < 2; ++half) {
        u16x8 cv = *(const u16x8*)&C2G[(size_t)tau * 4096 + row * 64 + q * 16 + half * 8];
        *(u16x8*)&C2t[swz(row, q * 32 + half * 16)] = cv;
        u16x8 hv = *(const u16x8*)&HPREV[(size_t)tau * 4096 + row * 64 + q * 16 + half * 8];
#pragma unroll
        for (int e = 0; e < 8; ++e) HT[swz(q * 16 + half * 8 + e, row * 2)] = hv[e];
    }
    __syncthreads();
    int R = wave >> 1, Cq = wave & 1, rr = lane & 15, sg = lane >> 4;
    float Dh = Dp[h];
    f32x4 acc[2][2];
#pragma unroll
    for (int mi = 0; mi < 2; ++mi)
#pragma unroll
        for (int ni = 0; ni < 2; ++ni)
#pragma unroll
            for (int r = 0; r < 4; ++r) {
                int i = R * 32 + mi * 16 + sg * 4 + r;
                int p = Cq * 32 + ni * 16 + rr;
                acc[mi][ni][r] = yraw[(size_t)(t0g + i) * DIN + h * HDD + p];
            }
#pragma unroll
    for (int kt = 0; kt < 2; ++kt) {
        int cb = kt * 64 + sg * 16;
        bf16x8 a0 = *(const bf16x8*)&C2t[swz(R * 32 + rr, cb)];
        bf16x8 a1 = *(const bf16x8*)&C2t[swz(R * 32 + 16 + rr, cb)];
        bf16x8 b0 = *(const bf16x8*)&HT[swz(Cq * 32 + rr, cb)];
        bf16x8 b1 = *(const bf16x8*)&HT[swz(Cq * 32 + 16 + rr, cb)];
        acc[0][0] = __builtin_amdgcn_mfma_f32_16x16x32_bf16(a0, b0, acc[0][0], 0, 0, 0);
        acc[0][1] = __builtin_amdgcn_mfma_f32_16x16x32_bf16(a0, b1, acc[0][1], 0, 0, 0);
        acc[1][0] = __builtin_amdgcn_mfma_f32_16x16x32_bf16(a1, b0, acc[1][0], 0, 0, 0);
        acc[1][1] = __builtin_amdgcn_mfma_f32_16x16x32_bf16(a1, b1, acc[1][1], 0, 0, 0);
    }
#pragma unroll
    for (int mi = 0; mi < 2; ++mi)
#pragma unroll
        for (int ni = 0; ni < 2; ++ni)
#pragma unroll
            for (int r = 0; r < 4; ++r) {
                int i = R * 32 + mi * 16 + sg * 4 + r;
                int p = Cq * 32 + ni * 16 + rr;
                size_t tok = t0g + i;
                int col = h * HDD + p;
                float xf = bf2f(xbc[tok * DXBC + col]);
                float zf = bf2f(zx[tok * NPADW + col]);
                float yo = (acc[mi][ni][r] + Dh * xf) * (zf / (1.f + __expf(-zf)));
                yraw[tok * DIN + col] = yo;
            }
}

// ---------- RMSNorm over d_inner, write bf16 ----------
__global__ __launch_bounds__(256) void rms_kernel(const float* __restrict__ y,
                                                  const float* __restrict__ w,
                                                  u16* __restrict__ y2) {
    int row = blockIdx.x, t = threadIdx.x;
    const float4 v = *(const float4*)&y[(size_t)row * DIN + t * 4];
    float ss = v.x * v.x + v.y * v.y + v.z * v.z + v.w * v.w;
#pragma unroll
    for (int o = 1; o < 64; o <<= 1) ss += __shfl_xor(ss, o, 64);
    __shared__ float ps[4];
    if ((t & 63) == 0) ps[t >> 6] = ss;
    __syncthreads();
    float tot = ps[0] + ps[1] + ps[2] + ps[3];
    float rs = rsqrtf(tot * (1.f / DIN) + 1e-5f);
    int c = t * 4;
    ushort4 o4;
    o4.x = f2bf(v.x * rs * w[c]);
    o4.y = f2bf(v.y * rs * w[c + 1]);
    o4.z = f2bf(v.z * rs * w[c + 2]);
    o4.w = f2bf(v.w * rs * w[c + 3]);
    *(ushort4*)&y2[(size_t)row * DIN + c] = o4;
}

extern "C" void kernel_launch(void* const* d_in, const int* in_sizes, int n_in,
                              void* d_out, int out_size, void* d_ws, size_t ws_size,
                              hipStream_t stream) {
    const float* x         = (const float*)d_in[0];
    const float* ln_w      = (const float*)d_in[1];
    const float* ln_b      = (const float*)d_in[2];
    const float* in_proj_w = (const float*)d_in[3];
    const float* conv1d_w  = (const float*)d_in[4];
    const float* conv1d_b  = (const float*)d_in[5];
    const float* dt_bias   = (const float*)d_in[6];
    const float* A_log     = (const float*)d_in[7];
    const float* Dp        = (const float*)d_in[8];
    const float* rms_w     = (const float*)d_in[9];
    const float* out_proj_w= (const float*)d_in[10];
    const float* conv2d_w  = (const float*)d_in[11];
    const float* conv2d_b  = (const float*)d_in[12];
    const float* bn_g      = (const float*)d_in[13];
    const float* bn_b      = (const float*)d_in[14];
    const float* bn_mean   = (const float*)d_in[15];
    const float* bn_var    = (const float*)d_in[16];

    const int TOK = NB * LL;  // 8192
    const int NTAU = NB * NHH * NCHUNK;  // 2048
    char* ws = (char*)d_ws;
    size_t off = 0;
    auto alloc = [&](size_t bytes) {
        void* p = ws + off;
        off += (bytes + 255) & ~(size_t)255;
        return p;
    };
    u16*   Win   = (u16*)alloc((size_t)NPADW * CIN * 2);
    u16*   Wout  = (u16*)alloc((size_t)CIN * DIN * 2);
    u16*   Wc2   = (u16*)alloc((size_t)CIN * CIN * 2);
    u16*   XN    = (u16*)alloc((size_t)TOK * CIN * 2);
    u16*   ZX    = (u16*)alloc((size_t)TOK * NPADW * 2);
    u16*   XBC   = (u16*)alloc((size_t)TOK * DXBC * 2);
    float* Bcb   = (float*)alloc((size_t)TOK * DST * 4);
    float* Ccb   = (float*)alloc((size_t)TOK * DST * 4);
    float2* DTDA = (float2*)alloc((size_t)TOK * NHH * 8);
    float* YRAW  = (float*)alloc((size_t)TOK * DIN * 4);
    float* DHb   = (float*)alloc((size_t)NTAU * 4096 * 4);
    u16*   C2G   = (u16*)alloc((size_t)NTAU * 4096 * 2);
    u16*   HPREV = (u16*)alloc((size_t)NTAU * 4096 * 2);
    float* DC    = (float*)alloc((size_t)NTAU * 4);
    u16*   Y2    = (u16*)alloc((size_t)TOK * DIN * 2);
    u16*   OUT1  = (u16*)alloc((size_t)TOK * CIN * 2);
    float* BNSC  = (float*)alloc(CIN * 4);
    float* BNSH  = (float*)alloc(CIN * 4);

    f2bf_pad<<<(NPADW * CIN + 255) / 256, 256, 0, stream>>>(in_proj_w, Win, DPROJ * CIN, NPADW * CIN);
    f2bf_kernel<<<(CIN * DIN + 255) / 256, 256, 0, stream>>>(out_proj_w, Wout, CIN * DIN);
    f2bf_kernel<<<(CIN * CIN + 255) / 256, 256, 0, stream>>>(conv2d_w, Wc2, CIN * CIN);
    bn_prep<<<2, 256, 0, stream>>>(conv2d_b, bn_g, bn_b, bn_mean, bn_var, BNSC, BNSH);

    ln_kernel<<<256, 256, 0, stream>>>(x, ln_w, ln_b, XN);

    gemm_bt<0><<<dim3(NPADW / 128, TOK / 128), 256, 0, stream>>>(XN, Win, ZX, TOK, NPADW, CIN, NPADW,
                                                                 nullptr, nullptr);

    conv1d_silu<<<TOK, 256, 0, stream>>>(ZX, conv1d_w, conv1d_b, XBC, Bcb, Ccb);
    dt_gemv<<<TOK, 256, 0, stream>>>(XN, in_proj_w, dt_bias, A_log, DTDA);

    ssd_chunk<<<NTAU, 256, 0, stream>>>(Bcb, Ccb, XBC, DTDA, YRAW, DHb, C2G, DC);
    ssd_carry<<<256, 256, 0, stream>>>(DHb, DC, HPREV);
    ssd_final<<<NTAU, 256, 0, stream>>>(C2G, HPREV, XBC, ZX, Dp, YRAW);

    rms_kernel<<<TOK, 256, 0, stream>>>(YRAW, rms_w, Y2);

    gemm_bt<0><<<dim3(CIN / 128, TOK / 128), 256, 0, stream>>>(Y2, Wout, OUT1, TOK, CIN, DIN, CIN,
                                                               nullptr, nullptr);

    gemm_bt<1><<<dim3(TOK / 128, CIN / 128), 256, 0, stream>>>(Wc2, OUT1, d_out, CIN, TOK, CIN, 0,
                                                               BNSC, BNSH);
}

// Round 4
// 230.967 us; speedup vs baseline: 3.1623x; 1.0620x over previous
//
#include <hip/hip_runtime.h>
#include <hip/hip_bf16.h>

// Problem constants
#define NB 8
#define LL 1024        // H*W tokens per batch
#define CIN 512
#define DIN 1024       // d_inner
#define DXBC 1152      // d_inner + 2*d_state
#define DPROJ 2192     // actual in_proj rows
#define NPADW 2304     // padded to 18*128 for GEMM tiles
#define NHH 16
#define HDD 64
#define DST 64
#define NCHUNK 16
#define QCH 64         // chunk length

typedef unsigned short u16;
typedef unsigned int u32;
typedef __bf16 bf16x8 __attribute__((ext_vector_type(8)));
typedef float f32x4 __attribute__((ext_vector_type(4)));
typedef u16 u16x8 __attribute__((ext_vector_type(8)));

__device__ __forceinline__ float bf2f(u16 u) {
    u32 x = ((u32)u) << 16; float f; __builtin_memcpy(&f, &x, 4); return f;
}
__device__ __forceinline__ u16 f2bf(float f) {
    u32 x; __builtin_memcpy(&x, &f, 4);
    u32 r = x + 0x7fff + ((x >> 16) & 1);
    return (u16)(r >> 16);
}

__device__ __forceinline__ void gload16(const u16* g, u16* l) {
    __builtin_amdgcn_global_load_lds((__attribute__((address_space(1))) void*)(g),
                                     (__attribute__((address_space(3))) void*)(l), 16, 0, 0);
}

// swizzled u16 index into a [64][64] bf16 LDS tile (128B rows, 16B-slot XOR swizzle)
__device__ __forceinline__ int swz(int row, int cb) {
    return row * 64 + ((cb ^ ((row & 7) << 4)) >> 1);
}

// ---------- weight converts ----------
__global__ void f2bf_kernel(const float* __restrict__ s, u16* __restrict__ d, int n) {
    int i = blockIdx.x * 256 + threadIdx.x;
    if (i < n) d[i] = f2bf(s[i]);
}
__global__ void f2bf_pad(const float* __restrict__ s, u16* __restrict__ d, int nsrc, int ndst) {
    int i = blockIdx.x * 256 + threadIdx.x;
    if (i < ndst) d[i] = (i < nsrc) ? f2bf(s[i]) : (u16)0;
}
__global__ void bn_prep(const float* __restrict__ cb, const float* __restrict__ g,
                        const float* __restrict__ bb, const float* __restrict__ mean,
                        const float* __restrict__ var, float* __restrict__ scale,
                        float* __restrict__ shift) {
    int i = blockIdx.x * 256 + threadIdx.x;
    if (i < CIN) {
        float rs = rsqrtf(var[i] + 1e-5f);
        float sc = g[i] * rs;
        scale[i] = sc;
        shift[i] = (cb[i] - mean[i]) * sc + bb[i];
    }
}

// ---------- LayerNorm over channels + transpose (B,C,HW) -> (tok, C) bf16 ----------
__global__ __launch_bounds__(256) void ln_kernel(const float* __restrict__ x,
                                                 const float* __restrict__ lw,
                                                 const float* __restrict__ lb,
                                                 u16* __restrict__ xn) {
    __shared__ u16 tile[CIN * 33];
    __shared__ float psum[8][32], psq[8][32], muA[32], rsA[32];
    int bid = blockIdx.x;
    int b = bid >> 5, hw0 = (bid & 31) * 32;
    int t = threadIdx.x;
    int hw = t & 31, cg = t >> 5;
    const float* xb = x + (size_t)b * CIN * LL + hw0 + hw;
    float s = 0.f, sq = 0.f;
    for (int r = 0; r < CIN / 8; ++r) {
        int c = r * 8 + cg;
        float v = xb[(size_t)c * LL];
        s += v; sq += v * v;
        tile[c * 33 + hw] = f2bf(v);
    }
    psum[cg][hw] = s; psq[cg][hw] = sq;
    __syncthreads();
    if (t < 32) {
        float ss = 0.f, qq = 0.f;
        for (int g = 0; g < 8; ++g) { ss += psum[g][t]; qq += psq[g][t]; }
        float mu = ss * (1.f / CIN);
        float var = qq * (1.f / CIN) - mu * mu;
        muA[t] = mu; rsA[t] = rsqrtf(var + 1e-5f);
    }
    __syncthreads();
    for (int r = 0; r < 64; ++r) {
        int idx = r * 256 + t;
        int c = idx & (CIN - 1);
        int hh = idx >> 9;
        float v = (bf2f(tile[c * 33 + hh]) - muA[hh]) * rsA[hh] * lw[c] + lb[c];
        xn[((size_t)(b * LL + hw0 + hh)) * CIN + c] = f2bf(v);
    }
}

// ---------- bf16 MFMA GEMM: BK=64, XOR-swizzled LDS (pre-swizzled global source) ----------
template <int EPI>
__global__ __launch_bounds__(256) void gemm_bt(const u16* __restrict__ A, const u16* __restrict__ Bw,
                                               void* __restrict__ Cout, int M, int N, int K, int ldc,
                                               const float* __restrict__ scale,
                                               const float* __restrict__ shift) {
    __shared__ u16 As[128 * 64], Bs[128 * 64];
    int t = threadIdx.x;
    int lane = t & 63, wave = t >> 6;
    int m0 = blockIdx.y * 128, n0 = blockIdx.x * 128;
    int wr = wave >> 1, wc = wave & 1;
    f32x4 acc[4][4];
    for (int m = 0; m < 4; ++m)
        for (int n = 0; n < 4; ++n)
            for (int q = 0; q < 4; ++q) acc[m][n][q] = 0.f;

    const u16* Arow = A + (size_t)m0 * K;
    const u16* Brow = Bw + (size_t)n0 * K;
    int s4 = lane >> 4;   // quarter-wave -> 8-elem k-group
    int rr = lane & 15;
    for (int k0 = 0; k0 < K; k0 += 64) {
        // stage 128x64 tiles; LDS dest linear (wave-uniform + lane*16B), source slot pre-swizzled
#pragma unroll
        for (int j = 0; j < 4; ++j) {
            int e = j * 256 + t;          // 16B-slot id, 8 slots per row
            int r = e >> 3, sr = e & 7;
            int src = (sr ^ (r & 7)) * 8; // inverse (= same) XOR permutation on source
            gload16(Arow + (size_t)r * K + k0 + src, As + e * 8);
            gload16(Brow + (size_t)r * K + k0 + src, Bs + e * 8);
        }
        __syncthreads();
#pragma unroll
        for (int kk = 0; kk < 2; ++kk) {
            bf16x8 af[4], bfr[4];
#pragma unroll
            for (int m = 0; m < 4; ++m) {
                int row = wr * 64 + m * 16 + rr;
                int ss = (kk * 4 + s4) ^ (row & 7);
                af[m] = *(const bf16x8*)&As[row * 64 + ss * 8];
            }
#pragma unroll
            for (int n = 0; n < 4; ++n) {
                int row = wc * 64 + n * 16 + rr;
                int ss = (kk * 4 + s4) ^ (row & 7);
                bfr[n] = *(const bf16x8*)&Bs[row * 64 + ss * 8];
            }
#pragma unroll
            for (int m = 0; m < 4; ++m)
#pragma unroll
                for (int n = 0; n < 4; ++n)
                    acc[m][n] = __builtin_amdgcn_mfma_f32_16x16x32_bf16(af[m], bfr[n], acc[m][n], 0, 0, 0);
        }
        __syncthreads();
    }
    int fq = lane >> 4, fr = lane & 15;
#pragma unroll
    for (int m = 0; m < 4; ++m) {
#pragma unroll
        for (int n = 0; n < 4; ++n) {
            int col = n0 + wc * 64 + n * 16 + fr;
#pragma unroll
            for (int q = 0; q < 4; ++q) {
                int row = m0 + wr * 64 + m * 16 + fq * 4 + q;
                float v = acc[m][n][q];
                if (EPI == 0) {
                    ((u16*)Cout)[(size_t)row * ldc + col] = f2bf(v);
                } else {
                    v = v * scale[row] + shift[row];
                    v = v > 0.f ? v : 0.f;
                    ((float*)Cout)[((size_t)(col >> 10)) * (CIN * LL) + (size_t)row * LL + (col & 1023)] = v;
                }
            }
        }
    }
}

// ---------- depthwise causal conv1d over L + SiLU; also emit B/C as f32 ----------
__global__ __launch_bounds__(256) void conv1d_silu(const u16* __restrict__ zx,
                                                   const float* __restrict__ w,
                                                   const float* __restrict__ bias,
                                                   u16* __restrict__ xbc,
                                                   float* __restrict__ Bc, float* __restrict__ Cc) {
    int tok = blockIdx.x;
    int b = tok >> 10, l = tok & 1023;
    for (int ch = threadIdx.x; ch < DXBC; ch += 256) {
        float acc = bias[ch];
#pragma unroll
        for (int j = 0; j < 4; ++j) {
            int l2 = l - 3 + j;
            if (l2 >= 0) acc += bf2f(zx[((size_t)(b * LL + l2)) * NPADW + DIN + ch]) * w[ch * 4 + j];
        }
        float sv = acc / (1.f + __expf(-acc));
        xbc[(size_t)tok * DXBC + ch] = f2bf(sv);
        int s = ch - DIN;
        if (s >= 0) {
            if (s < DST) Bc[(size_t)tok * DST + s] = sv;
            else Cc[(size_t)tok * DST + (s - DST)] = sv;
        }
    }
}

// ---------- dt GEMV: compute dtv = softplus(dt+bias), a = dtv*(-exp(A_log)) ----------
__global__ __launch_bounds__(256) void dt_gemv(const u16* __restrict__ xn,
                                               const float* __restrict__ wproj,
                                               const float* __restrict__ dt_bias,
                                               const float* __restrict__ A_log,
                                               float2* __restrict__ dtda) {
    int tok = blockIdx.x;
    int t = threadIdx.x;
    int h = t >> 4, part = t & 15;
    const u16* xr = xn + (size_t)tok * CIN;
    const float* wr = wproj + (size_t)(DIN + DXBC + h) * CIN;
    float s = 0.f;
    for (int c0 = part * 32; c0 < part * 32 + 32; c0 += 8) {
        u16x8 xv = *(const u16x8*)&xr[c0];
        float4 w0 = *(const float4*)&wr[c0];
        float4 w1 = *(const float4*)&wr[c0 + 4];
        s += bf2f(xv[0]) * w0.x + bf2f(xv[1]) * w0.y + bf2f(xv[2]) * w0.z + bf2f(xv[3]) * w0.w;
        s += bf2f(xv[4]) * w1.x + bf2f(xv[5]) * w1.y + bf2f(xv[6]) * w1.z + bf2f(xv[7]) * w1.w;
    }
    s += __shfl_xor(s, 1, 64);
    s += __shfl_xor(s, 2, 64);
    s += __shfl_xor(s, 4, 64);
    s += __shfl_xor(s, 8, 64);
    if (part == 0) {
        float si = s + dt_bias[h];
        float dtv = si > 15.f ? si : __logf(1.f + __expf(si));
        float An = -__expf(A_log[h]);
        float2 dd; dd.x = dtv; dd.y = dtv * An;
        dtda[(size_t)tok * NHH + h] = dd;
    }
}

// ---------- SSD K1: per-(b,h,chunk) — G̃, Y_intra(bf16), ΔH(bf16), C2, d_c ----------
__global__ __launch_bounds__(256) void ssd_chunk(const float* __restrict__ Bcb,
                                                 const float* __restrict__ Ccb,
                                                 const u16* __restrict__ xbc,
                                                 const float2* __restrict__ dtda,
                                                 u16* __restrict__ yi,
                                                 u16* __restrict__ DHb,
                                                 u16* __restrict__ C2G,
                                                 float* __restrict__ DC) {
    __shared__ u16 Bt[4096], Ct[4096], XT[4096], BTt[4096], Gt[4096];
    __shared__ float Sar[64], dtvA[64], wA[64], eSA[64];
    int tau = blockIdx.x;
    int b = tau >> 8, h = (tau >> 4) & 15, c = tau & 15;
    int t0g = b * LL + c * QCH;
    int t = threadIdx.x, lane = t & 63, wave = t >> 6;
    int row = t >> 2, q = t & 3;

    // ---- phase A: stage B, C (fp32->bf16), X (transposed), dt scan ----
    {
        const float* bp = Bcb + (size_t)(t0g + row) * DST + q * 16;
        const float* cp = Ccb + (size_t)(t0g + row) * DST + q * 16;
#pragma unroll
        for (int half = 0; half < 2; ++half) {
            float4 v0 = *(const float4*)(bp + half * 8);
            float4 v1 = *(const float4*)(bp + half * 8 + 4);
            u16x8 o;
            o[0] = f2bf(v0.x); o[1] = f2bf(v0.y); o[2] = f2bf(v0.z); o[3] = f2bf(v0.w);
            o[4] = f2bf(v1.x); o[5] = f2bf(v1.y); o[6] = f2bf(v1.z); o[7] = f2bf(v1.w);
            *(u16x8*)&Bt[swz(row, q * 32 + half * 16)] = o;
            float4 c0 = *(const float4*)(cp + half * 8);
            float4 c1 = *(const float4*)(cp + half * 8 + 4);
            u16x8 oc;
            oc[0] = f2bf(c0.x); oc[1] = f2bf(c0.y); oc[2] = f2bf(c0.z); oc[3] = f2bf(c0.w);
            oc[4] = f2bf(c1.x); oc[5] = f2bf(c1.y); oc[6] = f2bf(c1.z); oc[7] = f2bf(c1.w);
            *(u16x8*)&Ct[swz(row, q * 32 + half * 16)] = oc;
        }
        const u16* xp = xbc + (size_t)(t0g + row) * DXBC + h * HDD + q * 16;
        u16x8 x0 = *(const u16x8*)xp;
        u16x8 x1 = *(const u16x8*)(xp + 8);
#pragma unroll
        for (int e = 0; e < 8; ++e) XT[swz(q * 16 + e, row * 2)] = x0[e];
#pragma unroll
        for (int e = 0; e < 8; ++e) XT[swz(q * 16 + 8 + e, row * 2)] = x1[e];
    }
    if (t < 64) {
        float2 dd = dtda[(size_t)(t0g + t) * NHH + h];
        float s = dd.y;  // a_t
#pragma unroll
        for (int off = 1; off < 64; off <<= 1) {
            float u = __shfl_up(s, off, 64);
            if (t >= off) s += u;
        }
        float SQ = __shfl(s, 63, 64);
        Sar[t] = s; dtvA[t] = dd.x;
        wA[t] = __expf(SQ - s) * dd.x;
        eSA[t] = __expf(s);
        if (t == 0) DC[tau] = __expf(SQ);
    }
    __syncthreads();

    int R = wave >> 1, Cq = wave & 1, rr = lane & 15, sg = lane >> 4;
    // ---- phase B: G = C·B^T, scale/mask -> Gt; also C2 + B~T ----
    f32x4 g[2][2];
#pragma unroll
    for (int mi = 0; mi < 2; ++mi)
#pragma unroll
        for (int ni = 0; ni < 2; ++ni)
#pragma unroll
            for (int r = 0; r < 4; ++r) g[mi][ni][r] = 0.f;
#pragma unroll
    for (int kt = 0; kt < 2; ++kt) {
        int cb = kt * 64 + sg * 16;
        bf16x8 a0 = *(const bf16x8*)&Ct[swz(R * 32 + rr, cb)];
        bf16x8 a1 = *(const bf16x8*)&Ct[swz(R * 32 + 16 + rr, cb)];
        bf16x8 b0 = *(const bf16x8*)&Bt[swz(Cq * 32 + rr, cb)];
        bf16x8 b1 = *(const bf16x8*)&Bt[swz(Cq * 32 + 16 + rr, cb)];
        g[0][0] = __builtin_amdgcn_mfma_f32_16x16x32_bf16(a0, b0, g[0][0], 0, 0, 0);
        g[0][1] = __builtin_amdgcn_mfma_f32_16x16x32_bf16(a0, b1, g[0][1], 0, 0, 0);
        g[1][0] = __builtin_amdgcn_mfma_f32_16x16x32_bf16(a1, b0, g[1][0], 0, 0, 0);
        g[1][1] = __builtin_amdgcn_mfma_f32_16x16x32_bf16(a1, b1, g[1][1], 0, 0, 0);
    }
#pragma unroll
    for (int mi = 0; mi < 2; ++mi)
#pragma unroll
        for (int ni = 0; ni < 2; ++ni)
#pragma unroll
            for (int r = 0; r < 4; ++r) {
                int i = R * 32 + mi * 16 + sg * 4 + r;
                int j = Cq * 32 + ni * 16 + rr;
                float v = (i >= j) ? g[mi][ni][r] * __expf(Sar[i] - Sar[j]) * dtvA[j] : 0.f;
                Gt[swz(i, j * 2)] = f2bf(v);
            }
    // C2 (global) and B~T (LDS, transposed)
#pragma unroll
    for (int half = 0; half < 2; ++half) {
        u16x8 cv = *(const u16x8*)&Ct[swz(row, q * 32 + half * 16)];
        u16x8 ov;
#pragma unroll
        for (int e = 0; e < 8; ++e) ov[e] = f2bf(bf2f(cv[e]) * eSA[row]);
        *(u16x8*)&C2G[(size_t)tau * 4096 + row * 64 + q * 16 + half * 8] = ov;
        u16x8 bv = *(const u16x8*)&Bt[swz(row, q * 32 + half * 16)];
#pragma unroll
        for (int e = 0; e < 8; ++e)
            BTt[swz(q * 16 + half * 8 + e, row * 2)] = f2bf(bf2f(bv[e]) * wA[row]);
    }
    __syncthreads();

    // ---- phase C: Y_intra = G~·X and ΔH = B~T·X ----
    f32x4 y[2][2], dh[2][2];
#pragma unroll
    for (int mi = 0; mi < 2; ++mi)
#pragma unroll
        for (int ni = 0; ni < 2; ++ni)
#pragma unroll
            for (int r = 0; r < 4; ++r) { y[mi][ni][r] = 0.f; dh[mi][ni][r] = 0.f; }
#pragma unroll
    for (int kt = 0; kt < 2; ++kt) {
        int cb = kt * 64 + sg * 16;
        bf16x8 xb0 = *(const bf16x8*)&XT[swz(Cq * 32 + rr, cb)];
        bf16x8 xb1 = *(const bf16x8*)&XT[swz(Cq * 32 + 16 + rr, cb)];
        bf16x8 ga0 = *(const bf16x8*)&Gt[swz(R * 32 + rr, cb)];
        bf16x8 ga1 = *(const bf16x8*)&Gt[swz(R * 32 + 16 + rr, cb)];
        bf16x8 ba0 = *(const bf16x8*)&BTt[swz(R * 32 + rr, cb)];
        bf16x8 ba1 = *(const bf16x8*)&BTt[swz(R * 32 + 16 + rr, cb)];
        y[0][0] = __builtin_amdgcn_mfma_f32_16x16x32_bf16(ga0, xb0, y[0][0], 0, 0, 0);
        y[0][1] = __builtin_amdgcn_mfma_f32_16x16x32_bf16(ga0, xb1, y[0][1], 0, 0, 0);
        y[1][0] = __builtin_amdgcn_mfma_f32_16x16x32_bf16(ga1, xb0, y[1][0], 0, 0, 0);
        y[1][1] = __builtin_amdgcn_mfma_f32_16x16x32_bf16(ga1, xb1, y[1][1], 0, 0, 0);
        dh[0][0] = __builtin_amdgcn_mfma_f32_16x16x32_bf16(ba0, xb0, dh[0][0], 0, 0, 0);
        dh[0][1] = __builtin_amdgcn_mfma_f32_16x16x32_bf16(ba0, xb1, dh[0][1], 0, 0, 0);
        dh[1][0] = __builtin_amdgcn_mfma_f32_16x16x32_bf16(ba1, xb0, dh[1][0], 0, 0, 0);
        dh[1][1] = __builtin_amdgcn_mfma_f32_16x16x32_bf16(ba1, xb1, dh[1][1], 0, 0, 0);
    }
#pragma unroll
    for (int mi = 0; mi < 2; ++mi)
#pragma unroll
        for (int ni = 0; ni < 2; ++ni)
#pragma unroll
            for (int r = 0; r < 4; ++r) {
                int i = R * 32 + mi * 16 + sg * 4 + r;
                int p = Cq * 32 + ni * 16 + rr;
                yi[(size_t)(t0g + i) * DIN + h * HDD + p] = f2bf(y[mi][ni][r]);
                DHb[(size_t)tau * 4096 + i * 64 + p] = f2bf(dh[mi][ni][r]);
            }
}

// ---------- SSD K2: sequential chunk-state carry ----------
__global__ __launch_bounds__(256) void ssd_carry(const u16* __restrict__ DHb,
                                                 const float* __restrict__ DC,
                                                 u16* __restrict__ HPREV) {
    int bid = blockIdx.x;
    int bh = bid >> 1, ph = bid & 1;
    int t = threadIdx.x;
    int s = t >> 2, p0 = ph * 32 + (t & 3) * 8;
    size_t base = (size_t)bh * NCHUNK * 4096 + s * 64 + p0;
    float Hv[8] = {0.f, 0.f, 0.f, 0.f, 0.f, 0.f, 0.f, 0.f};
    for (int c = 0; c < NCHUNK; ++c) {
        size_t off = base + (size_t)c * 4096;
        u16x8 hp;
#pragma unroll
        for (int e = 0; e < 8; ++e) hp[e] = f2bf(Hv[e]);
        *(u16x8*)&HPREV[off] = hp;
        float d = DC[bh * NCHUNK + c];
        u16x8 dv = *(const u16x8*)&DHb[off];
#pragma unroll
        for (int e = 0; e < 8; ++e) Hv[e] = d * Hv[e] + bf2f(dv[e]);
    }
}

// ---------- SSD K3: Y = Y_intra + C2·Hprev; fuse D·x and z-gate; in-place into yi ----------
__global__ __launch_bounds__(256) void ssd_final(const u16* __restrict__ C2G,
                                                 const u16* __restrict__ HPREV,
                                                 const u16* __restrict__ xbc,
                                                 const u16* __restrict__ zx,
                                                 const float* __restrict__ Dp,
                                                 u16* __restrict__ yi) {
    __shared__ u16 C2t[4096], HT[4096];
    int tau = blockIdx.x;
    int b = tau >> 8, h = (tau >> 4) & 15, c = tau & 15;
    int t0g = b * LL + c * QCH;
    int t = threadIdx.x, lane = t & 63, wave = t >> 6;
    int row = t >> 2, q = t & 3;
#pragma unroll
    for (int half = 0; half < 2; ++half) {
        u16x8 cv = *(const u16x8*)&C2G[(size_t)tau * 4096 + row * 64 + q * 16 + half * 8];
        *(u16x8*)&C2t[swz(row, q * 32 + half * 16)] = cv;
        u16x8 hv = *(const u16x8*)&HPREV[(size_t)tau * 4096 + row * 64 + q * 16 + half * 8];
#pragma unroll
        for (int e = 0; e < 8; ++e) HT[swz(q * 16 + half * 8 + e, row * 2)] = hv[e];
    }
    __syncthreads();
    int R = wave >> 1, Cq = wave & 1, rr = lane & 15, sg = lane >> 4;
    float Dh = Dp[h];
    f32x4 acc[2][2];
#pragma unroll
    for (int mi = 0; mi < 2; ++mi)
#pragma unroll
        for (int ni = 0; ni < 2; ++ni)
#pragma unroll
            for (int r = 0; r < 4; ++r) {
                int i = R * 32 + mi * 16 + sg * 4 + r;
                int p = Cq * 32 + ni * 16 + rr;
                acc[mi][ni][r] = bf2f(yi[(size_t)(t0g + i) * DIN + h * HDD + p]);
            }
#pragma unroll
    for (int kt = 0; kt < 2; ++kt) {
        int cb = kt * 64 + sg * 16;
        bf16x8 a0 = *(const bf16x8*)&C2t[swz(R * 32 + rr, cb)];
        bf16x8 a1 = *(const bf16x8*)&C2t[swz(R * 32 + 16 + rr, cb)];
        bf16x8 b0 = *(const bf16x8*)&HT[swz(Cq * 32 + rr, cb)];
        bf16x8 b1 = *(const bf16x8*)&HT[swz(Cq * 32 + 16 + rr, cb)];
        acc[0][0] = __builtin_amdgcn_mfma_f32_16x16x32_bf16(a0, b0, acc[0][0], 0, 0, 0);
        acc[0][1] = __builtin_amdgcn_mfma_f32_16x16x32_bf16(a0, b1, acc[0][1], 0, 0, 0);
        acc[1][0] = __builtin_amdgcn_mfma_f32_16x16x32_bf16(a1, b0, acc[1][0], 0, 0, 0);
        acc[1][1] = __builtin_amdgcn_mfma_f32_16x16x32_bf16(a1, b1, acc[1][1], 0, 0, 0);
    }
#pragma unroll
    for (int mi = 0; mi < 2; ++mi)
#pragma unroll
        for (int ni = 0; ni < 2; ++ni)
#pragma unroll
            for (int r = 0; r < 4; ++r) {
                int i = R * 32 + mi * 16 + sg * 4 + r;
                int p = Cq * 32 + ni * 16 + rr;
                size_t tok = t0g + i;
                int col = h * HDD + p;
                float xf = bf2f(xbc[tok * DXBC + col]);
                float zf = bf2f(zx[tok * NPADW + col]);
                float yo = (acc[mi][ni][r] + Dh * xf) * (zf / (1.f + __expf(-zf)));
                yi[tok * DIN + col] = f2bf(yo);
            }
}

// ---------- RMSNorm over d_inner (bf16 in), write bf16 ----------
__global__ __launch_bounds__(256) void rms_kernel(const u16* __restrict__ y,
                                                  const float* __restrict__ w,
                                                  u16* __restrict__ y2) {
    int row = blockIdx.x, t = threadIdx.x;
    ushort4 uv = *(const ushort4*)&y[(size_t)row * DIN + t * 4];
    float v0 = bf2f(uv.x), v1 = bf2f(uv.y), v2 = bf2f(uv.z), v3 = bf2f(uv.w);
    float ss = v0 * v0 + v1 * v1 + v2 * v2 + v3 * v3;
#pragma unroll
    for (int o = 1; o < 64; o <<= 1) ss += __shfl_xor(ss, o, 64);
    __shared__ float ps[4];
    if ((t & 63) == 0) ps[t >> 6] = ss;
    __syncthreads();
    float tot = ps[0] + ps[1] + ps[2] + ps[3];
    float rs = rsqrtf(tot * (1.f / DIN) + 1e-5f);
    int c = t * 4;
    ushort4 o4;
    o4.x = f2bf(v0 * rs * w[c]);
    o4.y = f2bf(v1 * rs * w[c + 1]);
    o4.z = f2bf(v2 * rs * w[c + 2]);
    o4.w = f2bf(v3 * rs * w[c + 3]);
    *(ushort4*)&y2[(size_t)row * DIN + c] = o4;
}

extern "C" void kernel_launch(void* const* d_in, const int* in_sizes, int n_in,
                              void* d_out, int out_size, void* d_ws, size_t ws_size,
                              hipStream_t stream) {
    const float* x         = (const float*)d_in[0];
    const float* ln_w      = (const float*)d_in[1];
    const float* ln_b      = (const float*)d_in[2];
    const float* in_proj_w = (const float*)d_in[3];
    const float* conv1d_w  = (const float*)d_in[4];
    const float* conv1d_b  = (const float*)d_in[5];
    const float* dt_bias   = (const float*)d_in[6];
    const float* A_log     = (const float*)d_in[7];
    const float* Dp        = (const float*)d_in[8];
    const float* rms_w     = (const float*)d_in[9];
    const float* out_proj_w= (const float*)d_in[10];
    const float* conv2d_w  = (const float*)d_in[11];
    const float* conv2d_b  = (const float*)d_in[12];
    const float* bn_g      = (const float*)d_in[13];
    const float* bn_b      = (const float*)d_in[14];
    const float* bn_mean   = (const float*)d_in[15];
    const float* bn_var    = (const float*)d_in[16];

    const int TOK = NB * LL;  // 8192
    const int NTAU = NB * NHH * NCHUNK;  // 2048
    char* ws = (char*)d_ws;
    size_t off = 0;
    auto alloc = [&](size_t bytes) {
        void* p = ws + off;
        off += (bytes + 255) & ~(size_t)255;
        return p;
    };
    u16*   Win   = (u16*)alloc((size_t)NPADW * CIN * 2);
    u16*   Wout  = (u16*)alloc((size_t)CIN * DIN * 2);
    u16*   Wc2   = (u16*)alloc((size_t)CIN * CIN * 2);
    u16*   XN    = (u16*)alloc((size_t)TOK * CIN * 2);
    u16*   ZX    = (u16*)alloc((size_t)TOK * NPADW * 2);
    u16*   XBC   = (u16*)alloc((size_t)TOK * DXBC * 2);
    float* Bcb   = (float*)alloc((size_t)TOK * DST * 4);
    float* Ccb   = (float*)alloc((size_t)TOK * DST * 4);
    float2* DTDA = (float2*)alloc((size_t)TOK * NHH * 8);
    u16*   YI    = (u16*)alloc((size_t)TOK * DIN * 2);
    u16*   DHb   = (u16*)alloc((size_t)NTAU * 4096 * 2);
    u16*   C2G   = (u16*)alloc((size_t)NTAU * 4096 * 2);
    u16*   HPREV = (u16*)alloc((size_t)NTAU * 4096 * 2);
    float* DC    = (float*)alloc((size_t)NTAU * 4);
    u16*   Y2    = (u16*)alloc((size_t)TOK * DIN * 2);
    u16*   OUT1  = (u16*)alloc((size_t)TOK * CIN * 2);
    float* BNSC  = (float*)alloc(CIN * 4);
    float* BNSH  = (float*)alloc(CIN * 4);

    f2bf_pad<<<(NPADW * CIN + 255) / 256, 256, 0, stream>>>(in_proj_w, Win, DPROJ * CIN, NPADW * CIN);
    f2bf_kernel<<<(CIN * DIN + 255) / 256, 256, 0, stream>>>(out_proj_w, Wout, CIN * DIN);
    f2bf_kernel<<<(CIN * CIN + 255) / 256, 256, 0, stream>>>(conv2d_w, Wc2, CIN * CIN);
    bn_prep<<<2, 256, 0, stream>>>(conv2d_b, bn_g, bn_b, bn_mean, bn_var, BNSC, BNSH);

    ln_kernel<<<256, 256, 0, stream>>>(x, ln_w, ln_b, XN);

    gemm_bt<0><<<dim3(NPADW / 128, TOK / 128), 256, 0, stream>>>(XN, Win, ZX, TOK, NPADW, CIN, NPADW,
                                                                 nullptr, nullptr);

    conv1d_silu<<<TOK, 256, 0, stream>>>(ZX, conv1d_w, conv1d_b, XBC, Bcb, Ccb);
    dt_gemv<<<TOK, 256, 0, stream>>>(XN, in_proj_w, dt_bias, A_log, DTDA);

    ssd_chunk<<<NTAU, 256, 0, stream>>>(Bcb, Ccb, XBC, DTDA, YI, DHb, C2G, DC);
    ssd_carry<<<256, 256, 0, stream>>>(DHb, DC, HPREV);
    ssd_final<<<NTAU, 256, 0, stream>>>(C2G, HPREV, XBC, ZX, Dp, YI);

    rms_kernel<<<TOK, 256, 0, stream>>>(YI, rms_w, Y2);

    gemm_bt<0><<<dim3(CIN / 128, TOK / 128), 256, 0, stream>>>(Y2, Wout, OUT1, TOK, CIN, DIN, CIN,
                                                               nullptr, nullptr);

    gemm_bt<1><<<dim3(TOK / 128, CIN / 128), 256, 0, stream>>>(Wc2, OUT1, d_out, CIN, TOK, CIN, 0,
                                                               BNSC, BNSH);
}

// Round 5
// 206.993 us; speedup vs baseline: 3.5286x; 1.1158x over previous
//
#include <hip/hip_runtime.h>
#include <hip/hip_bf16.h>

// Problem constants
#define NB 8
#define LL 1024        // H*W tokens per batch
#define CIN 512
#define DIN 1024       // d_inner
#define DXBC 1152      // d_inner + 2*d_state
#define DPROJ 2192     // actual in_proj rows
#define NPADW 2304     // padded to 18*128 for GEMM tiles
#define NHH 16
#define HDD 64
#define DST 64
#define NCHUNK 16
#define QCH 64         // chunk length
#define XBCS 1024      // XBC stored stride (x-part only; B/C never re-read from it)
#define CTT 32         // conv tokens per block

typedef unsigned short u16;
typedef unsigned int u32;
typedef __bf16 bf16x8 __attribute__((ext_vector_type(8)));
typedef float f32x4 __attribute__((ext_vector_type(4)));
typedef u16 u16x8 __attribute__((ext_vector_type(8)));

__device__ __forceinline__ float bf2f(u16 u) {
    u32 x = ((u32)u) << 16; float f; __builtin_memcpy(&f, &x, 4); return f;
}
__device__ __forceinline__ u16 f2bf(float f) {
    u32 x; __builtin_memcpy(&x, &f, 4);
    u32 r = x + 0x7fff + ((x >> 16) & 1);
    return (u16)(r >> 16);
}

__device__ __forceinline__ void gload16(const u16* g, u16* l) {
    __builtin_amdgcn_global_load_lds((__attribute__((address_space(1))) void*)(g),
                                     (__attribute__((address_space(3))) void*)(l), 16, 0, 0);
}

// swizzled u16 index into a [64][64] bf16 LDS tile (128B rows, 16B-slot XOR swizzle)
__device__ __forceinline__ int swz(int row, int cb) {
    return row * 64 + ((cb ^ ((row & 7) << 4)) >> 1);
}

// ---------- weight converts ----------
__global__ void f2bf_kernel(const float* __restrict__ s, u16* __restrict__ d, int n) {
    int i = blockIdx.x * 256 + threadIdx.x;
    if (i < n) d[i] = f2bf(s[i]);
}
__global__ void f2bf_pad(const float* __restrict__ s, u16* __restrict__ d, int nsrc, int ndst) {
    int i = blockIdx.x * 256 + threadIdx.x;
    if (i < ndst) d[i] = (i < nsrc) ? f2bf(s[i]) : (u16)0;
}
__global__ void bn_prep(const float* __restrict__ cb, const float* __restrict__ g,
                        const float* __restrict__ bb, const float* __restrict__ mean,
                        const float* __restrict__ var, float* __restrict__ scale,
                        float* __restrict__ shift) {
    int i = blockIdx.x * 256 + threadIdx.x;
    if (i < CIN) {
        float rs = rsqrtf(var[i] + 1e-5f);
        float sc = g[i] * rs;
        scale[i] = sc;
        shift[i] = (cb[i] - mean[i]) * sc + bb[i];
    }
}

// ---------- LayerNorm over channels + transpose (B,C,HW) -> (tok, C) bf16 ----------
__global__ __launch_bounds__(256) void ln_kernel(const float* __restrict__ x,
                                                 const float* __restrict__ lw,
                                                 const float* __restrict__ lb,
                                                 u16* __restrict__ xn) {
    __shared__ u16 tile[CIN * 33];
    __shared__ float psum[8][32], psq[8][32], muA[32], rsA[32];
    int bid = blockIdx.x;
    int b = bid >> 5, hw0 = (bid & 31) * 32;
    int t = threadIdx.x;
    int hw = t & 31, cg = t >> 5;
    const float* xb = x + (size_t)b * CIN * LL + hw0 + hw;
    float s = 0.f, sq = 0.f;
    for (int r = 0; r < CIN / 8; ++r) {
        int c = r * 8 + cg;
        float v = xb[(size_t)c * LL];
        s += v; sq += v * v;
        tile[c * 33 + hw] = f2bf(v);
    }
    psum[cg][hw] = s; psq[cg][hw] = sq;
    __syncthreads();
    if (t < 32) {
        float ss = 0.f, qq = 0.f;
        for (int g = 0; g < 8; ++g) { ss += psum[g][t]; qq += psq[g][t]; }
        float mu = ss * (1.f / CIN);
        float var = qq * (1.f / CIN) - mu * mu;
        muA[t] = mu; rsA[t] = rsqrtf(var + 1e-5f);
    }
    __syncthreads();
    for (int r = 0; r < 64; ++r) {
        int idx = r * 256 + t;
        int c = idx & (CIN - 1);
        int hh = idx >> 9;
        float v = (bf2f(tile[c * 33 + hh]) - muA[hh]) * rsA[hh] * lw[c] + lb[c];
        xn[((size_t)(b * LL + hw0 + hh)) * CIN + c] = f2bf(v);
    }
}

// ---------- bf16 MFMA GEMM: BK=64, XOR-swizzled LDS (pre-swizzled global source) ----------
template <int EPI>
__global__ __launch_bounds__(256) void gemm_bt(const u16* __restrict__ A, const u16* __restrict__ Bw,
                                               void* __restrict__ Cout, int M, int N, int K, int ldc,
                                               const float* __restrict__ scale,
                                               const float* __restrict__ shift) {
    __shared__ u16 As[128 * 64], Bs[128 * 64];
    int t = threadIdx.x;
    int lane = t & 63, wave = t >> 6;
    int m0 = blockIdx.y * 128, n0 = blockIdx.x * 128;
    int wr = wave >> 1, wc = wave & 1;
    f32x4 acc[4][4];
    for (int m = 0; m < 4; ++m)
        for (int n = 0; n < 4; ++n)
            for (int q = 0; q < 4; ++q) acc[m][n][q] = 0.f;

    const u16* Arow = A + (size_t)m0 * K;
    const u16* Brow = Bw + (size_t)n0 * K;
    int s4 = lane >> 4;   // quarter-wave -> 8-elem k-group
    int rr = lane & 15;
    for (int k0 = 0; k0 < K; k0 += 64) {
#pragma unroll
        for (int j = 0; j < 4; ++j) {
            int e = j * 256 + t;          // 16B-slot id, 8 slots per row
            int r = e >> 3, sr = e & 7;
            int src = (sr ^ (r & 7)) * 8; // inverse (= same) XOR permutation on source
            gload16(Arow + (size_t)r * K + k0 + src, As + e * 8);
            gload16(Brow + (size_t)r * K + k0 + src, Bs + e * 8);
        }
        __syncthreads();
#pragma unroll
        for (int kk = 0; kk < 2; ++kk) {
            bf16x8 af[4], bfr[4];
#pragma unroll
            for (int m = 0; m < 4; ++m) {
                int row = wr * 64 + m * 16 + rr;
                int ss = (kk * 4 + s4) ^ (row & 7);
                af[m] = *(const bf16x8*)&As[row * 64 + ss * 8];
            }
#pragma unroll
            for (int n = 0; n < 4; ++n) {
                int row = wc * 64 + n * 16 + rr;
                int ss = (kk * 4 + s4) ^ (row & 7);
                bfr[n] = *(const bf16x8*)&Bs[row * 64 + ss * 8];
            }
#pragma unroll
            for (int m = 0; m < 4; ++m)
#pragma unroll
                for (int n = 0; n < 4; ++n)
                    acc[m][n] = __builtin_amdgcn_mfma_f32_16x16x32_bf16(af[m], bfr[n], acc[m][n], 0, 0, 0);
        }
        __syncthreads();
    }
    int fq = lane >> 4, fr = lane & 15;
#pragma unroll
    for (int m = 0; m < 4; ++m) {
#pragma unroll
        for (int n = 0; n < 4; ++n) {
            int col = n0 + wc * 64 + n * 16 + fr;
#pragma unroll
            for (int q = 0; q < 4; ++q) {
                int row = m0 + wr * 64 + m * 16 + fq * 4 + q;
                float v = acc[m][n][q];
                if (EPI == 0) {
                    ((u16*)Cout)[(size_t)row * ldc + col] = f2bf(v);
                } else {
                    v = v * scale[row] + shift[row];
                    v = v > 0.f ? v : 0.f;
                    ((float*)Cout)[((size_t)(col >> 10)) * (CIN * LL) + (size_t)row * LL + (col & 1023)] = v;
                }
            }
        }
    }
}

// ---------- depthwise causal conv1d + SiLU, register sliding window ----------
// grid: NB * (LL/CTT) blocks; 288 threads.
// threads 0..255: x-part, 4 ch each (ushort4).  threads 256..287: B/C part, 4 ch each.
__global__ __launch_bounds__(288) void conv1d_fused(const u16* __restrict__ zx,
                                                    const float* __restrict__ w,
                                                    const float* __restrict__ bias,
                                                    u16* __restrict__ xbc,
                                                    float* __restrict__ Bc, float* __restrict__ Cc) {
    int bid = blockIdx.x;
    int b = bid >> 5;            // LL/CTT = 32 strips per batch
    int l0 = (bid & 31) * CTT;
    int t = threadIdx.x;
    bool isX = t < 256;
    int ch = isX ? t * 4 : 1024 + (t - 256) * 4;   // channel within xBC slice

    // per-channel weights and bias
    float4 wv0 = *(const float4*)&w[(ch + 0) * 4];
    float4 wv1 = *(const float4*)&w[(ch + 1) * 4];
    float4 wv2 = *(const float4*)&w[(ch + 2) * 4];
    float4 wv3 = *(const float4*)&w[(ch + 3) * 4];
    float4 bv = *(const float4*)&bias[ch];

    // load all input rows for this strip (3 halo + CTT)
    ushort4 xin[CTT + 3];
    const u16* src = zx + (size_t)(b * LL + l0 - 3) * NPADW + DIN + ch;
#pragma unroll
    for (int i = 0; i < CTT + 3; ++i) {
        ushort4 v = {0, 0, 0, 0};
        if (l0 + i - 3 >= 0) v = *(const ushort4*)(src + (size_t)i * NPADW);
        xin[i] = v;
    }
#pragma unroll
    for (int i = 0; i < CTT; ++i) {
        int tok = b * LL + l0 + i;
        float a0 = bv.x + bf2f(xin[i].x) * wv0.x + bf2f(xin[i + 1].x) * wv0.y +
                   bf2f(xin[i + 2].x) * wv0.z + bf2f(xin[i + 3].x) * wv0.w;
        float a1 = bv.y + bf2f(xin[i].y) * wv1.x + bf2f(xin[i + 1].y) * wv1.y +
                   bf2f(xin[i + 2].y) * wv1.z + bf2f(xin[i + 3].y) * wv1.w;
        float a2 = bv.z + bf2f(xin[i].z) * wv2.x + bf2f(xin[i + 1].z) * wv2.y +
                   bf2f(xin[i + 2].z) * wv2.z + bf2f(xin[i + 3].z) * wv2.w;
        float a3 = bv.w + bf2f(xin[i].w) * wv3.x + bf2f(xin[i + 1].w) * wv3.y +
                   bf2f(xin[i + 2].w) * wv3.z + bf2f(xin[i + 3].w) * wv3.w;
        float s0 = a0 / (1.f + __expf(-a0));
        float s1 = a1 / (1.f + __expf(-a1));
        float s2 = a2 / (1.f + __expf(-a2));
        float s3 = a3 / (1.f + __expf(-a3));
        if (isX) {
            ushort4 o;
            o.x = f2bf(s0); o.y = f2bf(s1); o.z = f2bf(s2); o.w = f2bf(s3);
            *(ushort4*)&xbc[(size_t)tok * XBCS + ch] = o;
        } else {
            int s = ch - 1024;   // 0..124
            float4 o4; o4.x = s0; o4.y = s1; o4.z = s2; o4.w = s3;
            if (s < DST) *(float4*)&Bc[(size_t)tok * DST + s] = o4;
            else         *(float4*)&Cc[(size_t)tok * DST + (s - DST)] = o4;
        }
    }
}

// ---------- dt GEMV: compute dtv = softplus(dt+bias), a = dtv*(-exp(A_log)) ----------
__global__ __launch_bounds__(256) void dt_gemv(const u16* __restrict__ xn,
                                               const float* __restrict__ wproj,
                                               const float* __restrict__ dt_bias,
                                               const float* __restrict__ A_log,
                                               float2* __restrict__ dtda) {
    int tok = blockIdx.x;
    int t = threadIdx.x;
    int h = t >> 4, part = t & 15;
    const u16* xr = xn + (size_t)tok * CIN;
    const float* wr = wproj + (size_t)(DIN + DXBC + h) * CIN;
    float s = 0.f;
    for (int c0 = part * 32; c0 < part * 32 + 32; c0 += 8) {
        u16x8 xv = *(const u16x8*)&xr[c0];
        float4 w0 = *(const float4*)&wr[c0];
        float4 w1 = *(const float4*)&wr[c0 + 4];
        s += bf2f(xv[0]) * w0.x + bf2f(xv[1]) * w0.y + bf2f(xv[2]) * w0.z + bf2f(xv[3]) * w0.w;
        s += bf2f(xv[4]) * w1.x + bf2f(xv[5]) * w1.y + bf2f(xv[6]) * w1.z + bf2f(xv[7]) * w1.w;
    }
    s += __shfl_xor(s, 1, 64);
    s += __shfl_xor(s, 2, 64);
    s += __shfl_xor(s, 4, 64);
    s += __shfl_xor(s, 8, 64);
    if (part == 0) {
        float si = s + dt_bias[h];
        float dtv = si > 15.f ? si : __logf(1.f + __expf(si));
        float An = -__expf(A_log[h]);
        float2 dd; dd.x = dtv; dd.y = dtv * An;
        dtda[(size_t)tok * NHH + h] = dd;
    }
}

// ---------- SSD K1: per-(b,h,chunk) — G̃, Y_intra(bf16), ΔH(bf16), C2, d_c ----------
__global__ __launch_bounds__(256) void ssd_chunk(const float* __restrict__ Bcb,
                                                 const float* __restrict__ Ccb,
                                                 const u16* __restrict__ xbc,
                                                 const float2* __restrict__ dtda,
                                                 u16* __restrict__ yi,
                                                 u16* __restrict__ DHb,
                                                 u16* __restrict__ C2G,
                                                 float* __restrict__ DC) {
    __shared__ u16 Bt[4096], Ct[4096], XT[4096], BTt[4096], Gt[4096];
    __shared__ float Sar[64], dtvA[64], wA[64], eSA[64];
    int tau = blockIdx.x;
    int b = tau >> 8, h = (tau >> 4) & 15, c = tau & 15;
    int t0g = b * LL + c * QCH;
    int t = threadIdx.x, lane = t & 63, wave = t >> 6;
    int row = t >> 2, q = t & 3;

    // ---- phase A: stage B, C (fp32->bf16), X (transposed), dt scan ----
    {
        const float* bp = Bcb + (size_t)(t0g + row) * DST + q * 16;
        const float* cp = Ccb + (size_t)(t0g + row) * DST + q * 16;
#pragma unroll
        for (int half = 0; half < 2; ++half) {
            float4 v0 = *(const float4*)(bp + half * 8);
            float4 v1 = *(const float4*)(bp + half * 8 + 4);
            u16x8 o;
            o[0] = f2bf(v0.x); o[1] = f2bf(v0.y); o[2] = f2bf(v0.z); o[3] = f2bf(v0.w);
            o[4] = f2bf(v1.x); o[5] = f2bf(v1.y); o[6] = f2bf(v1.z); o[7] = f2bf(v1.w);
            *(u16x8*)&Bt[swz(row, q * 32 + half * 16)] = o;
            float4 c0 = *(const float4*)(cp + half * 8);
            float4 c1 = *(const float4*)(cp + half * 8 + 4);
            u16x8 oc;
            oc[0] = f2bf(c0.x); oc[1] = f2bf(c0.y); oc[2] = f2bf(c0.z); oc[3] = f2bf(c0.w);
            oc[4] = f2bf(c1.x); oc[5] = f2bf(c1.y); oc[6] = f2bf(c1.z); oc[7] = f2bf(c1.w);
            *(u16x8*)&Ct[swz(row, q * 32 + half * 16)] = oc;
        }
        const u16* xp = xbc + (size_t)(t0g + row) * XBCS + h * HDD + q * 16;
        u16x8 x0 = *(const u16x8*)xp;
        u16x8 x1 = *(const u16x8*)(xp + 8);
#pragma unroll
        for (int e = 0; e < 8; ++e) XT[swz(q * 16 + e, row * 2)] = x0[e];
#pragma unroll
        for (int e = 0; e < 8; ++e) XT[swz(q * 16 + 8 + e, row * 2)] = x1[e];
    }
    if (t < 64) {
        float2 dd = dtda[(size_t)(t0g + t) * NHH + h];
        float s = dd.y;  // a_t
#pragma unroll
        for (int off = 1; off < 64; off <<= 1) {
            float u = __shfl_up(s, off, 64);
            if (t >= off) s += u;
        }
        float SQ = __shfl(s, 63, 64);
        Sar[t] = s; dtvA[t] = dd.x;
        wA[t] = __expf(SQ - s) * dd.x;
        eSA[t] = __expf(s);
        if (t == 0) DC[tau] = __expf(SQ);
    }
    __syncthreads();

    int R = wave >> 1, Cq = wave & 1, rr = lane & 15, sg = lane >> 4;
    // ---- phase B: G = C·B^T, scale/mask -> Gt; also C2 + B~T ----
    f32x4 g[2][2];
#pragma unroll
    for (int mi = 0; mi < 2; ++mi)
#pragma unroll
        for (int ni = 0; ni < 2; ++ni)
#pragma unroll
            for (int r = 0; r < 4; ++r) g[mi][ni][r] = 0.f;
#pragma unroll
    for (int kt = 0; kt < 2; ++kt) {
        int cb = kt * 64 + sg * 16;
        bf16x8 a0 = *(const bf16x8*)&Ct[swz(R * 32 + rr, cb)];
        bf16x8 a1 = *(const bf16x8*)&Ct[swz(R * 32 + 16 + rr, cb)];
        bf16x8 b0 = *(const bf16x8*)&Bt[swz(Cq * 32 + rr, cb)];
        bf16x8 b1 = *(const bf16x8*)&Bt[swz(Cq * 32 + 16 + rr, cb)];
        g[0][0] = __builtin_amdgcn_mfma_f32_16x16x32_bf16(a0, b0, g[0][0], 0, 0, 0);
        g[0][1] = __builtin_amdgcn_mfma_f32_16x16x32_bf16(a0, b1, g[0][1], 0, 0, 0);
        g[1][0] = __builtin_amdgcn_mfma_f32_16x16x32_bf16(a1, b0, g[1][0], 0, 0, 0);
        g[1][1] = __builtin_amdgcn_mfma_f32_16x16x32_bf16(a1, b1, g[1][1], 0, 0, 0);
    }
#pragma unroll
    for (int mi = 0; mi < 2; ++mi)
#pragma unroll
        for (int ni = 0; ni < 2; ++ni)
#pragma unroll
            for (int r = 0; r < 4; ++r) {
                int i = R * 32 + mi * 16 + sg * 4 + r;
                int j = Cq * 32 + ni * 16 + rr;
                float v = (i >= j) ? g[mi][ni][r] * __expf(Sar[i] - Sar[j]) * dtvA[j] : 0.f;
                Gt[swz(i, j * 2)] = f2bf(v);
            }
    // C2 (global) and B~T (LDS, transposed)
#pragma unroll
    for (int half = 0; half < 2; ++half) {
        u16x8 cv = *(const u16x8*)&Ct[swz(row, q * 32 + half * 16)];
        u16x8 ov;
#pragma unroll
        for (int e = 0; e < 8; ++e) ov[e] = f2bf(bf2f(cv[e]) * eSA[row]);
        *(u16x8*)&C2G[(size_t)tau * 4096 + row * 64 + q * 16 + half * 8] = ov;
        u16x8 bv = *(const u16x8*)&Bt[swz(row, q * 32 + half * 16)];
#pragma unroll
        for (int e = 0; e < 8; ++e)
            BTt[swz(q * 16 + half * 8 + e, row * 2)] = f2bf(bf2f(bv[e]) * wA[row]);
    }
    __syncthreads();

    // ---- phase C: Y_intra = G~·X and ΔH = B~T·X ----
    f32x4 y[2][2], dh[2][2];
#pragma unroll
    for (int mi = 0; mi < 2; ++mi)
#pragma unroll
        for (int ni = 0; ni < 2; ++ni)
#pragma unroll
            for (int r = 0; r < 4; ++r) { y[mi][ni][r] = 0.f; dh[mi][ni][r] = 0.f; }
#pragma unroll
    for (int kt = 0; kt < 2; ++kt) {
        int cb = kt * 64 + sg * 16;
        bf16x8 xb0 = *(const bf16x8*)&XT[swz(Cq * 32 + rr, cb)];
        bf16x8 xb1 = *(const bf16x8*)&XT[swz(Cq * 32 + 16 + rr, cb)];
        bf16x8 ga0 = *(const bf16x8*)&Gt[swz(R * 32 + rr, cb)];
        bf16x8 ga1 = *(const bf16x8*)&Gt[swz(R * 32 + 16 + rr, cb)];
        bf16x8 ba0 = *(const bf16x8*)&BTt[swz(R * 32 + rr, cb)];
        bf16x8 ba1 = *(const bf16x8*)&BTt[swz(R * 32 + 16 + rr, cb)];
        y[0][0] = __builtin_amdgcn_mfma_f32_16x16x32_bf16(ga0, xb0, y[0][0], 0, 0, 0);
        y[0][1] = __builtin_amdgcn_mfma_f32_16x16x32_bf16(ga0, xb1, y[0][1], 0, 0, 0);
        y[1][0] = __builtin_amdgcn_mfma_f32_16x16x32_bf16(ga1, xb0, y[1][0], 0, 0, 0);
        y[1][1] = __builtin_amdgcn_mfma_f32_16x16x32_bf16(ga1, xb1, y[1][1], 0, 0, 0);
        dh[0][0] = __builtin_amdgcn_mfma_f32_16x16x32_bf16(ba0, xb0, dh[0][0], 0, 0, 0);
        dh[0][1] = __builtin_amdgcn_mfma_f32_16x16x32_bf16(ba0, xb1, dh[0][1], 0, 0, 0);
        dh[1][0] = __builtin_amdgcn_mfma_f32_16x16x32_bf16(ba1, xb0, dh[1][0], 0, 0, 0);
        dh[1][1] = __builtin_amdgcn_mfma_f32_16x16x32_bf16(ba1, xb1, dh[1][1], 0, 0, 0);
    }
#pragma unroll
    for (int mi = 0; mi < 2; ++mi)
#pragma unroll
        for (int ni = 0; ni < 2; ++ni)
#pragma unroll
            for (int r = 0; r < 4; ++r) {
                int i = R * 32 + mi * 16 + sg * 4 + r;
                int p = Cq * 32 + ni * 16 + rr;
                yi[(size_t)(t0g + i) * DIN + h * HDD + p] = f2bf(y[mi][ni][r]);
                DHb[(size_t)tau * 4096 + i * 64 + p] = f2bf(dh[mi][ni][r]);
            }
}

// ---------- SSD K2: sequential chunk-state carry ----------
__global__ __launch_bounds__(256) void ssd_carry(const u16* __restrict__ DHb,
                                                 const float* __restrict__ DC,
                                                 u16* __restrict__ HPREV) {
    int bid = blockIdx.x;
    int bh = bid >> 1, ph = bid & 1;
    int t = threadIdx.x;
    int s = t >> 2, p0 = ph * 32 + (t & 3) * 8;
    size_t base = (size_t)bh * NCHUNK * 4096 + s * 64 + p0;
    float Hv[8] = {0.f, 0.f, 0.f, 0.f, 0.f, 0.f, 0.f, 0.f};
    for (int c = 0; c < NCHUNK; ++c) {
        size_t off = base + (size_t)c * 4096;
        u16x8 hp;
#pragma unroll
        for (int e = 0; e < 8; ++e) hp[e] = f2bf(Hv[e]);
        *(u16x8*)&HPREV[off] = hp;
        float d = DC[bh * NCHUNK + c];
        u16x8 dv = *(const u16x8*)&DHb[off];
#pragma unroll
        for (int e = 0; e < 8; ++e) Hv[e] = d * Hv[e] + bf2f(dv[e]);
    }
}

// ---------- SSD K3: Y = Y_intra + C2·Hprev; fuse D·x and z-gate; in-place into yi ----------
__global__ __launch_bounds__(256) void ssd_final(const u16* __restrict__ C2G,
                                                 const u16* __restrict__ HPREV,
                                                 const u16* __restrict__ xbc,
                                                 const u16* __restrict__ zx,
                                                 const float* __restrict__ Dp,
                                                 u16* __restrict__ yi) {
    __shared__ u16 C2t[4096], HT[4096];
    int tau = blockIdx.x;
    int b = tau >> 8, h = (tau >> 4) & 15, c = tau & 15;
    int t0g = b * LL + c * QCH;
    int t = threadIdx.x, lane = t & 63, wave = t >> 6;
    int row = t >> 2, q = t & 3;
#pragma unroll
    for (int half = 0; half < 2; ++half) {
        u16x8 cv = *(const u16x8*)&C2G[(size_t)tau * 4096 + row * 64 + q * 16 + half * 8];
        *(u16x8*)&C2t[swz(row, q * 32 + half * 16)] = cv;
        u16x8 hv = *(const u16x8*)&HPREV[(size_t)tau * 4096 + row * 64 + q * 16 + half * 8];
#pragma unroll
        for (int e = 0; e < 8; ++e) HT[swz(q * 16 + half * 8 + e, row * 2)] = hv[e];
    }
    __syncthreads();
    int R = wave >> 1, Cq = wave & 1, rr = lane & 15, sg = lane >> 4;
    float Dh = Dp[h];
    f32x4 acc[2][2];
#pragma unroll
    for (int mi = 0; mi < 2; ++mi)
#pragma unroll
        for (int ni = 0; ni < 2; ++ni)
#pragma unroll
            for (int r = 0; r < 4; ++r) {
                int i = R * 32 + mi * 16 + sg * 4 + r;
                int p = Cq * 32 + ni * 16 + rr;
                acc[mi][ni][r] = bf2f(yi[(size_t)(t0g + i) * DIN + h * HDD + p]);
            }
#pragma unroll
    for (int kt = 0; kt < 2; ++kt) {
        int cb = kt * 64 + sg * 16;
        bf16x8 a0 = *(const bf16x8*)&C2t[swz(R * 32 + rr, cb)];
        bf16x8 a1 = *(const bf16x8*)&C2t[swz(R * 32 + 16 + rr, cb)];
        bf16x8 b0 = *(const bf16x8*)&HT[swz(Cq * 32 + rr, cb)];
        bf16x8 b1 = *(const bf16x8*)&HT[swz(Cq * 32 + 16 + rr, cb)];
        acc[0][0] = __builtin_amdgcn_mfma_f32_16x16x32_bf16(a0, b0, acc[0][0], 0, 0, 0);
        acc[0][1] = __builtin_amdgcn_mfma_f32_16x16x32_bf16(a0, b1, acc[0][1], 0, 0, 0);
        acc[1][0] = __builtin_amdgcn_mfma_f32_16x16x32_bf16(a1, b0, acc[1][0], 0, 0, 0);
        acc[1][1] = __builtin_amdgcn_mfma_f32_16x16x32_bf16(a1, b1, acc[1][1], 0, 0, 0);
    }
#pragma unroll
    for (int mi = 0; mi < 2; ++mi)
#pragma unroll
        for (int ni = 0; ni < 2; ++ni)
#pragma unroll
            for (int r = 0; r < 4; ++r) {
                int i = R * 32 + mi * 16 + sg * 4 + r;
                int p = Cq * 32 + ni * 16 + rr;
                size_t tok = t0g + i;
                int col = h * HDD + p;
                float xf = bf2f(xbc[tok * XBCS + col]);
                float zf = bf2f(zx[tok * NPADW + col]);
                float yo = (acc[mi][ni][r] + Dh * xf) * (zf / (1.f + __expf(-zf)));
                yi[tok * DIN + col] = f2bf(yo);
            }
}

// ---------- RMSNorm over d_inner (bf16 in), write bf16 ----------
__global__ __launch_bounds__(256) void rms_kernel(const u16* __restrict__ y,
                                                  const float* __restrict__ w,
                                                  u16* __restrict__ y2) {
    int row = blockIdx.x, t = threadIdx.x;
    ushort4 uv = *(const ushort4*)&y[(size_t)row * DIN + t * 4];
    float v0 = bf2f(uv.x), v1 = bf2f(uv.y), v2 = bf2f(uv.z), v3 = bf2f(uv.w);
    float ss = v0 * v0 + v1 * v1 + v2 * v2 + v3 * v3;
#pragma unroll
    for (int o = 1; o < 64; o <<= 1) ss += __shfl_xor(ss, o, 64);
    __shared__ float ps[4];
    if ((t & 63) == 0) ps[t >> 6] = ss;
    __syncthreads();
    float tot = ps[0] + ps[1] + ps[2] + ps[3];
    float rs = rsqrtf(tot * (1.f / DIN) + 1e-5f);
    int c = t * 4;
    ushort4 o4;
    o4.x = f2bf(v0 * rs * w[c]);
    o4.y = f2bf(v1 * rs * w[c + 1]);
    o4.z = f2bf(v2 * rs * w[c + 2]);
    o4.w = f2bf(v3 * rs * w[c + 3]);
    *(ushort4*)&y2[(size_t)row * DIN + c] = o4;
}

extern "C" void kernel_launch(void* const* d_in, const int* in_sizes, int n_in,
                              void* d_out, int out_size, void* d_ws, size_t ws_size,
                              hipStream_t stream) {
    const float* x         = (const float*)d_in[0];
    const float* ln_w      = (const float*)d_in[1];
    const float* ln_b      = (const float*)d_in[2];
    const float* in_proj_w = (const float*)d_in[3];
    const float* conv1d_w  = (const float*)d_in[4];
    const float* conv1d_b  = (const float*)d_in[5];
    const float* dt_bias   = (const float*)d_in[6];
    const float* A_log     = (const float*)d_in[7];
    const float* Dp        = (const float*)d_in[8];
    const float* rms_w     = (const float*)d_in[9];
    const float* out_proj_w= (const float*)d_in[10];
    const float* conv2d_w  = (const float*)d_in[11];
    const float* conv2d_b  = (const float*)d_in[12];
    const float* bn_g      = (const float*)d_in[13];
    const float* bn_b      = (const float*)d_in[14];
    const float* bn_mean   = (const float*)d_in[15];
    const float* bn_var    = (const float*)d_in[16];

    const int TOK = NB * LL;  // 8192
    const int NTAU = NB * NHH * NCHUNK;  // 2048
    char* ws = (char*)d_ws;
    size_t off = 0;
    auto alloc = [&](size_t bytes) {
        void* p = ws + off;
        off += (bytes + 255) & ~(size_t)255;
        return p;
    };
    u16*   Win   = (u16*)alloc((size_t)NPADW * CIN * 2);
    u16*   Wout  = (u16*)alloc((size_t)CIN * DIN * 2);
    u16*   Wc2   = (u16*)alloc((size_t)CIN * CIN * 2);
    u16*   XN    = (u16*)alloc((size_t)TOK * CIN * 2);
    u16*   ZX    = (u16*)alloc((size_t)TOK * NPADW * 2);
    u16*   XBC   = (u16*)alloc((size_t)TOK * XBCS * 2);
    float* Bcb   = (float*)alloc((size_t)TOK * DST * 4);
    float* Ccb   = (float*)alloc((size_t)TOK * DST * 4);
    float2* DTDA = (float2*)alloc((size_t)TOK * NHH * 8);
    u16*   YI    = (u16*)alloc((size_t)TOK * DIN * 2);
    u16*   DHb   = (u16*)alloc((size_t)NTAU * 4096 * 2);
    u16*   C2G   = (u16*)alloc((size_t)NTAU * 4096 * 2);
    u16*   HPREV = (u16*)alloc((size_t)NTAU * 4096 * 2);
    float* DC    = (float*)alloc((size_t)NTAU * 4);
    u16*   Y2    = (u16*)alloc((size_t)TOK * DIN * 2);
    u16*   OUT1  = (u16*)alloc((size_t)TOK * CIN * 2);
    float* BNSC  = (float*)alloc(CIN * 4);
    float* BNSH  = (float*)alloc(CIN * 4);

    f2bf_pad<<<(NPADW * CIN + 255) / 256, 256, 0, stream>>>(in_proj_w, Win, DPROJ * CIN, NPADW * CIN);
    f2bf_kernel<<<(CIN * DIN + 255) / 256, 256, 0, stream>>>(out_proj_w, Wout, CIN * DIN);
    f2bf_kernel<<<(CIN * CIN + 255) / 256, 256, 0, stream>>>(conv2d_w, Wc2, CIN * CIN);
    bn_prep<<<2, 256, 0, stream>>>(conv2d_b, bn_g, bn_b, bn_mean, bn_var, BNSC, BNSH);

    ln_kernel<<<256, 256, 0, stream>>>(x, ln_w, ln_b, XN);

    gemm_bt<0><<<dim3(NPADW / 128, TOK / 128), 256, 0, stream>>>(XN, Win, ZX, TOK, NPADW, CIN, NPADW,
                                                                 nullptr, nullptr);

    conv1d_fused<<<NB * (LL / CTT), 288, 0, stream>>>(ZX, conv1d_w, conv1d_b, XBC, Bcb, Ccb);
    dt_gemv<<<TOK, 256, 0, stream>>>(XN, in_proj_w, dt_bias, A_log, DTDA);

    ssd_chunk<<<NTAU, 256, 0, stream>>>(Bcb, Ccb, XBC, DTDA, YI, DHb, C2G, DC);
    ssd_carry<<<256, 256, 0, stream>>>(DHb, DC, HPREV);
    ssd_final<<<NTAU, 256, 0, stream>>>(C2G, HPREV, XBC, ZX, Dp, YI);

    rms_kernel<<<TOK, 256, 0, stream>>>(YI, rms_w, Y2);

    gemm_bt<0><<<dim3(CIN / 128, TOK / 128), 256, 0, stream>>>(Y2, Wout, OUT1, TOK, CIN, DIN, CIN,
                                                               nullptr, nullptr);

    gemm_bt<1><<<dim3(TOK / 128, CIN / 128), 256, 0, stream>>>(Wc2, OUT1, d_out, CIN, TOK, CIN, 0,
                                                               BNSC, BNSH);
}

// Round 6
// 202.617 us; speedup vs baseline: 3.6048x; 1.0216x over previous
//
#include <hip/hip_runtime.h>
#include <hip/hip_bf16.h>

// Problem constants
#define NB 8
#define LL 1024        // H*W tokens per batch
#define CIN 512
#define DIN 1024       // d_inner
#define DXBC 1152      // d_inner + 2*d_state
#define DPROJ 2192     // actual in_proj rows
#define NPADW 2304     // padded to 18*128 for GEMM tiles
#define NHH 16
#define HDD 64
#define DST 64
#define NCHUNK 16
#define QCH 64         // chunk length
#define XBCS 1024      // XBC stored stride (x-part only; B/C never re-read from it)
#define CTT 8          // conv tokens per block (8 => 1024 blocks => ~18 waves/CU)

typedef unsigned short u16;
typedef unsigned int u32;
typedef __bf16 bf16x8 __attribute__((ext_vector_type(8)));
typedef float f32x4 __attribute__((ext_vector_type(4)));
typedef u16 u16x8 __attribute__((ext_vector_type(8)));

__device__ __forceinline__ float bf2f(u16 u) {
    u32 x = ((u32)u) << 16; float f; __builtin_memcpy(&f, &x, 4); return f;
}
__device__ __forceinline__ u16 f2bf(float f) {
    u32 x; __builtin_memcpy(&x, &f, 4);
    u32 r = x + 0x7fff + ((x >> 16) & 1);
    return (u16)(r >> 16);
}

__device__ __forceinline__ void gload16(const u16* g, u16* l) {
    __builtin_amdgcn_global_load_lds((__attribute__((address_space(1))) void*)(g),
                                     (__attribute__((address_space(3))) void*)(l), 16, 0, 0);
}

// swizzled u16 index into a [64][64] bf16 LDS tile (128B rows, 16B-slot XOR swizzle)
__device__ __forceinline__ int swz(int row, int cb) {
    return row * 64 + ((cb ^ ((row & 7) << 4)) >> 1);
}

// ---------- weight converts ----------
__global__ void f2bf_kernel(const float* __restrict__ s, u16* __restrict__ d, int n) {
    int i = blockIdx.x * 256 + threadIdx.x;
    if (i < n) d[i] = f2bf(s[i]);
}
__global__ void f2bf_pad(const float* __restrict__ s, u16* __restrict__ d, int nsrc, int ndst) {
    int i = blockIdx.x * 256 + threadIdx.x;
    if (i < ndst) d[i] = (i < nsrc) ? f2bf(s[i]) : (u16)0;
}
__global__ void bn_prep(const float* __restrict__ cb, const float* __restrict__ g,
                        const float* __restrict__ bb, const float* __restrict__ mean,
                        const float* __restrict__ var, float* __restrict__ scale,
                        float* __restrict__ shift) {
    int i = blockIdx.x * 256 + threadIdx.x;
    if (i < CIN) {
        float rs = rsqrtf(var[i] + 1e-5f);
        float sc = g[i] * rs;
        scale[i] = sc;
        shift[i] = (cb[i] - mean[i]) * sc + bb[i];
    }
}

// ---------- LayerNorm over channels + transpose (B,C,HW) -> (tok, C) bf16 ----------
__global__ __launch_bounds__(256) void ln_kernel(const float* __restrict__ x,
                                                 const float* __restrict__ lw,
                                                 const float* __restrict__ lb,
                                                 u16* __restrict__ xn) {
    __shared__ u16 tile[CIN * 33];
    __shared__ float psum[8][32], psq[8][32], muA[32], rsA[32];
    int bid = blockIdx.x;
    int b = bid >> 5, hw0 = (bid & 31) * 32;
    int t = threadIdx.x;
    int hw = t & 31, cg = t >> 5;
    const float* xb = x + (size_t)b * CIN * LL + hw0 + hw;
    float s = 0.f, sq = 0.f;
    for (int r = 0; r < CIN / 8; ++r) {
        int c = r * 8 + cg;
        float v = xb[(size_t)c * LL];
        s += v; sq += v * v;
        tile[c * 33 + hw] = f2bf(v);
    }
    psum[cg][hw] = s; psq[cg][hw] = sq;
    __syncthreads();
    if (t < 32) {
        float ss = 0.f, qq = 0.f;
        for (int g = 0; g < 8; ++g) { ss += psum[g][t]; qq += psq[g][t]; }
        float mu = ss * (1.f / CIN);
        float var = qq * (1.f / CIN) - mu * mu;
        muA[t] = mu; rsA[t] = rsqrtf(var + 1e-5f);
    }
    __syncthreads();
    for (int r = 0; r < 64; ++r) {
        int idx = r * 256 + t;
        int c = idx & (CIN - 1);
        int hh = idx >> 9;
        float v = (bf2f(tile[c * 33 + hh]) - muA[hh]) * rsA[hh] * lw[c] + lb[c];
        xn[((size_t)(b * LL + hw0 + hh)) * CIN + c] = f2bf(v);
    }
}

// ---------- bf16 MFMA GEMM: BK=64, XOR-swizzled LDS (pre-swizzled global source) ----------
template <int EPI>
__global__ __launch_bounds__(256) void gemm_bt(const u16* __restrict__ A, const u16* __restrict__ Bw,
                                               void* __restrict__ Cout, int M, int N, int K, int ldc,
                                               const float* __restrict__ scale,
                                               const float* __restrict__ shift) {
    __shared__ u16 As[128 * 64], Bs[128 * 64];
    int t = threadIdx.x;
    int lane = t & 63, wave = t >> 6;
    int m0 = blockIdx.y * 128, n0 = blockIdx.x * 128;
    int wr = wave >> 1, wc = wave & 1;
    f32x4 acc[4][4];
    for (int m = 0; m < 4; ++m)
        for (int n = 0; n < 4; ++n)
            for (int q = 0; q < 4; ++q) acc[m][n][q] = 0.f;

    const u16* Arow = A + (size_t)m0 * K;
    const u16* Brow = Bw + (size_t)n0 * K;
    int s4 = lane >> 4;   // quarter-wave -> 8-elem k-group
    int rr = lane & 15;
    for (int k0 = 0; k0 < K; k0 += 64) {
#pragma unroll
        for (int j = 0; j < 4; ++j) {
            int e = j * 256 + t;          // 16B-slot id, 8 slots per row
            int r = e >> 3, sr = e & 7;
            int src = (sr ^ (r & 7)) * 8; // inverse (= same) XOR permutation on source
            gload16(Arow + (size_t)r * K + k0 + src, As + e * 8);
            gload16(Brow + (size_t)r * K + k0 + src, Bs + e * 8);
        }
        __syncthreads();
#pragma unroll
        for (int kk = 0; kk < 2; ++kk) {
            bf16x8 af[4], bfr[4];
#pragma unroll
            for (int m = 0; m < 4; ++m) {
                int row = wr * 64 + m * 16 + rr;
                int ss = (kk * 4 + s4) ^ (row & 7);
                af[m] = *(const bf16x8*)&As[row * 64 + ss * 8];
            }
#pragma unroll
            for (int n = 0; n < 4; ++n) {
                int row = wc * 64 + n * 16 + rr;
                int ss = (kk * 4 + s4) ^ (row & 7);
                bfr[n] = *(const bf16x8*)&Bs[row * 64 + ss * 8];
            }
#pragma unroll
            for (int m = 0; m < 4; ++m)
#pragma unroll
                for (int n = 0; n < 4; ++n)
                    acc[m][n] = __builtin_amdgcn_mfma_f32_16x16x32_bf16(af[m], bfr[n], acc[m][n], 0, 0, 0);
        }
        __syncthreads();
    }
    int fq = lane >> 4, fr = lane & 15;
#pragma unroll
    for (int m = 0; m < 4; ++m) {
#pragma unroll
        for (int n = 0; n < 4; ++n) {
            int col = n0 + wc * 64 + n * 16 + fr;
#pragma unroll
            for (int q = 0; q < 4; ++q) {
                int row = m0 + wr * 64 + m * 16 + fq * 4 + q;
                float v = acc[m][n][q];
                if (EPI == 0) {
                    ((u16*)Cout)[(size_t)row * ldc + col] = f2bf(v);
                } else {
                    v = v * scale[row] + shift[row];
                    v = v > 0.f ? v : 0.f;
                    ((float*)Cout)[((size_t)(col >> 10)) * (CIN * LL) + (size_t)row * LL + (col & 1023)] = v;
                }
            }
        }
    }
}

// ---------- depthwise causal conv1d + SiLU, register sliding window ----------
// grid: NB * (LL/CTT) blocks; 288 threads.
// threads 0..255: x-part, 4 ch each (ushort4).  threads 256..287: B/C part, 4 ch each.
__global__ __launch_bounds__(288) void conv1d_fused(const u16* __restrict__ zx,
                                                    const float* __restrict__ w,
                                                    const float* __restrict__ bias,
                                                    u16* __restrict__ xbc,
                                                    float* __restrict__ Bc, float* __restrict__ Cc) {
    int bid = blockIdx.x;
    int b = bid >> 7;            // LL/CTT = 128 strips per batch
    int l0 = (bid & 127) * CTT;
    int t = threadIdx.x;
    bool isX = t < 256;
    int ch = isX ? t * 4 : 1024 + (t - 256) * 4;   // channel within xBC slice

    // per-channel weights and bias
    float4 wv0 = *(const float4*)&w[(ch + 0) * 4];
    float4 wv1 = *(const float4*)&w[(ch + 1) * 4];
    float4 wv2 = *(const float4*)&w[(ch + 2) * 4];
    float4 wv3 = *(const float4*)&w[(ch + 3) * 4];
    float4 bv = *(const float4*)&bias[ch];

    // load all input rows for this strip (3 halo + CTT)
    ushort4 xin[CTT + 3];
    const u16* src = zx + (size_t)(b * LL + l0 - 3) * NPADW + DIN + ch;
#pragma unroll
    for (int i = 0; i < CTT + 3; ++i) {
        ushort4 v = {0, 0, 0, 0};
        if (l0 + i - 3 >= 0) v = *(const ushort4*)(src + (size_t)i * NPADW);
        xin[i] = v;
    }
#pragma unroll
    for (int i = 0; i < CTT; ++i) {
        int tok = b * LL + l0 + i;
        float a0 = bv.x + bf2f(xin[i].x) * wv0.x + bf2f(xin[i + 1].x) * wv0.y +
                   bf2f(xin[i + 2].x) * wv0.z + bf2f(xin[i + 3].x) * wv0.w;
        float a1 = bv.y + bf2f(xin[i].y) * wv1.x + bf2f(xin[i + 1].y) * wv1.y +
                   bf2f(xin[i + 2].y) * wv1.z + bf2f(xin[i + 3].y) * wv1.w;
        float a2 = bv.z + bf2f(xin[i].z) * wv2.x + bf2f(xin[i + 1].z) * wv2.y +
                   bf2f(xin[i + 2].z) * wv2.z + bf2f(xin[i + 3].z) * wv2.w;
        float a3 = bv.w + bf2f(xin[i].w) * wv3.x + bf2f(xin[i + 1].w) * wv3.y +
                   bf2f(xin[i + 2].w) * wv3.z + bf2f(xin[i + 3].w) * wv3.w;
        float s0 = a0 / (1.f + __expf(-a0));
        float s1 = a1 / (1.f + __expf(-a1));
        float s2 = a2 / (1.f + __expf(-a2));
        float s3 = a3 / (1.f + __expf(-a3));
        if (isX) {
            ushort4 o;
            o.x = f2bf(s0); o.y = f2bf(s1); o.z = f2bf(s2); o.w = f2bf(s3);
            *(ushort4*)&xbc[(size_t)tok * XBCS + ch] = o;
        } else {
            int s = ch - 1024;   // 0..124
            float4 o4; o4.x = s0; o4.y = s1; o4.z = s2; o4.w = s3;
            if (s < DST) *(float4*)&Bc[(size_t)tok * DST + s] = o4;
            else         *(float4*)&Cc[(size_t)tok * DST + (s - DST)] = o4;
        }
    }
}

// ---------- dt GEMV: compute dtv = softplus(dt+bias), a = dtv*(-exp(A_log)) ----------
__global__ __launch_bounds__(256) void dt_gemv(const u16* __restrict__ xn,
                                               const float* __restrict__ wproj,
                                               const float* __restrict__ dt_bias,
                                               const float* __restrict__ A_log,
                                               float2* __restrict__ dtda) {
    int tok = blockIdx.x;
    int t = threadIdx.x;
    int h = t >> 4, part = t & 15;
    const u16* xr = xn + (size_t)tok * CIN;
    const float* wr = wproj + (size_t)(DIN + DXBC + h) * CIN;
    float s = 0.f;
    for (int c0 = part * 32; c0 < part * 32 + 32; c0 += 8) {
        u16x8 xv = *(const u16x8*)&xr[c0];
        float4 w0 = *(const float4*)&wr[c0];
        float4 w1 = *(const float4*)&wr[c0 + 4];
        s += bf2f(xv[0]) * w0.x + bf2f(xv[1]) * w0.y + bf2f(xv[2]) * w0.z + bf2f(xv[3]) * w0.w;
        s += bf2f(xv[4]) * w1.x + bf2f(xv[5]) * w1.y + bf2f(xv[6]) * w1.z + bf2f(xv[7]) * w1.w;
    }
    s += __shfl_xor(s, 1, 64);
    s += __shfl_xor(s, 2, 64);
    s += __shfl_xor(s, 4, 64);
    s += __shfl_xor(s, 8, 64);
    if (part == 0) {
        float si = s + dt_bias[h];
        float dtv = si > 15.f ? si : __logf(1.f + __expf(si));
        float An = -__expf(A_log[h]);
        float2 dd; dd.x = dtv; dd.y = dtv * An;
        dtda[(size_t)tok * NHH + h] = dd;
    }
}

// ---------- SSD K1: per-(b,h,chunk) — G̃, Y_intra(bf16), ΔH(bf16), C2, d_c ----------
__global__ __launch_bounds__(256) void ssd_chunk(const float* __restrict__ Bcb,
                                                 const float* __restrict__ Ccb,
                                                 const u16* __restrict__ xbc,
                                                 const float2* __restrict__ dtda,
                                                 u16* __restrict__ yi,
                                                 u16* __restrict__ DHb,
                                                 u16* __restrict__ C2G,
                                                 float* __restrict__ DC) {
    __shared__ u16 Bt[4096], Ct[4096], XT[4096], BTt[4096], Gt[4096];
    __shared__ float Sar[64], dtvA[64], wA[64], eSA[64];
    int tau = blockIdx.x;
    int b = tau >> 8, h = (tau >> 4) & 15, c = tau & 15;
    int t0g = b * LL + c * QCH;
    int t = threadIdx.x, lane = t & 63, wave = t >> 6;
    int row = t >> 2, q = t & 3;

    // ---- phase A: stage B, C (fp32->bf16), X (transposed), dt scan ----
    {
        const float* bp = Bcb + (size_t)(t0g + row) * DST + q * 16;
        const float* cp = Ccb + (size_t)(t0g + row) * DST + q * 16;
#pragma unroll
        for (int half = 0; half < 2; ++half) {
            float4 v0 = *(const float4*)(bp + half * 8);
            float4 v1 = *(const float4*)(bp + half * 8 + 4);
            u16x8 o;
            o[0] = f2bf(v0.x); o[1] = f2bf(v0.y); o[2] = f2bf(v0.z); o[3] = f2bf(v0.w);
            o[4] = f2bf(v1.x); o[5] = f2bf(v1.y); o[6] = f2bf(v1.z); o[7] = f2bf(v1.w);
            *(u16x8*)&Bt[swz(row, q * 32 + half * 16)] = o;
            float4 c0 = *(const float4*)(cp + half * 8);
            float4 c1 = *(const float4*)(cp + half * 8 + 4);
            u16x8 oc;
            oc[0] = f2bf(c0.x); oc[1] = f2bf(c0.y); oc[2] = f2bf(c0.z); oc[3] = f2bf(c0.w);
            oc[4] = f2bf(c1.x); oc[5] = f2bf(c1.y); oc[6] = f2bf(c1.z); oc[7] = f2bf(c1.w);
            *(u16x8*)&Ct[swz(row, q * 32 + half * 16)] = oc;
        }
        const u16* xp = xbc + (size_t)(t0g + row) * XBCS + h * HDD + q * 16;
        u16x8 x0 = *(const u16x8*)xp;
        u16x8 x1 = *(const u16x8*)(xp + 8);
#pragma unroll
        for (int e = 0; e < 8; ++e) XT[swz(q * 16 + e, row * 2)] = x0[e];
#pragma unroll
        for (int e = 0; e < 8; ++e) XT[swz(q * 16 + 8 + e, row * 2)] = x1[e];
    }
    if (t < 64) {
        float2 dd = dtda[(size_t)(t0g + t) * NHH + h];
        float s = dd.y;  // a_t
#pragma unroll
        for (int off = 1; off < 64; off <<= 1) {
            float u = __shfl_up(s, off, 64);
            if (t >= off) s += u;
        }
        float SQ = __shfl(s, 63, 64);
        Sar[t] = s; dtvA[t] = dd.x;
        wA[t] = __expf(SQ - s) * dd.x;
        eSA[t] = __expf(s);
        if (t == 0) DC[tau] = __expf(SQ);
    }
    __syncthreads();

    int R = wave >> 1, Cq = wave & 1, rr = lane & 15, sg = lane >> 4;
    // ---- phase B: G = C·B^T, scale/mask -> Gt; also C2 + B~T ----
    f32x4 g[2][2];
#pragma unroll
    for (int mi = 0; mi < 2; ++mi)
#pragma unroll
        for (int ni = 0; ni < 2; ++ni)
#pragma unroll
            for (int r = 0; r < 4; ++r) g[mi][ni][r] = 0.f;
#pragma unroll
    for (int kt = 0; kt < 2; ++kt) {
        int cb = kt * 64 + sg * 16;
        bf16x8 a0 = *(const bf16x8*)&Ct[swz(R * 32 + rr, cb)];
        bf16x8 a1 = *(const bf16x8*)&Ct[swz(R * 32 + 16 + rr, cb)];
        bf16x8 b0 = *(const bf16x8*)&Bt[swz(Cq * 32 + rr, cb)];
        bf16x8 b1 = *(const bf16x8*)&Bt[swz(Cq * 32 + 16 + rr, cb)];
        g[0][0] = __builtin_amdgcn_mfma_f32_16x16x32_bf16(a0, b0, g[0][0], 0, 0, 0);
        g[0][1] = __builtin_amdgcn_mfma_f32_16x16x32_bf16(a0, b1, g[0][1], 0, 0, 0);
        g[1][0] = __builtin_amdgcn_mfma_f32_16x16x32_bf16(a1, b0, g[1][0], 0, 0, 0);
        g[1][1] = __builtin_amdgcn_mfma_f32_16x16x32_bf16(a1, b1, g[1][1], 0, 0, 0);
    }
#pragma unroll
    for (int mi = 0; mi < 2; ++mi)
#pragma unroll
        for (int ni = 0; ni < 2; ++ni)
#pragma unroll
            for (int r = 0; r < 4; ++r) {
                int i = R * 32 + mi * 16 + sg * 4 + r;
                int j = Cq * 32 + ni * 16 + rr;
                float v = (i >= j) ? g[mi][ni][r] * __expf(Sar[i] - Sar[j]) * dtvA[j] : 0.f;
                Gt[swz(i, j * 2)] = f2bf(v);
            }
    // C2 (global) and B~T (LDS, transposed)
#pragma unroll
    for (int half = 0; half < 2; ++half) {
        u16x8 cv = *(const u16x8*)&Ct[swz(row, q * 32 + half * 16)];
        u16x8 ov;
#pragma unroll
        for (int e = 0; e < 8; ++e) ov[e] = f2bf(bf2f(cv[e]) * eSA[row]);
        *(u16x8*)&C2G[(size_t)tau * 4096 + row * 64 + q * 16 + half * 8] = ov;
        u16x8 bv = *(const u16x8*)&Bt[swz(row, q * 32 + half * 16)];
#pragma unroll
        for (int e = 0; e < 8; ++e)
            BTt[swz(q * 16 + half * 8 + e, row * 2)] = f2bf(bf2f(bv[e]) * wA[row]);
    }
    __syncthreads();

    // ---- phase C: Y_intra = G~·X and ΔH = B~T·X ----
    f32x4 y[2][2], dh[2][2];
#pragma unroll
    for (int mi = 0; mi < 2; ++mi)
#pragma unroll
        for (int ni = 0; ni < 2; ++ni)
#pragma unroll
            for (int r = 0; r < 4; ++r) { y[mi][ni][r] = 0.f; dh[mi][ni][r] = 0.f; }
#pragma unroll
    for (int kt = 0; kt < 2; ++kt) {
        int cb = kt * 64 + sg * 16;
        bf16x8 xb0 = *(const bf16x8*)&XT[swz(Cq * 32 + rr, cb)];
        bf16x8 xb1 = *(const bf16x8*)&XT[swz(Cq * 32 + 16 + rr, cb)];
        bf16x8 ga0 = *(const bf16x8*)&Gt[swz(R * 32 + rr, cb)];
        bf16x8 ga1 = *(const bf16x8*)&Gt[swz(R * 32 + 16 + rr, cb)];
        bf16x8 ba0 = *(const bf16x8*)&BTt[swz(R * 32 + rr, cb)];
        bf16x8 ba1 = *(const bf16x8*)&BTt[swz(R * 32 + 16 + rr, cb)];
        y[0][0] = __builtin_amdgcn_mfma_f32_16x16x32_bf16(ga0, xb0, y[0][0], 0, 0, 0);
        y[0][1] = __builtin_amdgcn_mfma_f32_16x16x32_bf16(ga0, xb1, y[0][1], 0, 0, 0);
        y[1][0] = __builtin_amdgcn_mfma_f32_16x16x32_bf16(ga1, xb0, y[1][0], 0, 0, 0);
        y[1][1] = __builtin_amdgcn_mfma_f32_16x16x32_bf16(ga1, xb1, y[1][1], 0, 0, 0);
        dh[0][0] = __builtin_amdgcn_mfma_f32_16x16x32_bf16(ba0, xb0, dh[0][0], 0, 0, 0);
        dh[0][1] = __builtin_amdgcn_mfma_f32_16x16x32_bf16(ba0, xb1, dh[0][1], 0, 0, 0);
        dh[1][0] = __builtin_amdgcn_mfma_f32_16x16x32_bf16(ba1, xb0, dh[1][0], 0, 0, 0);
        dh[1][1] = __builtin_amdgcn_mfma_f32_16x16x32_bf16(ba1, xb1, dh[1][1], 0, 0, 0);
    }
#pragma unroll
    for (int mi = 0; mi < 2; ++mi)
#pragma unroll
        for (int ni = 0; ni < 2; ++ni)
#pragma unroll
            for (int r = 0; r < 4; ++r) {
                int i = R * 32 + mi * 16 + sg * 4 + r;
                int p = Cq * 32 + ni * 16 + rr;
                yi[(size_t)(t0g + i) * DIN + h * HDD + p] = f2bf(y[mi][ni][r]);
                DHb[(size_t)tau * 4096 + i * 64 + p] = f2bf(dh[mi][ni][r]);
            }
}

// ---------- SSD K2: sequential chunk-state carry ----------
__global__ __launch_bounds__(256) void ssd_carry(const u16* __restrict__ DHb,
                                                 const float* __restrict__ DC,
                                                 u16* __restrict__ HPREV) {
    int bid = blockIdx.x;
    int bh = bid >> 1, ph = bid & 1;
    int t = threadIdx.x;
    int s = t >> 2, p0 = ph * 32 + (t & 3) * 8;
    size_t base = (size_t)bh * NCHUNK * 4096 + s * 64 + p0;
    float Hv[8] = {0.f, 0.f, 0.f, 0.f, 0.f, 0.f, 0.f, 0.f};
    for (int c = 0; c < NCHUNK; ++c) {
        size_t off = base + (size_t)c * 4096;
        u16x8 hp;
#pragma unroll
        for (int e = 0; e < 8; ++e) hp[e] = f2bf(Hv[e]);
        *(u16x8*)&HPREV[off] = hp;
        float d = DC[bh * NCHUNK + c];
        u16x8 dv = *(const u16x8*)&DHb[off];
#pragma unroll
        for (int e = 0; e < 8; ++e) Hv[e] = d * Hv[e] + bf2f(dv[e]);
    }
}

// ---------- SSD K3: Y = Y_intra + C2·Hprev; fuse D·x and z-gate; in-place into yi ----------
__global__ __launch_bounds__(256) void ssd_final(const u16* __restrict__ C2G,
                                                 const u16* __restrict__ HPREV,
                                                 const u16* __restrict__ xbc,
                                                 const u16* __restrict__ zx,
                                                 const float* __restrict__ Dp,
                                                 u16* __restrict__ yi) {
    __shared__ u16 C2t[4096], HT[4096];
    int tau = blockIdx.x;
    int b = tau >> 8, h = (tau >> 4) & 15, c = tau & 15;
    int t0g = b * LL + c * QCH;
    int t = threadIdx.x, lane = t & 63, wave = t >> 6;
    int row = t >> 2, q = t & 3;
#pragma unroll
    for (int half = 0; half < 2; ++half) {
        u16x8 cv = *(const u16x8*)&C2G[(size_t)tau * 4096 + row * 64 + q * 16 + half * 8];
        *(u16x8*)&C2t[swz(row, q * 32 + half * 16)] = cv;
        u16x8 hv = *(const u16x8*)&HPREV[(size_t)tau * 4096 + row * 64 + q * 16 + half * 8];
#pragma unroll
        for (int e = 0; e < 8; ++e) HT[swz(q * 16 + half * 8 + e, row * 2)] = hv[e];
    }
    __syncthreads();
    int R = wave >> 1, Cq = wave & 1, rr = lane & 15, sg = lane >> 4;
    float Dh = Dp[h];
    f32x4 acc[2][2];
#pragma unroll
    for (int mi = 0; mi < 2; ++mi)
#pragma unroll
        for (int ni = 0; ni < 2; ++ni)
#pragma unroll
            for (int r = 0; r < 4; ++r) {
                int i = R * 32 + mi * 16 + sg * 4 + r;
                int p = Cq * 32 + ni * 16 + rr;
                acc[mi][ni][r] = bf2f(yi[(size_t)(t0g + i) * DIN + h * HDD + p]);
            }
#pragma unroll
    for (int kt = 0; kt < 2; ++kt) {
        int cb = kt * 64 + sg * 16;
        bf16x8 a0 = *(const bf16x8*)&C2t[swz(R * 32 + rr, cb)];
        bf16x8 a1 = *(const bf16x8*)&C2t[swz(R * 32 + 16 + rr, cb)];
        bf16x8 b0 = *(const bf16x8*)&HT[swz(Cq * 32 + rr, cb)];
        bf16x8 b1 = *(const bf16x8*)&HT[swz(Cq * 32 + 16 + rr, cb)];
        acc[0][0] = __builtin_amdgcn_mfma_f32_16x16x32_bf16(a0, b0, acc[0][0], 0, 0, 0);
        acc[0][1] = __builtin_amdgcn_mfma_f32_16x16x32_bf16(a0, b1, acc[0][1], 0, 0, 0);
        acc[1][0] = __builtin_amdgcn_mfma_f32_16x16x32_bf16(a1, b0, acc[1][0], 0, 0, 0);
        acc[1][1] = __builtin_amdgcn_mfma_f32_16x16x32_bf16(a1, b1, acc[1][1], 0, 0, 0);
    }
#pragma unroll
    for (int mi = 0; mi < 2; ++mi)
#pragma unroll
        for (int ni = 0; ni < 2; ++ni)
#pragma unroll
            for (int r = 0; r < 4; ++r) {
                int i = R * 32 + mi * 16 + sg * 4 + r;
                int p = Cq * 32 + ni * 16 + rr;
                size_t tok = t0g + i;
                int col = h * HDD + p;
                float xf = bf2f(xbc[tok * XBCS + col]);
                float zf = bf2f(zx[tok * NPADW + col]);
                float yo = (acc[mi][ni][r] + Dh * xf) * (zf / (1.f + __expf(-zf)));
                yi[tok * DIN + col] = f2bf(yo);
            }
}

// ---------- RMSNorm over d_inner (bf16 in), write bf16 ----------
__global__ __launch_bounds__(256) void rms_kernel(const u16* __restrict__ y,
                                                  const float* __restrict__ w,
                                                  u16* __restrict__ y2) {
    int row = blockIdx.x, t = threadIdx.x;
    ushort4 uv = *(const ushort4*)&y[(size_t)row * DIN + t * 4];
    float v0 = bf2f(uv.x), v1 = bf2f(uv.y), v2 = bf2f(uv.z), v3 = bf2f(uv.w);
    float ss = v0 * v0 + v1 * v1 + v2 * v2 + v3 * v3;
#pragma unroll
    for (int o = 1; o < 64; o <<= 1) ss += __shfl_xor(ss, o, 64);
    __shared__ float ps[4];
    if ((t & 63) == 0) ps[t >> 6] = ss;
    __syncthreads();
    float tot = ps[0] + ps[1] + ps[2] + ps[3];
    float rs = rsqrtf(tot * (1.f / DIN) + 1e-5f);
    int c = t * 4;
    ushort4 o4;
    o4.x = f2bf(v0 * rs * w[c]);
    o4.y = f2bf(v1 * rs * w[c + 1]);
    o4.z = f2bf(v2 * rs * w[c + 2]);
    o4.w = f2bf(v3 * rs * w[c + 3]);
    *(ushort4*)&y2[(size_t)row * DIN + c] = o4;
}

extern "C" void kernel_launch(void* const* d_in, const int* in_sizes, int n_in,
                              void* d_out, int out_size, void* d_ws, size_t ws_size,
                              hipStream_t stream) {
    const float* x         = (const float*)d_in[0];
    const float* ln_w      = (const float*)d_in[1];
    const float* ln_b      = (const float*)d_in[2];
    const float* in_proj_w = (const float*)d_in[3];
    const float* conv1d_w  = (const float*)d_in[4];
    const float* conv1d_b  = (const float*)d_in[5];
    const float* dt_bias   = (const float*)d_in[6];
    const float* A_log     = (const float*)d_in[7];
    const float* Dp        = (const float*)d_in[8];
    const float* rms_w     = (const float*)d_in[9];
    const float* out_proj_w= (const float*)d_in[10];
    const float* conv2d_w  = (const float*)d_in[11];
    const float* conv2d_b  = (const float*)d_in[12];
    const float* bn_g      = (const float*)d_in[13];
    const float* bn_b      = (const float*)d_in[14];
    const float* bn_mean   = (const float*)d_in[15];
    const float* bn_var    = (const float*)d_in[16];

    const int TOK = NB * LL;  // 8192
    const int NTAU = NB * NHH * NCHUNK;  // 2048
    char* ws = (char*)d_ws;
    size_t off = 0;
    auto alloc = [&](size_t bytes) {
        void* p = ws + off;
        off += (bytes + 255) & ~(size_t)255;
        return p;
    };
    u16*   Win   = (u16*)alloc((size_t)NPADW * CIN * 2);
    u16*   Wout  = (u16*)alloc((size_t)CIN * DIN * 2);
    u16*   Wc2   = (u16*)alloc((size_t)CIN * CIN * 2);
    u16*   XN    = (u16*)alloc((size_t)TOK * CIN * 2);
    u16*   ZX    = (u16*)alloc((size_t)TOK * NPADW * 2);
    u16*   XBC   = (u16*)alloc((size_t)TOK * XBCS * 2);
    float* Bcb   = (float*)alloc((size_t)TOK * DST * 4);
    float* Ccb   = (float*)alloc((size_t)TOK * DST * 4);
    float2* DTDA = (float2*)alloc((size_t)TOK * NHH * 8);
    u16*   YI    = (u16*)alloc((size_t)TOK * DIN * 2);
    u16*   DHb   = (u16*)alloc((size_t)NTAU * 4096 * 2);
    u16*   C2G   = (u16*)alloc((size_t)NTAU * 4096 * 2);
    u16*   HPREV = (u16*)alloc((size_t)NTAU * 4096 * 2);
    float* DC    = (float*)alloc((size_t)NTAU * 4);
    u16*   Y2    = (u16*)alloc((size_t)TOK * DIN * 2);
    u16*   OUT1  = (u16*)alloc((size_t)TOK * CIN * 2);
    float* BNSC  = (float*)alloc(CIN * 4);
    float* BNSH  = (float*)alloc(CIN * 4);

    f2bf_pad<<<(NPADW * CIN + 255) / 256, 256, 0, stream>>>(in_proj_w, Win, DPROJ * CIN, NPADW * CIN);
    f2bf_kernel<<<(CIN * DIN + 255) / 256, 256, 0, stream>>>(out_proj_w, Wout, CIN * DIN);
    f2bf_kernel<<<(CIN * CIN + 255) / 256, 256, 0, stream>>>(conv2d_w, Wc2, CIN * CIN);
    bn_prep<<<2, 256, 0, stream>>>(conv2d_b, bn_g, bn_b, bn_mean, bn_var, BNSC, BNSH);

    ln_kernel<<<256, 256, 0, stream>>>(x, ln_w, ln_b, XN);

    gemm_bt<0><<<dim3(NPADW / 128, TOK / 128), 256, 0, stream>>>(XN, Win, ZX, TOK, NPADW, CIN, NPADW,
                                                                 nullptr, nullptr);

    conv1d_fused<<<NB * (LL / CTT), 288, 0, stream>>>(ZX, conv1d_w, conv1d_b, XBC, Bcb, Ccb);
    dt_gemv<<<TOK, 256, 0, stream>>>(XN, in_proj_w, dt_bias, A_log, DTDA);

    ssd_chunk<<<NTAU, 256, 0, stream>>>(Bcb, Ccb, XBC, DTDA, YI, DHb, C2G, DC);
    ssd_carry<<<256, 256, 0, stream>>>(DHb, DC, HPREV);
    ssd_final<<<NTAU, 256, 0, stream>>>(C2G, HPREV, XBC, ZX, Dp, YI);

    rms_kernel<<<TOK, 256, 0, stream>>>(YI, rms_w, Y2);

    gemm_bt<0><<<dim3(CIN / 128, TOK / 128), 256, 0, stream>>>(Y2, Wout, OUT1, TOK, CIN, DIN, CIN,
                                                               nullptr, nullptr);

    gemm_bt<1><<<dim3(TOK / 128, CIN / 128), 256, 0, stream>>>(Wc2, OUT1, d_out, CIN, TOK, CIN, 0,
                                                               BNSC, BNSH);
}

// Round 7
// 194.930 us; speedup vs baseline: 3.7469x; 1.0394x over previous
//
#include <hip/hip_runtime.h>
#include <hip/hip_bf16.h>

// Problem constants
#define NB 8
#define LL 1024        // H*W tokens per batch
#define CIN 512
#define DIN 1024       // d_inner
#define DXBC 1152      // d_inner + 2*d_state
#define DPROJ 2192     // actual in_proj rows
#define NPADW 2304     // padded to 18*128 for GEMM tiles
#define NHH 16
#define HDD 64
#define DST 64
#define NCHUNK 16
#define QCH 64         // chunk length
#define XBCS 1024      // XBC stored stride (x-part only)
#define CTT 8          // conv tokens per block

typedef unsigned short u16;
typedef unsigned int u32;
typedef __bf16 bf16x8 __attribute__((ext_vector_type(8)));
typedef float f32x4 __attribute__((ext_vector_type(4)));
typedef u16 u16x8 __attribute__((ext_vector_type(8)));

__device__ __forceinline__ float bf2f(u16 u) {
    u32 x = ((u32)u) << 16; float f; __builtin_memcpy(&f, &x, 4); return f;
}
__device__ __forceinline__ u16 f2bf(float f) {
    u32 x; __builtin_memcpy(&x, &f, 4);
    u32 r = x + 0x7fff + ((x >> 16) & 1);
    return (u16)(r >> 16);
}

__device__ __forceinline__ void gload16(const u16* g, u16* l) {
    __builtin_amdgcn_global_load_lds((__attribute__((address_space(1))) void*)(g),
                                     (__attribute__((address_space(3))) void*)(l), 16, 0, 0);
}

// swizzled u16 index into a [64][64] bf16 LDS tile (128B rows, 16B-slot XOR swizzle)
__device__ __forceinline__ int swz(int row, int cb) {
    return row * 64 + ((cb ^ ((row & 7) << 4)) >> 1);
}

// ---------- weight converts ----------
__global__ void f2bf_kernel(const float* __restrict__ s, u16* __restrict__ d, int n) {
    int i = blockIdx.x * 256 + threadIdx.x;
    if (i < n) d[i] = f2bf(s[i]);
}
__global__ void f2bf_pad(const float* __restrict__ s, u16* __restrict__ d, int nsrc, int ndst) {
    int i = blockIdx.x * 256 + threadIdx.x;
    if (i < ndst) d[i] = (i < nsrc) ? f2bf(s[i]) : (u16)0;
}
// out_proj weight with rms_w folded per-column: W'[c][d] = W[c][d]*rms_w[d]
__global__ void wout_conv(const float* __restrict__ s, const float* __restrict__ rw,
                          u16* __restrict__ d, int n) {
    int i = blockIdx.x * 256 + threadIdx.x;
    if (i < n) d[i] = f2bf(s[i] * rw[i & (DIN - 1)]);
}
__global__ void bn_prep(const float* __restrict__ cb, const float* __restrict__ g,
                        const float* __restrict__ bb, const float* __restrict__ mean,
                        const float* __restrict__ var, float* __restrict__ scale,
                        float* __restrict__ shift) {
    int i = blockIdx.x * 256 + threadIdx.x;
    if (i < CIN) {
        float rs = rsqrtf(var[i] + 1e-5f);
        float sc = g[i] * rs;
        scale[i] = sc;
        shift[i] = (cb[i] - mean[i]) * sc + bb[i];
    }
}

// ---------- LayerNorm over channels + transpose (B,C,HW) -> (tok, C) bf16 ----------
__global__ __launch_bounds__(256) void ln_kernel(const float* __restrict__ x,
                                                 const float* __restrict__ lw,
                                                 const float* __restrict__ lb,
                                                 u16* __restrict__ xn) {
    __shared__ u16 tile[CIN * 33];
    __shared__ float psum[8][32], psq[8][32], muA[32], rsA[32];
    int bid = blockIdx.x;
    int b = bid >> 5, hw0 = (bid & 31) * 32;
    int t = threadIdx.x;
    int hw = t & 31, cg = t >> 5;
    const float* xb = x + (size_t)b * CIN * LL + hw0 + hw;
    float s = 0.f, sq = 0.f;
    for (int r = 0; r < CIN / 8; ++r) {
        int c = r * 8 + cg;
        float v = xb[(size_t)c * LL];
        s += v; sq += v * v;
        tile[c * 33 + hw] = f2bf(v);
    }
    psum[cg][hw] = s; psq[cg][hw] = sq;
    __syncthreads();
    if (t < 32) {
        float ss = 0.f, qq = 0.f;
        for (int g = 0; g < 8; ++g) { ss += psum[g][t]; qq += psq[g][t]; }
        float mu = ss * (1.f / CIN);
        float var = qq * (1.f / CIN) - mu * mu;
        muA[t] = mu; rsA[t] = rsqrtf(var + 1e-5f);
    }
    __syncthreads();
    for (int r = 0; r < 64; ++r) {
        int idx = r * 256 + t;
        int c = idx & (CIN - 1);
        int hh = idx >> 9;
        float v = (bf2f(tile[c * 33 + hh]) - muA[hh]) * rsA[hh] * lw[c] + lb[c];
        xn[((size_t)(b * LL + hw0 + hh)) * CIN + c] = f2bf(v);
    }
}

// ---------- bf16 MFMA GEMM: BK=64, XOR-swizzled LDS, 2-phase dbuf, XCD-swizzled grid ----------
// EPI 0: bf16 store. EPI 1: conv2d+BN+ReLU remapped f32 store. EPI 2: bf16 store * scale[row].
template <int EPI>
__global__ __launch_bounds__(256) void gemm_bt(const u16* __restrict__ A, const u16* __restrict__ Bw,
                                               void* __restrict__ Cout, int M, int N, int K, int ldc,
                                               int nx,
                                               const float* __restrict__ scale,
                                               const float* __restrict__ shift) {
    __shared__ u16 As[2][128 * 64], Bs[2][128 * 64];
    int t = threadIdx.x;
    int lane = t & 63, wave = t >> 6;
    // bijective XCD swizzle (m204): contiguous chunk of blocks per XCD
    int nblk = gridDim.x;
    int qq = nblk >> 3, rm = nblk & 7;
    int xcd = blockIdx.x & 7, idx = blockIdx.x >> 3;
    int swzb = (xcd < rm ? xcd * (qq + 1) : rm * (qq + 1) + (xcd - rm) * qq) + idx;
    int m0 = (swzb / nx) * 128, n0 = (swzb % nx) * 128;
    int wr = wave >> 1, wc = wave & 1;
    f32x4 acc[4][4];
    for (int m = 0; m < 4; ++m)
        for (int n = 0; n < 4; ++n)
            for (int q = 0; q < 4; ++q) acc[m][n][q] = 0.f;

    const u16* Arow = A + (size_t)m0 * K;
    const u16* Brow = Bw + (size_t)n0 * K;
    int s4 = lane >> 4;
    int rr = lane & 15;

    auto STAGE = [&](int buf, int k0) {
#pragma unroll
        for (int j = 0; j < 4; ++j) {
            int e = j * 256 + t;          // 16B-slot id, 8 slots per row
            int r = e >> 3, sr = e & 7;
            int src = (sr ^ (r & 7)) * 8; // inverse XOR permutation on source
            gload16(Arow + (size_t)r * K + k0 + src, &As[buf][e * 8]);
            gload16(Brow + (size_t)r * K + k0 + src, &Bs[buf][e * 8]);
        }
    };

    STAGE(0, 0);
    __syncthreads();           // compiler drains vmcnt(0) here
    int NK = K >> 6, cur = 0;
    for (int kt = 0; kt < NK; ++kt) {
        if (kt + 1 < NK) STAGE(cur ^ 1, (kt + 1) << 6);   // prefetch next tile
#pragma unroll
        for (int kk = 0; kk < 2; ++kk) {
            bf16x8 af[4], bfr[4];
#pragma unroll
            for (int m = 0; m < 4; ++m) {
                int row = wr * 64 + m * 16 + rr;
                int ss = (kk * 4 + s4) ^ (row & 7);
                af[m] = *(const bf16x8*)&As[cur][row * 64 + ss * 8];
            }
#pragma unroll
            for (int n = 0; n < 4; ++n) {
                int row = wc * 64 + n * 16 + rr;
                int ss = (kk * 4 + s4) ^ (row & 7);
                bfr[n] = *(const bf16x8*)&Bs[cur][row * 64 + ss * 8];
            }
#pragma unroll
            for (int m = 0; m < 4; ++m)
#pragma unroll
                for (int n = 0; n < 4; ++n)
                    acc[m][n] = __builtin_amdgcn_mfma_f32_16x16x32_bf16(af[m], bfr[n], acc[m][n], 0, 0, 0);
        }
        __syncthreads();       // drains next-tile loads (issued above, hidden under compute)
        cur ^= 1;
    }
    int fq = lane >> 4, fr = lane & 15;
#pragma unroll
    for (int m = 0; m < 4; ++m) {
#pragma unroll
        for (int n = 0; n < 4; ++n) {
            int col = n0 + wc * 64 + n * 16 + fr;
#pragma unroll
            for (int q = 0; q < 4; ++q) {
                int row = m0 + wr * 64 + m * 16 + fq * 4 + q;
                float v = acc[m][n][q];
                if (EPI == 0) {
                    ((u16*)Cout)[(size_t)row * ldc + col] = f2bf(v);
                } else if (EPI == 1) {
                    v = v * scale[row] + shift[row];
                    v = v > 0.f ? v : 0.f;
                    ((float*)Cout)[((size_t)(col >> 10)) * (CIN * LL) + (size_t)row * LL + (col & 1023)] = v;
                } else {
                    ((u16*)Cout)[(size_t)row * ldc + col] = f2bf(v * scale[row]);
                }
            }
        }
    }
}

// ---------- depthwise causal conv1d + SiLU, register sliding window ----------
__global__ __launch_bounds__(288) void conv1d_fused(const u16* __restrict__ zx,
                                                    const float* __restrict__ w,
                                                    const float* __restrict__ bias,
                                                    u16* __restrict__ xbc,
                                                    float* __restrict__ Bc, float* __restrict__ Cc) {
    int bid = blockIdx.x;
    int b = bid >> 7;
    int l0 = (bid & 127) * CTT;
    int t = threadIdx.x;
    bool isX = t < 256;
    int ch = isX ? t * 4 : 1024 + (t - 256) * 4;

    float4 wv0 = *(const float4*)&w[(ch + 0) * 4];
    float4 wv1 = *(const float4*)&w[(ch + 1) * 4];
    float4 wv2 = *(const float4*)&w[(ch + 2) * 4];
    float4 wv3 = *(const float4*)&w[(ch + 3) * 4];
    float4 bv = *(const float4*)&bias[ch];

    ushort4 xin[CTT + 3];
    const u16* src = zx + (size_t)(b * LL + l0 - 3) * NPADW + DIN + ch;
#pragma unroll
    for (int i = 0; i < CTT + 3; ++i) {
        ushort4 v = {0, 0, 0, 0};
        if (l0 + i - 3 >= 0) v = *(const ushort4*)(src + (size_t)i * NPADW);
        xin[i] = v;
    }
#pragma unroll
    for (int i = 0; i < CTT; ++i) {
        int tok = b * LL + l0 + i;
        float a0 = bv.x + bf2f(xin[i].x) * wv0.x + bf2f(xin[i + 1].x) * wv0.y +
                   bf2f(xin[i + 2].x) * wv0.z + bf2f(xin[i + 3].x) * wv0.w;
        float a1 = bv.y + bf2f(xin[i].y) * wv1.x + bf2f(xin[i + 1].y) * wv1.y +
                   bf2f(xin[i + 2].y) * wv1.z + bf2f(xin[i + 3].y) * wv1.w;
        float a2 = bv.z + bf2f(xin[i].z) * wv2.x + bf2f(xin[i + 1].z) * wv2.y +
                   bf2f(xin[i + 2].z) * wv2.z + bf2f(xin[i + 3].z) * wv2.w;
        float a3 = bv.w + bf2f(xin[i].w) * wv3.x + bf2f(xin[i + 1].w) * wv3.y +
                   bf2f(xin[i + 2].w) * wv3.z + bf2f(xin[i + 3].w) * wv3.w;
        float s0 = a0 / (1.f + __expf(-a0));
        float s1 = a1 / (1.f + __expf(-a1));
        float s2 = a2 / (1.f + __expf(-a2));
        float s3 = a3 / (1.f + __expf(-a3));
        if (isX) {
            ushort4 o;
            o.x = f2bf(s0); o.y = f2bf(s1); o.z = f2bf(s2); o.w = f2bf(s3);
            *(ushort4*)&xbc[(size_t)tok * XBCS + ch] = o;
        } else {
            int s = ch - 1024;
            float4 o4; o4.x = s0; o4.y = s1; o4.z = s2; o4.w = s3;
            if (s < DST) *(float4*)&Bc[(size_t)tok * DST + s] = o4;
            else         *(float4*)&Cc[(size_t)tok * DST + (s - DST)] = o4;
        }
    }
}

// ---------- dt GEMV: dtv = softplus(dt+bias), a = dtv*(-exp(A_log)) ----------
__global__ __launch_bounds__(256) void dt_gemv(const u16* __restrict__ xn,
                                               const float* __restrict__ wproj,
                                               const float* __restrict__ dt_bias,
                                               const float* __restrict__ A_log,
                                               float2* __restrict__ dtda) {
    int tok = blockIdx.x;
    int t = threadIdx.x;
    int h = t >> 4, part = t & 15;
    const u16* xr = xn + (size_t)tok * CIN;
    const float* wr = wproj + (size_t)(DIN + DXBC + h) * CIN;
    float s = 0.f;
    for (int c0 = part * 32; c0 < part * 32 + 32; c0 += 8) {
        u16x8 xv = *(const u16x8*)&xr[c0];
        float4 w0 = *(const float4*)&wr[c0];
        float4 w1 = *(const float4*)&wr[c0 + 4];
        s += bf2f(xv[0]) * w0.x + bf2f(xv[1]) * w0.y + bf2f(xv[2]) * w0.z + bf2f(xv[3]) * w0.w;
        s += bf2f(xv[4]) * w1.x + bf2f(xv[5]) * w1.y + bf2f(xv[6]) * w1.z + bf2f(xv[7]) * w1.w;
    }
    s += __shfl_xor(s, 1, 64);
    s += __shfl_xor(s, 2, 64);
    s += __shfl_xor(s, 4, 64);
    s += __shfl_xor(s, 8, 64);
    if (part == 0) {
        float si = s + dt_bias[h];
        float dtv = si > 15.f ? si : __logf(1.f + __expf(si));
        float An = -__expf(A_log[h]);
        float2 dd; dd.x = dtv; dd.y = dtv * An;
        dtda[(size_t)tok * NHH + h] = dd;
    }
}

// ---------- SSD K1 ----------
__global__ __launch_bounds__(256) void ssd_chunk(const float* __restrict__ Bcb,
                                                 const float* __restrict__ Ccb,
                                                 const u16* __restrict__ xbc,
                                                 const float2* __restrict__ dtda,
                                                 u16* __restrict__ yi,
                                                 u16* __restrict__ DHb,
                                                 u16* __restrict__ C2G,
                                                 float* __restrict__ DC) {
    __shared__ u16 Bt[4096], Ct[4096], XT[4096], BTt[4096], Gt[4096];
    __shared__ float Sar[64], dtvA[64], wA[64], eSA[64];
    int tau = blockIdx.x;
    int b = tau >> 8, h = (tau >> 4) & 15, c = tau & 15;
    int t0g = b * LL + c * QCH;
    int t = threadIdx.x, lane = t & 63, wave = t >> 6;
    int row = t >> 2, q = t & 3;

    {
        const float* bp = Bcb + (size_t)(t0g + row) * DST + q * 16;
        const float* cp = Ccb + (size_t)(t0g + row) * DST + q * 16;
#pragma unroll
        for (int half = 0; half < 2; ++half) {
            float4 v0 = *(const float4*)(bp + half * 8);
            float4 v1 = *(const float4*)(bp + half * 8 + 4);
            u16x8 o;
            o[0] = f2bf(v0.x); o[1] = f2bf(v0.y); o[2] = f2bf(v0.z); o[3] = f2bf(v0.w);
            o[4] = f2bf(v1.x); o[5] = f2bf(v1.y); o[6] = f2bf(v1.z); o[7] = f2bf(v1.w);
            *(u16x8*)&Bt[swz(row, q * 32 + half * 16)] = o;
            float4 c0 = *(const float4*)(cp + half * 8);
            float4 c1 = *(const float4*)(cp + half * 8 + 4);
            u16x8 oc;
            oc[0] = f2bf(c0.x); oc[1] = f2bf(c0.y); oc[2] = f2bf(c0.z); oc[3] = f2bf(c0.w);
            oc[4] = f2bf(c1.x); oc[5] = f2bf(c1.y); oc[6] = f2bf(c1.z); oc[7] = f2bf(c1.w);
            *(u16x8*)&Ct[swz(row, q * 32 + half * 16)] = oc;
        }
        const u16* xp = xbc + (size_t)(t0g + row) * XBCS + h * HDD + q * 16;
        u16x8 x0 = *(const u16x8*)xp;
        u16x8 x1 = *(const u16x8*)(xp + 8);
#pragma unroll
        for (int e = 0; e < 8; ++e) XT[swz(q * 16 + e, row * 2)] = x0[e];
#pragma unroll
        for (int e = 0; e < 8; ++e) XT[swz(q * 16 + 8 + e, row * 2)] = x1[e];
    }
    if (t < 64) {
        float2 dd = dtda[(size_t)(t0g + t) * NHH + h];
        float s = dd.y;
#pragma unroll
        for (int off = 1; off < 64; off <<= 1) {
            float u = __shfl_up(s, off, 64);
            if (t >= off) s += u;
        }
        float SQ = __shfl(s, 63, 64);
        Sar[t] = s; dtvA[t] = dd.x;
        wA[t] = __expf(SQ - s) * dd.x;
        eSA[t] = __expf(s);
        if (t == 0) DC[tau] = __expf(SQ);
    }
    __syncthreads();

    int R = wave >> 1, Cq = wave & 1, rr = lane & 15, sg = lane >> 4;
    f32x4 g[2][2];
#pragma unroll
    for (int mi = 0; mi < 2; ++mi)
#pragma unroll
        for (int ni = 0; ni < 2; ++ni)
#pragma unroll
            for (int r = 0; r < 4; ++r) g[mi][ni][r] = 0.f;
#pragma unroll
    for (int kt = 0; kt < 2; ++kt) {
        int cb = kt * 64 + sg * 16;
        bf16x8 a0 = *(const bf16x8*)&Ct[swz(R * 32 + rr, cb)];
        bf16x8 a1 = *(const bf16x8*)&Ct[swz(R * 32 + 16 + rr, cb)];
        bf16x8 b0 = *(const bf16x8*)&Bt[swz(Cq * 32 + rr, cb)];
        bf16x8 b1 = *(const bf16x8*)&Bt[swz(Cq * 32 + 16 + rr, cb)];
        g[0][0] = __builtin_amdgcn_mfma_f32_16x16x32_bf16(a0, b0, g[0][0], 0, 0, 0);
        g[0][1] = __builtin_amdgcn_mfma_f32_16x16x32_bf16(a0, b1, g[0][1], 0, 0, 0);
        g[1][0] = __builtin_amdgcn_mfma_f32_16x16x32_bf16(a1, b0, g[1][0], 0, 0, 0);
        g[1][1] = __builtin_amdgcn_mfma_f32_16x16x32_bf16(a1, b1, g[1][1], 0, 0, 0);
    }
#pragma unroll
    for (int mi = 0; mi < 2; ++mi)
#pragma unroll
        for (int ni = 0; ni < 2; ++ni)
#pragma unroll
            for (int r = 0; r < 4; ++r) {
                int i = R * 32 + mi * 16 + sg * 4 + r;
                int j = Cq * 32 + ni * 16 + rr;
                float v = (i >= j) ? g[mi][ni][r] * __expf(Sar[i] - Sar[j]) * dtvA[j] : 0.f;
                Gt[swz(i, j * 2)] = f2bf(v);
            }
#pragma unroll
    for (int half = 0; half < 2; ++half) {
        u16x8 cv = *(const u16x8*)&Ct[swz(row, q * 32 + half * 16)];
        u16x8 ov;
#pragma unroll
        for (int e = 0; e < 8; ++e) ov[e] = f2bf(bf2f(cv[e]) * eSA[row]);
        *(u16x8*)&C2G[(size_t)tau * 4096 + row * 64 + q * 16 + half * 8] = ov;
        u16x8 bv = *(const u16x8*)&Bt[swz(row, q * 32 + half * 16)];
#pragma unroll
        for (int e = 0; e < 8; ++e)
            BTt[swz(q * 16 + half * 8 + e, row * 2)] = f2bf(bf2f(bv[e]) * wA[row]);
    }
    __syncthreads();

    f32x4 y[2][2], dh[2][2];
#pragma unroll
    for (int mi = 0; mi < 2; ++mi)
#pragma unroll
        for (int ni = 0; ni < 2; ++ni)
#pragma unroll
            for (int r = 0; r < 4; ++r) { y[mi][ni][r] = 0.f; dh[mi][ni][r] = 0.f; }
#pragma unroll
    for (int kt = 0; kt < 2; ++kt) {
        int cb = kt * 64 + sg * 16;
        bf16x8 xb0 = *(const bf16x8*)&XT[swz(Cq * 32 + rr, cb)];
        bf16x8 xb1 = *(const bf16x8*)&XT[swz(Cq * 32 + 16 + rr, cb)];
        bf16x8 ga0 = *(const bf16x8*)&Gt[swz(R * 32 + rr, cb)];
        bf16x8 ga1 = *(const bf16x8*)&Gt[swz(R * 32 + 16 + rr, cb)];
        bf16x8 ba0 = *(const bf16x8*)&BTt[swz(R * 32 + rr, cb)];
        bf16x8 ba1 = *(const bf16x8*)&BTt[swz(R * 32 + 16 + rr, cb)];
        y[0][0] = __builtin_amdgcn_mfma_f32_16x16x32_bf16(ga0, xb0, y[0][0], 0, 0, 0);
        y[0][1] = __builtin_amdgcn_mfma_f32_16x16x32_bf16(ga0, xb1, y[0][1], 0, 0, 0);
        y[1][0] = __builtin_amdgcn_mfma_f32_16x16x32_bf16(ga1, xb0, y[1][0], 0, 0, 0);
        y[1][1] = __builtin_amdgcn_mfma_f32_16x16x32_bf16(ga1, xb1, y[1][1], 0, 0, 0);
        dh[0][0] = __builtin_amdgcn_mfma_f32_16x16x32_bf16(ba0, xb0, dh[0][0], 0, 0, 0);
        dh[0][1] = __builtin_amdgcn_mfma_f32_16x16x32_bf16(ba0, xb1, dh[0][1], 0, 0, 0);
        dh[1][0] = __builtin_amdgcn_mfma_f32_16x16x32_bf16(ba1, xb0, dh[1][0], 0, 0, 0);
        dh[1][1] = __builtin_amdgcn_mfma_f32_16x16x32_bf16(ba1, xb1, dh[1][1], 0, 0, 0);
    }
#pragma unroll
    for (int mi = 0; mi < 2; ++mi)
#pragma unroll
        for (int ni = 0; ni < 2; ++ni)
#pragma unroll
            for (int r = 0; r < 4; ++r) {
                int i = R * 32 + mi * 16 + sg * 4 + r;
                int p = Cq * 32 + ni * 16 + rr;
                yi[(size_t)(t0g + i) * DIN + h * HDD + p] = f2bf(y[mi][ni][r]);
                DHb[(size_t)tau * 4096 + i * 64 + p] = f2bf(dh[mi][ni][r]);
            }
}

// ---------- SSD K2 ----------
__global__ __launch_bounds__(256) void ssd_carry(const u16* __restrict__ DHb,
                                                 const float* __restrict__ DC,
                                                 u16* __restrict__ HPREV) {
    int bid = blockIdx.x;
    int bh = bid >> 1, ph = bid & 1;
    int t = threadIdx.x;
    int s = t >> 2, p0 = ph * 32 + (t & 3) * 8;
    size_t base = (size_t)bh * NCHUNK * 4096 + s * 64 + p0;
    float Hv[8] = {0.f, 0.f, 0.f, 0.f, 0.f, 0.f, 0.f, 0.f};
    for (int c = 0; c < NCHUNK; ++c) {
        size_t off = base + (size_t)c * 4096;
        u16x8 hp;
#pragma unroll
        for (int e = 0; e < 8; ++e) hp[e] = f2bf(Hv[e]);
        *(u16x8*)&HPREV[off] = hp;
        float d = DC[bh * NCHUNK + c];
        u16x8 dv = *(const u16x8*)&DHb[off];
#pragma unroll
        for (int e = 0; e < 8; ++e) Hv[e] = d * Hv[e] + bf2f(dv[e]);
    }
}

// ---------- SSD K3 ----------
__global__ __launch_bounds__(256) void ssd_final(const u16* __restrict__ C2G,
                                                 const u16* __restrict__ HPREV,
                                                 const u16* __restrict__ xbc,
                                                 const u16* __restrict__ zx,
                                                 const float* __restrict__ Dp,
                                                 u16* __restrict__ yi) {
    __shared__ u16 C2t[4096], HT[4096];
    int tau = blockIdx.x;
    int b = tau >> 8, h = (tau >> 4) & 15, c = tau & 15;
    int t0g = b * LL + c * QCH;
    int t = threadIdx.x, lane = t & 63, wave = t >> 6;
    int row = t >> 2, q = t & 3;
#pragma unroll
    for (int half = 0; half < 2; ++half) {
        u16x8 cv = *(const u16x8*)&C2G[(size_t)tau * 4096 + row * 64 + q * 16 + half * 8];
        *(u16x8*)&C2t[swz(row, q * 32 + half * 16)] = cv;
        u16x8 hv = *(const u16x8*)&HPREV[(size_t)tau * 4096 + row * 64 + q * 16 + half * 8];
#pragma unroll
        for (int e = 0; e < 8; ++e) HT[swz(q * 16 + half * 8 + e, row * 2)] = hv[e];
    }
    __syncthreads();
    int R = wave >> 1, Cq = wave & 1, rr = lane & 15, sg = lane >> 4;
    float Dh = Dp[h];
    f32x4 acc[2][2];
#pragma unroll
    for (int mi = 0; mi < 2; ++mi)
#pragma unroll
        for (int ni = 0; ni < 2; ++ni)
#pragma unroll
            for (int r = 0; r < 4; ++r) {
                int i = R * 32 + mi * 16 + sg * 4 + r;
                int p = Cq * 32 + ni * 16 + rr;
                acc[mi][ni][r] = bf2f(yi[(size_t)(t0g + i) * DIN + h * HDD + p]);
            }
#pragma unroll
    for (int kt = 0; kt < 2; ++kt) {
        int cb = kt * 64 + sg * 16;
        bf16x8 a0 = *(const bf16x8*)&C2t[swz(R * 32 + rr, cb)];
        bf16x8 a1 = *(const bf16x8*)&C2t[swz(R * 32 + 16 + rr, cb)];
        bf16x8 b0 = *(const bf16x8*)&HT[swz(Cq * 32 + rr, cb)];
        bf16x8 b1 = *(const bf16x8*)&HT[swz(Cq * 32 + 16 + rr, cb)];
        acc[0][0] = __builtin_amdgcn_mfma_f32_16x16x32_bf16(a0, b0, acc[0][0], 0, 0, 0);
        acc[0][1] = __builtin_amdgcn_mfma_f32_16x16x32_bf16(a0, b1, acc[0][1], 0, 0, 0);
        acc[1][0] = __builtin_amdgcn_mfma_f32_16x16x32_bf16(a1, b0, acc[1][0], 0, 0, 0);
        acc[1][1] = __builtin_amdgcn_mfma_f32_16x16x32_bf16(a1, b1, acc[1][1], 0, 0, 0);
    }
#pragma unroll
    for (int mi = 0; mi < 2; ++mi)
#pragma unroll
        for (int ni = 0; ni < 2; ++ni)
#pragma unroll
            for (int r = 0; r < 4; ++r) {
                int i = R * 32 + mi * 16 + sg * 4 + r;
                int p = Cq * 32 + ni * 16 + rr;
                size_t tok = t0g + i;
                int col = h * HDD + p;
                float xf = bf2f(xbc[tok * XBCS + col]);
                float zf = bf2f(zx[tok * NPADW + col]);
                float yo = (acc[mi][ni][r] + Dh * xf) * (zf / (1.f + __expf(-zf)));
                yi[tok * DIN + col] = f2bf(yo);
            }
}

// ---------- per-token RMS scale: rs = rsqrt(mean(y^2)+eps) ----------
__global__ __launch_bounds__(256) void rs_kernel(const u16* __restrict__ y,
                                                 float* __restrict__ rs) {
    int row = blockIdx.x, t = threadIdx.x;
    ushort4 uv = *(const ushort4*)&y[(size_t)row * DIN + t * 4];
    float v0 = bf2f(uv.x), v1 = bf2f(uv.y), v2 = bf2f(uv.z), v3 = bf2f(uv.w);
    float ss = v0 * v0 + v1 * v1 + v2 * v2 + v3 * v3;
#pragma unroll
    for (int o = 1; o < 64; o <<= 1) ss += __shfl_xor(ss, o, 64);
    __shared__ float ps[4];
    if ((t & 63) == 0) ps[t >> 6] = ss;
    __syncthreads();
    if (t == 0) {
        float tot = ps[0] + ps[1] + ps[2] + ps[3];
        rs[row] = rsqrtf(tot * (1.f / DIN) + 1e-5f);
    }
}

extern "C" void kernel_launch(void* const* d_in, const int* in_sizes, int n_in,
                              void* d_out, int out_size, void* d_ws, size_t ws_size,
                              hipStream_t stream) {
    const float* x         = (const float*)d_in[0];
    const float* ln_w      = (const float*)d_in[1];
    const float* ln_b      = (const float*)d_in[2];
    const float* in_proj_w = (const float*)d_in[3];
    const float* conv1d_w  = (const float*)d_in[4];
    const float* conv1d_b  = (const float*)d_in[5];
    const float* dt_bias   = (const float*)d_in[6];
    const float* A_log     = (const float*)d_in[7];
    const float* Dp        = (const float*)d_in[8];
    const float* rms_w     = (const float*)d_in[9];
    const float* out_proj_w= (const float*)d_in[10];
    const float* conv2d_w  = (const float*)d_in[11];
    const float* conv2d_b  = (const float*)d_in[12];
    const float* bn_g      = (const float*)d_in[13];
    const float* bn_b      = (const float*)d_in[14];
    const float* bn_mean   = (const float*)d_in[15];
    const float* bn_var    = (const float*)d_in[16];

    const int TOK = NB * LL;  // 8192
    const int NTAU = NB * NHH * NCHUNK;  // 2048
    char* ws = (char*)d_ws;
    size_t off = 0;
    auto alloc = [&](size_t bytes) {
        void* p = ws + off;
        off += (bytes + 255) & ~(size_t)255;
        return p;
    };
    u16*   Win   = (u16*)alloc((size_t)NPADW * CIN * 2);
    u16*   Wout  = (u16*)alloc((size_t)CIN * DIN * 2);
    u16*   Wc2   = (u16*)alloc((size_t)CIN * CIN * 2);
    u16*   XN    = (u16*)alloc((size_t)TOK * CIN * 2);
    u16*   ZX    = (u16*)alloc((size_t)TOK * NPADW * 2);
    u16*   XBC   = (u16*)alloc((size_t)TOK * XBCS * 2);
    float* Bcb   = (float*)alloc((size_t)TOK * DST * 4);
    float* Ccb   = (float*)alloc((size_t)TOK * DST * 4);
    float2* DTDA = (float2*)alloc((size_t)TOK * NHH * 8);
    u16*   YI    = (u16*)alloc((size_t)TOK * DIN * 2);
    u16*   DHb   = (u16*)alloc((size_t)NTAU * 4096 * 2);
    u16*   C2G   = (u16*)alloc((size_t)NTAU * 4096 * 2);
    u16*   HPREV = (u16*)alloc((size_t)NTAU * 4096 * 2);
    float* DC    = (float*)alloc((size_t)NTAU * 4);
    float* RS    = (float*)alloc((size_t)TOK * 4);
    u16*   OUT1  = (u16*)alloc((size_t)TOK * CIN * 2);
    float* BNSC  = (float*)alloc(CIN * 4);
    float* BNSH  = (float*)alloc(CIN * 4);

    f2bf_pad<<<(NPADW * CIN + 255) / 256, 256, 0, stream>>>(in_proj_w, Win, DPROJ * CIN, NPADW * CIN);
    wout_conv<<<(CIN * DIN + 255) / 256, 256, 0, stream>>>(out_proj_w, rms_w, Wout, CIN * DIN);
    f2bf_kernel<<<(CIN * CIN + 255) / 256, 256, 0, stream>>>(conv2d_w, Wc2, CIN * CIN);
    bn_prep<<<2, 256, 0, stream>>>(conv2d_b, bn_g, bn_b, bn_mean, bn_var, BNSC, BNSH);

    ln_kernel<<<256, 256, 0, stream>>>(x, ln_w, ln_b, XN);

    gemm_bt<0><<<(TOK / 128) * (NPADW / 128), 256, 0, stream>>>(XN, Win, ZX, TOK, NPADW, CIN, NPADW,
                                                                NPADW / 128, nullptr, nullptr);

    conv1d_fused<<<NB * (LL / CTT), 288, 0, stream>>>(ZX, conv1d_w, conv1d_b, XBC, Bcb, Ccb);
    dt_gemv<<<TOK, 256, 0, stream>>>(XN, in_proj_w, dt_bias, A_log, DTDA);

    ssd_chunk<<<NTAU, 256, 0, stream>>>(Bcb, Ccb, XBC, DTDA, YI, DHb, C2G, DC);
    ssd_carry<<<256, 256, 0, stream>>>(DHb, DC, HPREV);
    ssd_final<<<NTAU, 256, 0, stream>>>(C2G, HPREV, XBC, ZX, Dp, YI);

    rs_kernel<<<TOK, 256, 0, stream>>>(YI, RS);

    gemm_bt<2><<<(TOK / 128) * (CIN / 128), 256, 0, stream>>>(YI, Wout, OUT1, TOK, CIN, DIN, CIN,
                                                              CIN / 128, RS, nullptr);

    gemm_bt<1><<<(CIN / 128) * (TOK / 128), 256, 0, stream>>>(Wc2, OUT1, d_out, CIN, TOK, CIN, 0,
                                                              TOK / 128, BNSC, BNSH);
}

// Round 8
// 192.326 us; speedup vs baseline: 3.7977x; 1.0135x over previous
//
#include <hip/hip_runtime.h>
#include <hip/hip_bf16.h>

// Problem constants
#define NB 8
#define LL 1024        // H*W tokens per batch
#define CIN 512
#define DIN 1024       // d_inner
#define DXBC 1152      // d_inner + 2*d_state
#define DPROJ 2192     // actual in_proj rows
#define NPADW 2304     // padded to 18*128 for GEMM tiles
#define NHH 16
#define HDD 64
#define DST 64
#define NCHUNK 16
#define QCH 64         // chunk length
#define XBCS 1024      // XBC stored stride (x-part only)
#define CTT 8          // conv tokens per block

typedef unsigned short u16;
typedef unsigned int u32;
typedef __bf16 bf16x8 __attribute__((ext_vector_type(8)));
typedef float f32x4 __attribute__((ext_vector_type(4)));
typedef u16 u16x8 __attribute__((ext_vector_type(8)));

__device__ __forceinline__ float bf2f(u16 u) {
    u32 x = ((u32)u) << 16; float f; __builtin_memcpy(&f, &x, 4); return f;
}
__device__ __forceinline__ u16 f2bf(float f) {
    u32 x; __builtin_memcpy(&x, &f, 4);
    u32 r = x + 0x7fff + ((x >> 16) & 1);
    return (u16)(r >> 16);
}

__device__ __forceinline__ void gload16(const u16* g, u16* l) {
    __builtin_amdgcn_global_load_lds((__attribute__((address_space(1))) void*)(g),
                                     (__attribute__((address_space(3))) void*)(l), 16, 0, 0);
}

// swizzled u16 index into a [64][64] bf16 LDS tile (128B rows, 16B-slot XOR swizzle)
__device__ __forceinline__ int swz(int row, int cb) {
    return row * 64 + ((cb ^ ((row & 7) << 4)) >> 1);
}

// ---------- weight converts ----------
__global__ void f2bf_kernel(const float* __restrict__ s, u16* __restrict__ d, int n) {
    int i = blockIdx.x * 256 + threadIdx.x;
    if (i < n) d[i] = f2bf(s[i]);
}
__global__ void f2bf_pad(const float* __restrict__ s, u16* __restrict__ d, int nsrc, int ndst) {
    int i = blockIdx.x * 256 + threadIdx.x;
    if (i < ndst) d[i] = (i < nsrc) ? f2bf(s[i]) : (u16)0;
}
// WoutT[d][c] = out_proj_w[c][d] * rms_w[d]   (LDS-tiled transpose, 64x64 tiles)
__global__ __launch_bounds__(256) void woutT_conv(const float* __restrict__ s,
                                                  const float* __restrict__ rw,
                                                  u16* __restrict__ dt) {
    __shared__ float tile[64][65];
    int bc = blockIdx.x & 7, bd = blockIdx.x >> 3;   // c-tile (512/64=8), d-tile (1024/64=16)
    int c0 = bc * 64, d0 = bd * 64;
    int t = threadIdx.x;
    int r4 = t >> 6, cc = t & 63;
#pragma unroll
    for (int rr = 0; rr < 16; ++rr) {
        int row = r4 * 16 + rr;
        tile[row][cc] = s[(size_t)(c0 + row) * DIN + d0 + cc];
    }
    __syncthreads();
#pragma unroll
    for (int rr = 0; rr < 16; ++rr) {
        int row = r4 * 16 + rr;   // d within tile
        dt[(size_t)(d0 + row) * CIN + c0 + cc] = f2bf(tile[cc][row] * rw[d0 + row]);
    }
}
__global__ void bn_prep(const float* __restrict__ cb, const float* __restrict__ g,
                        const float* __restrict__ bb, const float* __restrict__ mean,
                        const float* __restrict__ var, float* __restrict__ scale,
                        float* __restrict__ shift) {
    int i = blockIdx.x * 256 + threadIdx.x;
    if (i < CIN) {
        float rs = rsqrtf(var[i] + 1e-5f);
        float sc = g[i] * rs;
        scale[i] = sc;
        shift[i] = (cb[i] - mean[i]) * sc + bb[i];
    }
}

// ---------- LayerNorm over channels + transpose (B,C,HW) -> (tok, C) bf16 ----------
__global__ __launch_bounds__(256) void ln_kernel(const float* __restrict__ x,
                                                 const float* __restrict__ lw,
                                                 const float* __restrict__ lb,
                                                 u16* __restrict__ xn) {
    __shared__ u16 tile[CIN * 33];
    __shared__ float psum[8][32], psq[8][32], muA[32], rsA[32];
    int bid = blockIdx.x;
    int b = bid >> 5, hw0 = (bid & 31) * 32;
    int t = threadIdx.x;
    int hw = t & 31, cg = t >> 5;
    const float* xb = x + (size_t)b * CIN * LL + hw0 + hw;
    float s = 0.f, sq = 0.f;
    for (int r = 0; r < CIN / 8; ++r) {
        int c = r * 8 + cg;
        float v = xb[(size_t)c * LL];
        s += v; sq += v * v;
        tile[c * 33 + hw] = f2bf(v);
    }
    psum[cg][hw] = s; psq[cg][hw] = sq;
    __syncthreads();
    if (t < 32) {
        float ss = 0.f, qq = 0.f;
        for (int g = 0; g < 8; ++g) { ss += psum[g][t]; qq += psq[g][t]; }
        float mu = ss * (1.f / CIN);
        float var = qq * (1.f / CIN) - mu * mu;
        muA[t] = mu; rsA[t] = rsqrtf(var + 1e-5f);
    }
    __syncthreads();
    for (int r = 0; r < 64; ++r) {
        int idx = r * 256 + t;
        int c = idx & (CIN - 1);
        int hh = idx >> 9;
        float v = (bf2f(tile[c * 33 + hh]) - muA[hh]) * rsA[hh] * lw[c] + lb[c];
        xn[((size_t)(b * LL + hw0 + hh)) * CIN + c] = f2bf(v);
    }
}

// ---------- bf16 MFMA GEMM: BK=64, XOR-swizzled LDS, 2-phase dbuf with COUNTED vmcnt ----------
// EPI 0: bf16 store row-major ldc.
// EPI 1: v*rsc[col] -> BN(scale/shift[row]) -> ReLU -> remapped f32 store (d_out layout).
template <int EPI>
__global__ __launch_bounds__(256) void gemm_bt(const u16* __restrict__ A, const u16* __restrict__ Bw,
                                               void* __restrict__ Cout, int M, int N, int K, int ldc,
                                               int nx,
                                               const float* __restrict__ scale,
                                               const float* __restrict__ shift,
                                               const float* __restrict__ rsc) {
    __shared__ u16 As[2][128 * 64], Bs[2][128 * 64];
    int t = threadIdx.x;
    int lane = t & 63, wave = t >> 6;
    // bijective XCD swizzle (m204)
    int nblk = gridDim.x;
    int qq = nblk >> 3, rm = nblk & 7;
    int xcd = blockIdx.x & 7, idx = blockIdx.x >> 3;
    int swzb = (xcd < rm ? xcd * (qq + 1) : rm * (qq + 1) + (xcd - rm) * qq) + idx;
    int m0 = (swzb / nx) * 128, n0 = (swzb % nx) * 128;
    int wr = wave >> 1, wc = wave & 1;
    f32x4 acc[4][4];
    for (int m = 0; m < 4; ++m)
        for (int n = 0; n < 4; ++n)
            for (int q = 0; q < 4; ++q) acc[m][n][q] = 0.f;

    const u16* Arow = A + (size_t)m0 * K;
    const u16* Brow = Bw + (size_t)n0 * K;
    int s4 = lane >> 4;
    int rr = lane & 15;

    auto STAGE = [&](int buf, int k0) {
#pragma unroll
        for (int j = 0; j < 4; ++j) {
            int e = j * 256 + t;          // 16B-slot id, 8 slots per row
            int r = e >> 3, sr = e & 7;
            int src = (sr ^ (r & 7)) * 8; // inverse XOR permutation on source
            gload16(Arow + (size_t)r * K + k0 + src, &As[buf][e * 8]);
            gload16(Brow + (size_t)r * K + k0 + src, &Bs[buf][e * 8]);
        }
    };

    STAGE(0, 0);                       // 8 loads/thread in flight
    int NK = K >> 6, cur = 0;
    for (int kt = 0; kt < NK; ++kt) {
        if (kt + 1 < NK) {
            STAGE(cur ^ 1, (kt + 1) << 6);             // +8 loads (next tile)
            asm volatile("s_waitcnt vmcnt(8)" ::: "memory");  // cur tile's 8 done; next 8 fly
        } else {
            asm volatile("s_waitcnt vmcnt(0)" ::: "memory");
        }
        __builtin_amdgcn_s_barrier();   // all waves' cur-tile loads landed
        __builtin_amdgcn_sched_barrier(0);
#pragma unroll
        for (int kk = 0; kk < 2; ++kk) {
            bf16x8 af[4], bfr[4];
#pragma unroll
            for (int m = 0; m < 4; ++m) {
                int row = wr * 64 + m * 16 + rr;
                int ss = (kk * 4 + s4) ^ (row & 7);
                af[m] = *(const bf16x8*)&As[cur][row * 64 + ss * 8];
            }
#pragma unroll
            for (int n = 0; n < 4; ++n) {
                int row = wc * 64 + n * 16 + rr;
                int ss = (kk * 4 + s4) ^ (row & 7);
                bfr[n] = *(const bf16x8*)&Bs[cur][row * 64 + ss * 8];
            }
#pragma unroll
            for (int m = 0; m < 4; ++m)
#pragma unroll
                for (int n = 0; n < 4; ++n)
                    acc[m][n] = __builtin_amdgcn_mfma_f32_16x16x32_bf16(af[m], bfr[n], acc[m][n], 0, 0, 0);
        }
        __builtin_amdgcn_s_barrier();   // protect buf[cur] before next iter's STAGE overwrites it
        cur ^= 1;
    }
    int fq = lane >> 4, fr = lane & 15;
#pragma unroll
    for (int m = 0; m < 4; ++m) {
#pragma unroll
        for (int n = 0; n < 4; ++n) {
            int col = n0 + wc * 64 + n * 16 + fr;
#pragma unroll
            for (int q = 0; q < 4; ++q) {
                int row = m0 + wr * 64 + m * 16 + fq * 4 + q;
                float v = acc[m][n][q];
                if (EPI == 0) {
                    ((u16*)Cout)[(size_t)row * ldc + col] = f2bf(v);
                } else {
                    v = v * rsc[col];
                    v = v * scale[row] + shift[row];
                    v = v > 0.f ? v : 0.f;
                    // row = out-channel o, col = token (b*1024+hw)
                    ((float*)Cout)[((size_t)(col >> 10)) * (CIN * LL) + (size_t)row * LL + (col & 1023)] = v;
                }
            }
        }
    }
}

// ---------- depthwise causal conv1d + SiLU, register sliding window ----------
__global__ __launch_bounds__(288) void conv1d_fused(const u16* __restrict__ zx,
                                                    const float* __restrict__ w,
                                                    const float* __restrict__ bias,
                                                    u16* __restrict__ xbc,
                                                    float* __restrict__ Bc, float* __restrict__ Cc) {
    int bid = blockIdx.x;
    int b = bid >> 7;
    int l0 = (bid & 127) * CTT;
    int t = threadIdx.x;
    bool isX = t < 256;
    int ch = isX ? t * 4 : 1024 + (t - 256) * 4;

    float4 wv0 = *(const float4*)&w[(ch + 0) * 4];
    float4 wv1 = *(const float4*)&w[(ch + 1) * 4];
    float4 wv2 = *(const float4*)&w[(ch + 2) * 4];
    float4 wv3 = *(const float4*)&w[(ch + 3) * 4];
    float4 bv = *(const float4*)&bias[ch];

    ushort4 xin[CTT + 3];
    const u16* src = zx + (size_t)(b * LL + l0 - 3) * NPADW + DIN + ch;
#pragma unroll
    for (int i = 0; i < CTT + 3; ++i) {
        ushort4 v = {0, 0, 0, 0};
        if (l0 + i - 3 >= 0) v = *(const ushort4*)(src + (size_t)i * NPADW);
        xin[i] = v;
    }
#pragma unroll
    for (int i = 0; i < CTT; ++i) {
        int tok = b * LL + l0 + i;
        float a0 = bv.x + bf2f(xin[i].x) * wv0.x + bf2f(xin[i + 1].x) * wv0.y +
                   bf2f(xin[i + 2].x) * wv0.z + bf2f(xin[i + 3].x) * wv0.w;
        float a1 = bv.y + bf2f(xin[i].y) * wv1.x + bf2f(xin[i + 1].y) * wv1.y +
                   bf2f(xin[i + 2].y) * wv1.z + bf2f(xin[i + 3].y) * wv1.w;
        float a2 = bv.z + bf2f(xin[i].z) * wv2.x + bf2f(xin[i + 1].z) * wv2.y +
                   bf2f(xin[i + 2].z) * wv2.z + bf2f(xin[i + 3].z) * wv2.w;
        float a3 = bv.w + bf2f(xin[i].w) * wv3.x + bf2f(xin[i + 1].w) * wv3.y +
                   bf2f(xin[i + 2].w) * wv3.z + bf2f(xin[i + 3].w) * wv3.w;
        float s0 = a0 / (1.f + __expf(-a0));
        float s1 = a1 / (1.f + __expf(-a1));
        float s2 = a2 / (1.f + __expf(-a2));
        float s3 = a3 / (1.f + __expf(-a3));
        if (isX) {
            ushort4 o;
            o.x = f2bf(s0); o.y = f2bf(s1); o.z = f2bf(s2); o.w = f2bf(s3);
            *(ushort4*)&xbc[(size_t)tok * XBCS + ch] = o;
        } else {
            int s = ch - 1024;
            float4 o4; o4.x = s0; o4.y = s1; o4.z = s2; o4.w = s3;
            if (s < DST) *(float4*)&Bc[(size_t)tok * DST + s] = o4;
            else         *(float4*)&Cc[(size_t)tok * DST + (s - DST)] = o4;
        }
    }
}

// ---------- dt GEMV ----------
__global__ __launch_bounds__(256) void dt_gemv(const u16* __restrict__ xn,
                                               const float* __restrict__ wproj,
                                               const float* __restrict__ dt_bias,
                                               const float* __restrict__ A_log,
                                               float2* __restrict__ dtda) {
    int tok = blockIdx.x;
    int t = threadIdx.x;
    int h = t >> 4, part = t & 15;
    const u16* xr = xn + (size_t)tok * CIN;
    const float* wr = wproj + (size_t)(DIN + DXBC + h) * CIN;
    float s = 0.f;
    for (int c0 = part * 32; c0 < part * 32 + 32; c0 += 8) {
        u16x8 xv = *(const u16x8*)&xr[c0];
        float4 w0 = *(const float4*)&wr[c0];
        float4 w1 = *(const float4*)&wr[c0 + 4];
        s += bf2f(xv[0]) * w0.x + bf2f(xv[1]) * w0.y + bf2f(xv[2]) * w0.z + bf2f(xv[3]) * w0.w;
        s += bf2f(xv[4]) * w1.x + bf2f(xv[5]) * w1.y + bf2f(xv[6]) * w1.z + bf2f(xv[7]) * w1.w;
    }
    s += __shfl_xor(s, 1, 64);
    s += __shfl_xor(s, 2, 64);
    s += __shfl_xor(s, 4, 64);
    s += __shfl_xor(s, 8, 64);
    if (part == 0) {
        float si = s + dt_bias[h];
        float dtv = si > 15.f ? si : __logf(1.f + __expf(si));
        float An = -__expf(A_log[h]);
        float2 dd; dd.x = dtv; dd.y = dtv * An;
        dtda[(size_t)tok * NHH + h] = dd;
    }
}

// ---------- SSD K1 ----------
__global__ __launch_bounds__(256) void ssd_chunk(const float* __restrict__ Bcb,
                                                 const float* __restrict__ Ccb,
                                                 const u16* __restrict__ xbc,
                                                 const float2* __restrict__ dtda,
                                                 u16* __restrict__ yi,
                                                 u16* __restrict__ DHb,
                                                 u16* __restrict__ C2G,
                                                 float* __restrict__ DC) {
    __shared__ u16 Bt[4096], Ct[4096], XT[4096], BTt[4096], Gt[4096];
    __shared__ float Sar[64], dtvA[64], wA[64], eSA[64];
    int tau = blockIdx.x;
    int b = tau >> 8, h = (tau >> 4) & 15, c = tau & 15;
    int t0g = b * LL + c * QCH;
    int t = threadIdx.x, lane = t & 63, wave = t >> 6;
    int row = t >> 2, q = t & 3;

    {
        const float* bp = Bcb + (size_t)(t0g + row) * DST + q * 16;
        const float* cp = Ccb + (size_t)(t0g + row) * DST + q * 16;
#pragma unroll
        for (int half = 0; half < 2; ++half) {
            float4 v0 = *(const float4*)(bp + half * 8);
            float4 v1 = *(const float4*)(bp + half * 8 + 4);
            u16x8 o;
            o[0] = f2bf(v0.x); o[1] = f2bf(v0.y); o[2] = f2bf(v0.z); o[3] = f2bf(v0.w);
            o[4] = f2bf(v1.x); o[5] = f2bf(v1.y); o[6] = f2bf(v1.z); o[7] = f2bf(v1.w);
            *(u16x8*)&Bt[swz(row, q * 32 + half * 16)] = o;
            float4 c0 = *(const float4*)(cp + half * 8);
            float4 c1 = *(const float4*)(cp + half * 8 + 4);
            u16x8 oc;
            oc[0] = f2bf(c0.x); oc[1] = f2bf(c0.y); oc[2] = f2bf(c0.z); oc[3] = f2bf(c0.w);
            oc[4] = f2bf(c1.x); oc[5] = f2bf(c1.y); oc[6] = f2bf(c1.z); oc[7] = f2bf(c1.w);
            *(u16x8*)&Ct[swz(row, q * 32 + half * 16)] = oc;
        }
        const u16* xp = xbc + (size_t)(t0g + row) * XBCS + h * HDD + q * 16;
        u16x8 x0 = *(const u16x8*)xp;
        u16x8 x1 = *(const u16x8*)(xp + 8);
#pragma unroll
        for (int e = 0; e < 8; ++e) XT[swz(q * 16 + e, row * 2)] = x0[e];
#pragma unroll
        for (int e = 0; e < 8; ++e) XT[swz(q * 16 + 8 + e, row * 2)] = x1[e];
    }
    if (t < 64) {
        float2 dd = dtda[(size_t)(t0g + t) * NHH + h];
        float s = dd.y;
#pragma unroll
        for (int off = 1; off < 64; off <<= 1) {
            float u = __shfl_up(s, off, 64);
            if (t >= off) s += u;
        }
        float SQ = __shfl(s, 63, 64);
        Sar[t] = s; dtvA[t] = dd.x;
        wA[t] = __expf(SQ - s) * dd.x;
        eSA[t] = __expf(s);
        if (t == 0) DC[tau] = __expf(SQ);
    }
    __syncthreads();

    int R = wave >> 1, Cq = wave & 1, rr = lane & 15, sg = lane >> 4;
    f32x4 g[2][2];
#pragma unroll
    for (int mi = 0; mi < 2; ++mi)
#pragma unroll
        for (int ni = 0; ni < 2; ++ni)
#pragma unroll
            for (int r = 0; r < 4; ++r) g[mi][ni][r] = 0.f;
#pragma unroll
    for (int kt = 0; kt < 2; ++kt) {
        int cb = kt * 64 + sg * 16;
        bf16x8 a0 = *(const bf16x8*)&Ct[swz(R * 32 + rr, cb)];
        bf16x8 a1 = *(const bf16x8*)&Ct[swz(R * 32 + 16 + rr, cb)];
        bf16x8 b0 = *(const bf16x8*)&Bt[swz(Cq * 32 + rr, cb)];
        bf16x8 b1 = *(const bf16x8*)&Bt[swz(Cq * 32 + 16 + rr, cb)];
        g[0][0] = __builtin_amdgcn_mfma_f32_16x16x32_bf16(a0, b0, g[0][0], 0, 0, 0);
        g[0][1] = __builtin_amdgcn_mfma_f32_16x16x32_bf16(a0, b1, g[0][1], 0, 0, 0);
        g[1][0] = __builtin_amdgcn_mfma_f32_16x16x32_bf16(a1, b0, g[1][0], 0, 0, 0);
        g[1][1] = __builtin_amdgcn_mfma_f32_16x16x32_bf16(a1, b1, g[1][1], 0, 0, 0);
    }
#pragma unroll
    for (int mi = 0; mi < 2; ++mi)
#pragma unroll
        for (int ni = 0; ni < 2; ++ni)
#pragma unroll
            for (int r = 0; r < 4; ++r) {
                int i = R * 32 + mi * 16 + sg * 4 + r;
                int j = Cq * 32 + ni * 16 + rr;
                float v = (i >= j) ? g[mi][ni][r] * __expf(Sar[i] - Sar[j]) * dtvA[j] : 0.f;
                Gt[swz(i, j * 2)] = f2bf(v);
            }
#pragma unroll
    for (int half = 0; half < 2; ++half) {
        u16x8 cv = *(const u16x8*)&Ct[swz(row, q * 32 + half * 16)];
        u16x8 ov;
#pragma unroll
        for (int e = 0; e < 8; ++e) ov[e] = f2bf(bf2f(cv[e]) * eSA[row]);
        *(u16x8*)&C2G[(size_t)tau * 4096 + row * 64 + q * 16 + half * 8] = ov;
        u16x8 bv = *(const u16x8*)&Bt[swz(row, q * 32 + half * 16)];
#pragma unroll
        for (int e = 0; e < 8; ++e)
            BTt[swz(q * 16 + half * 8 + e, row * 2)] = f2bf(bf2f(bv[e]) * wA[row]);
    }
    __syncthreads();

    f32x4 y[2][2], dh[2][2];
#pragma unroll
    for (int mi = 0; mi < 2; ++mi)
#pragma unroll
        for (int ni = 0; ni < 2; ++ni)
#pragma unroll
            for (int r = 0; r < 4; ++r) { y[mi][ni][r] = 0.f; dh[mi][ni][r] = 0.f; }
#pragma unroll
    for (int kt = 0; kt < 2; ++kt) {
        int cb = kt * 64 + sg * 16;
        bf16x8 xb0 = *(const bf16x8*)&XT[swz(Cq * 32 + rr, cb)];
        bf16x8 xb1 = *(const bf16x8*)&XT[swz(Cq * 32 + 16 + rr, cb)];
        bf16x8 ga0 = *(const bf16x8*)&Gt[swz(R * 32 + rr, cb)];
        bf16x8 ga1 = *(const bf16x8*)&Gt[swz(R * 32 + 16 + rr, cb)];
        bf16x8 ba0 = *(const bf16x8*)&BTt[swz(R * 32 + rr, cb)];
        bf16x8 ba1 = *(const bf16x8*)&BTt[swz(R * 32 + 16 + rr, cb)];
        y[0][0] = __builtin_amdgcn_mfma_f32_16x16x32_bf16(ga0, xb0, y[0][0], 0, 0, 0);
        y[0][1] = __builtin_amdgcn_mfma_f32_16x16x32_bf16(ga0, xb1, y[0][1], 0, 0, 0);
        y[1][0] = __builtin_amdgcn_mfma_f32_16x16x32_bf16(ga1, xb0, y[1][0], 0, 0, 0);
        y[1][1] = __builtin_amdgcn_mfma_f32_16x16x32_bf16(ga1, xb1, y[1][1], 0, 0, 0);
        dh[0][0] = __builtin_amdgcn_mfma_f32_16x16x32_bf16(ba0, xb0, dh[0][0], 0, 0, 0);
        dh[0][1] = __builtin_amdgcn_mfma_f32_16x16x32_bf16(ba0, xb1, dh[0][1], 0, 0, 0);
        dh[1][0] = __builtin_amdgcn_mfma_f32_16x16x32_bf16(ba1, xb0, dh[1][0], 0, 0, 0);
        dh[1][1] = __builtin_amdgcn_mfma_f32_16x16x32_bf16(ba1, xb1, dh[1][1], 0, 0, 0);
    }
#pragma unroll
    for (int mi = 0; mi < 2; ++mi)
#pragma unroll
        for (int ni = 0; ni < 2; ++ni)
#pragma unroll
            for (int r = 0; r < 4; ++r) {
                int i = R * 32 + mi * 16 + sg * 4 + r;
                int p = Cq * 32 + ni * 16 + rr;
                yi[(size_t)(t0g + i) * DIN + h * HDD + p] = f2bf(y[mi][ni][r]);
                DHb[(size_t)tau * 4096 + i * 64 + p] = f2bf(dh[mi][ni][r]);
            }
}

// ---------- SSD K2 ----------
__global__ __launch_bounds__(256) void ssd_carry(const u16* __restrict__ DHb,
                                                 const float* __restrict__ DC,
                                                 u16* __restrict__ HPREV) {
    int bid = blockIdx.x;
    int bh = bid >> 1, ph = bid & 1;
    int t = threadIdx.x;
    int s = t >> 2, p0 = ph * 32 + (t & 3) * 8;
    size_t base = (size_t)bh * NCHUNK * 4096 + s * 64 + p0;
    float Hv[8] = {0.f, 0.f, 0.f, 0.f, 0.f, 0.f, 0.f, 0.f};
    for (int c = 0; c < NCHUNK; ++c) {
        size_t off = base + (size_t)c * 4096;
        u16x8 hp;
#pragma unroll
        for (int e = 0; e < 8; ++e) hp[e] = f2bf(Hv[e]);
        *(u16x8*)&HPREV[off] = hp;
        float d = DC[bh * NCHUNK + c];
        u16x8 dv = *(const u16x8*)&DHb[off];
#pragma unroll
        for (int e = 0; e < 8; ++e) Hv[e] = d * Hv[e] + bf2f(dv[e]);
    }
}

// ---------- SSD K3 ----------
__global__ __launch_bounds__(256) void ssd_final(const u16* __restrict__ C2G,
                                                 const u16* __restrict__ HPREV,
                                                 const u16* __restrict__ xbc,
                                                 const u16* __restrict__ zx,
                                                 const float* __restrict__ Dp,
                                                 u16* __restrict__ yi) {
    __shared__ u16 C2t[4096], HT[4096];
    int tau = blockIdx.x;
    int b = tau >> 8, h = (tau >> 4) & 15, c = tau & 15;
    int t0g = b * LL + c * QCH;
    int t = threadIdx.x, lane = t & 63, wave = t >> 6;
    int row = t >> 2, q = t & 3;
#pragma unroll
    for (int half = 0; half < 2; ++half) {
        u16x8 cv = *(const u16x8*)&C2G[(size_t)tau * 4096 + row * 64 + q * 16 + half * 8];
        *(u16x8*)&C2t[swz(row, q * 32 + half * 16)] = cv;
        u16x8 hv = *(const u16x8*)&HPREV[(size_t)tau * 4096 + row * 64 + q * 16 + half * 8];
#pragma unroll
        for (int e = 0; e < 8; ++e) HT[swz(q * 16 + half * 8 + e, row * 2)] = hv[e];
    }
    __syncthreads();
    int R = wave >> 1, Cq = wave & 1, rr = lane & 15, sg = lane >> 4;
    float Dh = Dp[h];
    f32x4 acc[2][2];
#pragma unroll
    for (int mi = 0; mi < 2; ++mi)
#pragma unroll
        for (int ni = 0; ni < 2; ++ni)
#pragma unroll
            for (int r = 0; r < 4; ++r) {
                int i = R * 32 + mi * 16 + sg * 4 + r;
                int p = Cq * 32 + ni * 16 + rr;
                acc[mi][ni][r] = bf2f(yi[(size_t)(t0g + i) * DIN + h * HDD + p]);
            }
#pragma unroll
    for (int kt = 0; kt < 2; ++kt) {
        int cb = kt * 64 + sg * 16;
        bf16x8 a0 = *(const bf16x8*)&C2t[swz(R * 32 + rr, cb)];
        bf16x8 a1 = *(const bf16x8*)&C2t[swz(R * 32 + 16 + rr, cb)];
        bf16x8 b0 = *(const bf16x8*)&HT[swz(Cq * 32 + rr, cb)];
        bf16x8 b1 = *(const bf16x8*)&HT[swz(Cq * 32 + 16 + rr, cb)];
        acc[0][0] = __builtin_amdgcn_mfma_f32_16x16x32_bf16(a0, b0, acc[0][0], 0, 0, 0);
        acc[0][1] = __builtin_amdgcn_mfma_f32_16x16x32_bf16(a0, b1, acc[0][1], 0, 0, 0);
        acc[1][0] = __builtin_amdgcn_mfma_f32_16x16x32_bf16(a1, b0, acc[1][0], 0, 0, 0);
        acc[1][1] = __builtin_amdgcn_mfma_f32_16x16x32_bf16(a1, b1, acc[1][1], 0, 0, 0);
    }
#pragma unroll
    for (int mi = 0; mi < 2; ++mi)
#pragma unroll
        for (int ni = 0; ni < 2; ++ni)
#pragma unroll
            for (int r = 0; r < 4; ++r) {
                int i = R * 32 + mi * 16 + sg * 4 + r;
                int p = Cq * 32 + ni * 16 + rr;
                size_t tok = t0g + i;
                int col = h * HDD + p;
                float xf = bf2f(xbc[tok * XBCS + col]);
                float zf = bf2f(zx[tok * NPADW + col]);
                float yo = (acc[mi][ni][r] + Dh * xf) * (zf / (1.f + __expf(-zf)));
                yi[tok * DIN + col] = f2bf(yo);
            }
}

// ---------- per-token RMS scale: rs = rsqrt(mean(y^2)+eps) ----------
__global__ __launch_bounds__(256) void rs_kernel(const u16* __restrict__ y,
                                                 float* __restrict__ rs) {
    int row = blockIdx.x, t = threadIdx.x;
    ushort4 uv = *(const ushort4*)&y[(size_t)row * DIN + t * 4];
    float v0 = bf2f(uv.x), v1 = bf2f(uv.y), v2 = bf2f(uv.z), v3 = bf2f(uv.w);
    float ss = v0 * v0 + v1 * v1 + v2 * v2 + v3 * v3;
#pragma unroll
    for (int o = 1; o < 64; o <<= 1) ss += __shfl_xor(ss, o, 64);
    __shared__ float ps[4];
    if ((t & 63) == 0) ps[t >> 6] = ss;
    __syncthreads();
    if (t == 0) {
        float tot = ps[0] + ps[1] + ps[2] + ps[3];
        rs[row] = rsqrtf(tot * (1.f / DIN) + 1e-5f);
    }
}

extern "C" void kernel_launch(void* const* d_in, const int* in_sizes, int n_in,
                              void* d_out, int out_size, void* d_ws, size_t ws_size,
                              hipStream_t stream) {
    const float* x         = (const float*)d_in[0];
    const float* ln_w      = (const float*)d_in[1];
    const float* ln_b      = (const float*)d_in[2];
    const float* in_proj_w = (const float*)d_in[3];
    const float* conv1d_w  = (const float*)d_in[4];
    const float* conv1d_b  = (const float*)d_in[5];
    const float* dt_bias   = (const float*)d_in[6];
    const float* A_log     = (const float*)d_in[7];
    const float* Dp        = (const float*)d_in[8];
    const float* rms_w     = (const float*)d_in[9];
    const float* out_proj_w= (const float*)d_in[10];
    const float* conv2d_w  = (const float*)d_in[11];
    const float* conv2d_b  = (const float*)d_in[12];
    const float* bn_g      = (const float*)d_in[13];
    const float* bn_b      = (const float*)d_in[14];
    const float* bn_mean   = (const float*)d_in[15];
    const float* bn_var    = (const float*)d_in[16];

    const int TOK = NB * LL;  // 8192
    const int NTAU = NB * NHH * NCHUNK;  // 2048
    char* ws = (char*)d_ws;
    size_t off = 0;
    auto alloc = [&](size_t bytes) {
        void* p = ws + off;
        off += (bytes + 255) & ~(size_t)255;
        return p;
    };
    u16*   Win   = (u16*)alloc((size_t)NPADW * CIN * 2);
    u16*   WoutT = (u16*)alloc((size_t)DIN * CIN * 2);
    u16*   Wc2   = (u16*)alloc((size_t)CIN * CIN * 2);
    u16*   WCMB  = (u16*)alloc((size_t)CIN * DIN * 2);
    u16*   XN    = (u16*)alloc((size_t)TOK * CIN * 2);
    u16*   ZX    = (u16*)alloc((size_t)TOK * NPADW * 2);
    u16*   XBC   = (u16*)alloc((size_t)TOK * XBCS * 2);
    float* Bcb   = (float*)alloc((size_t)TOK * DST * 4);
    float* Ccb   = (float*)alloc((size_t)TOK * DST * 4);
    float2* DTDA = (float2*)alloc((size_t)TOK * NHH * 8);
    u16*   YI    = (u16*)alloc((size_t)TOK * DIN * 2);
    u16*   DHb   = (u16*)alloc((size_t)NTAU * 4096 * 2);
    u16*   C2G   = (u16*)alloc((size_t)NTAU * 4096 * 2);
    u16*   HPREV = (u16*)alloc((size_t)NTAU * 4096 * 2);
    float* DC    = (float*)alloc((size_t)NTAU * 4);
    float* RS    = (float*)alloc((size_t)TOK * 4);
    float* BNSC  = (float*)alloc(CIN * 4);
    float* BNSH  = (float*)alloc(CIN * 4);

    // weight prep
    f2bf_pad<<<(NPADW * CIN + 255) / 256, 256, 0, stream>>>(in_proj_w, Win, DPROJ * CIN, NPADW * CIN);
    woutT_conv<<<128, 256, 0, stream>>>(out_proj_w, rms_w, WoutT);
    f2bf_kernel<<<(CIN * CIN + 255) / 256, 256, 0, stream>>>(conv2d_w, Wc2, CIN * CIN);
    bn_prep<<<2, 256, 0, stream>>>(conv2d_b, bn_g, bn_b, bn_mean, bn_var, BNSC, BNSH);
    // W_comb[o][d] = sum_c Wc2[o][c] * WoutT[d][c]   (M=512, N=1024, K=512)
    gemm_bt<0><<<(CIN / 128) * (DIN / 128), 256, 0, stream>>>(Wc2, WoutT, WCMB, CIN, DIN, CIN, DIN,
                                                              DIN / 128, nullptr, nullptr, nullptr);

    ln_kernel<<<256, 256, 0, stream>>>(x, ln_w, ln_b, XN);

    gemm_bt<0><<<(TOK / 128) * (NPADW / 128), 256, 0, stream>>>(XN, Win, ZX, TOK, NPADW, CIN, NPADW,
                                                                NPADW / 128, nullptr, nullptr, nullptr);

    conv1d_fused<<<NB * (LL / CTT), 288, 0, stream>>>(ZX, conv1d_w, conv1d_b, XBC, Bcb, Ccb);
    dt_gemv<<<TOK, 256, 0, stream>>>(XN, in_proj_w, dt_bias, A_log, DTDA);

    ssd_chunk<<<NTAU, 256, 0, stream>>>(Bcb, Ccb, XBC, DTDA, YI, DHb, C2G, DC);
    ssd_carry<<<256, 256, 0, stream>>>(DHb, DC, HPREV);
    ssd_final<<<NTAU, 256, 0, stream>>>(C2G, HPREV, XBC, ZX, Dp, YI);

    rs_kernel<<<TOK, 256, 0, stream>>>(YI, RS);

    // fused out_proj + conv2d + BN + ReLU:  d_out[o,tok] = relu(BN(rs[tok] * sum_d WCMB[o,d]*y[tok,d]))
    gemm_bt<1><<<(CIN / 128) * (TOK / 128), 256, 0, stream>>>(WCMB, YI, d_out, CIN, TOK, DIN, 0,
                                                              TOK / 128, BNSC, BNSH, RS);
}

// Round 9
// 167.160 us; speedup vs baseline: 4.3694x; 1.1506x over previous
//
#include <hip/hip_runtime.h>
#include <hip/hip_bf16.h>

// Problem constants
#define NB 8
#define LL 1024        // H*W tokens per batch
#define CIN 512
#define DIN 1024       // d_inner
#define DXBC 1152      // d_inner + 2*d_state
#define DPROJ 2192     // actual in_proj rows
#define NPADW 2304     // padded to 18*128 for GEMM tiles
#define NHH 16
#define HDD 64
#define DST 64
#define NCHUNK 16
#define QCH 64         // chunk length
#define XBCS 1024      // XBC stored stride (x-part only)
#define CTT 8          // conv tokens per block
#define DTB 16         // dt tokens per block

typedef unsigned short u16;
typedef unsigned int u32;
typedef __bf16 bf16x8 __attribute__((ext_vector_type(8)));
typedef float f32x4 __attribute__((ext_vector_type(4)));
typedef u16 u16x8 __attribute__((ext_vector_type(8)));

__device__ __forceinline__ float bf2f(u16 u) {
    u32 x = ((u32)u) << 16; float f; __builtin_memcpy(&f, &x, 4); return f;
}
__device__ __forceinline__ u16 f2bf(float f) {
    u32 x; __builtin_memcpy(&x, &f, 4);
    u32 r = x + 0x7fff + ((x >> 16) & 1);
    return (u16)(r >> 16);
}

__device__ __forceinline__ void gload16(const u16* g, u16* l) {
    __builtin_amdgcn_global_load_lds((__attribute__((address_space(1))) void*)(g),
                                     (__attribute__((address_space(3))) void*)(l), 16, 0, 0);
}

// swizzled u16 index into a [64][64] bf16 LDS tile (128B rows, 16B-slot XOR swizzle)
__device__ __forceinline__ int swz(int row, int cb) {
    return row * 64 + ((cb ^ ((row & 7) << 4)) >> 1);
}

// ---------- weight converts ----------
__global__ void f2bf_kernel(const float* __restrict__ s, u16* __restrict__ d, int n) {
    int i = blockIdx.x * 256 + threadIdx.x;
    if (i < n) d[i] = f2bf(s[i]);
}
__global__ void f2bf_pad(const float* __restrict__ s, u16* __restrict__ d, int nsrc, int ndst) {
    int i = blockIdx.x * 256 + threadIdx.x;
    if (i < ndst) d[i] = (i < nsrc) ? f2bf(s[i]) : (u16)0;
}
// WoutT[d][c] = out_proj_w[c][d] * rms_w[d]   (LDS-tiled transpose, 64x64 tiles)
__global__ __launch_bounds__(256) void woutT_conv(const float* __restrict__ s,
                                                  const float* __restrict__ rw,
                                                  u16* __restrict__ dt) {
    __shared__ float tile[64][65];
    int bc = blockIdx.x & 7, bd = blockIdx.x >> 3;   // c-tile (512/64=8), d-tile (1024/64=16)
    int c0 = bc * 64, d0 = bd * 64;
    int t = threadIdx.x;
    int r4 = t >> 6, cc = t & 63;
#pragma unroll
    for (int rr = 0; rr < 16; ++rr) {
        int row = r4 * 16 + rr;
        tile[row][cc] = s[(size_t)(c0 + row) * DIN + d0 + cc];
    }
    __syncthreads();
#pragma unroll
    for (int rr = 0; rr < 16; ++rr) {
        int row = r4 * 16 + rr;   // d within tile
        dt[(size_t)(d0 + row) * CIN + c0 + cc] = f2bf(tile[cc][row] * rw[d0 + row]);
    }
}
__global__ void bn_prep(const float* __restrict__ cb, const float* __restrict__ g,
                        const float* __restrict__ bb, const float* __restrict__ mean,
                        const float* __restrict__ var, float* __restrict__ scale,
                        float* __restrict__ shift) {
    int i = blockIdx.x * 256 + threadIdx.x;
    if (i < CIN) {
        float rs = rsqrtf(var[i] + 1e-5f);
        float sc = g[i] * rs;
        scale[i] = sc;
        shift[i] = (cb[i] - mean[i]) * sc + bb[i];
    }
}

// ---------- LayerNorm over channels + transpose (B,C,HW) -> (tok, C) bf16 ----------
__global__ __launch_bounds__(256) void ln_kernel(const float* __restrict__ x,
                                                 const float* __restrict__ lw,
                                                 const float* __restrict__ lb,
                                                 u16* __restrict__ xn) {
    __shared__ u16 tile[CIN * 33];
    __shared__ float psum[8][32], psq[8][32], muA[32], rsA[32];
    int bid = blockIdx.x;
    int b = bid >> 5, hw0 = (bid & 31) * 32;
    int t = threadIdx.x;
    int hw = t & 31, cg = t >> 5;
    const float* xb = x + (size_t)b * CIN * LL + hw0 + hw;
    float s = 0.f, sq = 0.f;
    for (int r = 0; r < CIN / 8; ++r) {
        int c = r * 8 + cg;
        float v = xb[(size_t)c * LL];
        s += v; sq += v * v;
        tile[c * 33 + hw] = f2bf(v);
    }
    psum[cg][hw] = s; psq[cg][hw] = sq;
    __syncthreads();
    if (t < 32) {
        float ss = 0.f, qq = 0.f;
        for (int g = 0; g < 8; ++g) { ss += psum[g][t]; qq += psq[g][t]; }
        float mu = ss * (1.f / CIN);
        float var = qq * (1.f / CIN) - mu * mu;
        muA[t] = mu; rsA[t] = rsqrtf(var + 1e-5f);
    }
    __syncthreads();
    for (int r = 0; r < 64; ++r) {
        int idx = r * 256 + t;
        int c = idx & (CIN - 1);
        int hh = idx >> 9;
        float v = (bf2f(tile[c * 33 + hh]) - muA[hh]) * rsA[hh] * lw[c] + lb[c];
        xn[((size_t)(b * LL + hw0 + hh)) * CIN + c] = f2bf(v);
    }
}

// ---------- bf16 MFMA GEMM: BK=64, XOR-swizzled LDS, 2-phase dbuf with COUNTED vmcnt ----------
// EPI 0: bf16 store row-major ldc.
// EPI 1: v*rsc[col] -> BN(scale/shift[row]) -> ReLU -> remapped f32 store (d_out layout).
template <int EPI>
__global__ __launch_bounds__(256) void gemm_bt(const u16* __restrict__ A, const u16* __restrict__ Bw,
                                               void* __restrict__ Cout, int M, int N, int K, int ldc,
                                               int nx,
                                               const float* __restrict__ scale,
                                               const float* __restrict__ shift,
                                               const float* __restrict__ rsc) {
    __shared__ u16 As[2][128 * 64], Bs[2][128 * 64];
    int t = threadIdx.x;
    int lane = t & 63, wave = t >> 6;
    // bijective XCD swizzle (m204)
    int nblk = gridDim.x;
    int qq = nblk >> 3, rm = nblk & 7;
    int xcd = blockIdx.x & 7, idx = blockIdx.x >> 3;
    int swzb = (xcd < rm ? xcd * (qq + 1) : rm * (qq + 1) + (xcd - rm) * qq) + idx;
    int m0 = (swzb / nx) * 128, n0 = (swzb % nx) * 128;
    int wr = wave >> 1, wc = wave & 1;
    f32x4 acc[4][4];
    for (int m = 0; m < 4; ++m)
        for (int n = 0; n < 4; ++n)
            for (int q = 0; q < 4; ++q) acc[m][n][q] = 0.f;

    const u16* Arow = A + (size_t)m0 * K;
    const u16* Brow = Bw + (size_t)n0 * K;
    int s4 = lane >> 4;
    int rr = lane & 15;

    auto STAGE = [&](int buf, int k0) {
#pragma unroll
        for (int j = 0; j < 4; ++j) {
            int e = j * 256 + t;          // 16B-slot id, 8 slots per row
            int r = e >> 3, sr = e & 7;
            int src = (sr ^ (r & 7)) * 8; // inverse XOR permutation on source
            gload16(Arow + (size_t)r * K + k0 + src, &As[buf][e * 8]);
            gload16(Brow + (size_t)r * K + k0 + src, &Bs[buf][e * 8]);
        }
    };

    STAGE(0, 0);                       // 8 loads/thread in flight
    int NK = K >> 6, cur = 0;
    for (int kt = 0; kt < NK; ++kt) {
        if (kt + 1 < NK) {
            STAGE(cur ^ 1, (kt + 1) << 6);             // +8 loads (next tile)
            asm volatile("s_waitcnt vmcnt(8)" ::: "memory");  // cur tile's 8 done; next 8 fly
        } else {
            asm volatile("s_waitcnt vmcnt(0)" ::: "memory");
        }
        __builtin_amdgcn_s_barrier();   // all waves' cur-tile loads landed
        __builtin_amdgcn_sched_barrier(0);
#pragma unroll
        for (int kk = 0; kk < 2; ++kk) {
            bf16x8 af[4], bfr[4];
#pragma unroll
            for (int m = 0; m < 4; ++m) {
                int row = wr * 64 + m * 16 + rr;
                int ss = (kk * 4 + s4) ^ (row & 7);
                af[m] = *(const bf16x8*)&As[cur][row * 64 + ss * 8];
            }
#pragma unroll
            for (int n = 0; n < 4; ++n) {
                int row = wc * 64 + n * 16 + rr;
                int ss = (kk * 4 + s4) ^ (row & 7);
                bfr[n] = *(const bf16x8*)&Bs[cur][row * 64 + ss * 8];
            }
#pragma unroll
            for (int m = 0; m < 4; ++m)
#pragma unroll
                for (int n = 0; n < 4; ++n)
                    acc[m][n] = __builtin_amdgcn_mfma_f32_16x16x32_bf16(af[m], bfr[n], acc[m][n], 0, 0, 0);
        }
        __builtin_amdgcn_s_barrier();   // protect buf[cur] before next iter's STAGE overwrites it
        cur ^= 1;
    }
    int fq = lane >> 4, fr = lane & 15;
#pragma unroll
    for (int m = 0; m < 4; ++m) {
#pragma unroll
        for (int n = 0; n < 4; ++n) {
            int col = n0 + wc * 64 + n * 16 + fr;
#pragma unroll
            for (int q = 0; q < 4; ++q) {
                int row = m0 + wr * 64 + m * 16 + fq * 4 + q;
                float v = acc[m][n][q];
                if (EPI == 0) {
                    ((u16*)Cout)[(size_t)row * ldc + col] = f2bf(v);
                } else {
                    v = v * rsc[col];
                    v = v * scale[row] + shift[row];
                    v = v > 0.f ? v : 0.f;
                    // row = out-channel o, col = token (b*1024+hw)
                    ((float*)Cout)[((size_t)(col >> 10)) * (CIN * LL) + (size_t)row * LL + (col & 1023)] = v;
                }
            }
        }
    }
}

// ---------- depthwise causal conv1d + SiLU, register sliding window ----------
__global__ __launch_bounds__(288) void conv1d_fused(const u16* __restrict__ zx,
                                                    const float* __restrict__ w,
                                                    const float* __restrict__ bias,
                                                    u16* __restrict__ xbc,
                                                    float* __restrict__ Bc, float* __restrict__ Cc) {
    int bid = blockIdx.x;
    int b = bid >> 7;
    int l0 = (bid & 127) * CTT;
    int t = threadIdx.x;
    bool isX = t < 256;
    int ch = isX ? t * 4 : 1024 + (t - 256) * 4;

    float4 wv0 = *(const float4*)&w[(ch + 0) * 4];
    float4 wv1 = *(const float4*)&w[(ch + 1) * 4];
    float4 wv2 = *(const float4*)&w[(ch + 2) * 4];
    float4 wv3 = *(const float4*)&w[(ch + 3) * 4];
    float4 bv = *(const float4*)&bias[ch];

    ushort4 xin[CTT + 3];
    const u16* src = zx + (size_t)(b * LL + l0 - 3) * NPADW + DIN + ch;
#pragma unroll
    for (int i = 0; i < CTT + 3; ++i) {
        ushort4 v = {0, 0, 0, 0};
        if (l0 + i - 3 >= 0) v = *(const ushort4*)(src + (size_t)i * NPADW);
        xin[i] = v;
    }
#pragma unroll
    for (int i = 0; i < CTT; ++i) {
        int tok = b * LL + l0 + i;
        float a0 = bv.x + bf2f(xin[i].x) * wv0.x + bf2f(xin[i + 1].x) * wv0.y +
                   bf2f(xin[i + 2].x) * wv0.z + bf2f(xin[i + 3].x) * wv0.w;
        float a1 = bv.y + bf2f(xin[i].y) * wv1.x + bf2f(xin[i + 1].y) * wv1.y +
                   bf2f(xin[i + 2].y) * wv1.z + bf2f(xin[i + 3].y) * wv1.w;
        float a2 = bv.z + bf2f(xin[i].z) * wv2.x + bf2f(xin[i + 1].z) * wv2.y +
                   bf2f(xin[i + 2].z) * wv2.z + bf2f(xin[i + 3].z) * wv2.w;
        float a3 = bv.w + bf2f(xin[i].w) * wv3.x + bf2f(xin[i + 1].w) * wv3.y +
                   bf2f(xin[i + 2].w) * wv3.z + bf2f(xin[i + 3].w) * wv3.w;
        float s0 = a0 / (1.f + __expf(-a0));
        float s1 = a1 / (1.f + __expf(-a1));
        float s2 = a2 / (1.f + __expf(-a2));
        float s3 = a3 / (1.f + __expf(-a3));
        if (isX) {
            ushort4 o;
            o.x = f2bf(s0); o.y = f2bf(s1); o.z = f2bf(s2); o.w = f2bf(s3);
            *(ushort4*)&xbc[(size_t)tok * XBCS + ch] = o;
        } else {
            int s = ch - 1024;
            float4 o4; o4.x = s0; o4.y = s1; o4.z = s2; o4.w = s3;
            if (s < DST) *(float4*)&Bc[(size_t)tok * DST + s] = o4;
            else         *(float4*)&Cc[(size_t)tok * DST + (s - DST)] = o4;
        }
    }
}

// ---------- dt GEMV: weights in registers, DTB tokens per block ----------
// grid: TOK/DTB blocks; thread (h = t>>4, part = t&15) owns W[h][part*32..+32] in regs.
__global__ __launch_bounds__(256) void dt_gemv(const u16* __restrict__ xn,
                                               const float* __restrict__ wproj,
                                               const float* __restrict__ dt_bias,
                                               const float* __restrict__ A_log,
                                               float2* __restrict__ dtda) {
    int t = threadIdx.x;
    int h = t >> 4, part = t & 15;
    int tok0 = blockIdx.x * DTB;
    const float* wr = wproj + (size_t)(DIN + DXBC + h) * CIN + part * 32;
    float4 w[8];
#pragma unroll
    for (int i = 0; i < 8; ++i) w[i] = *(const float4*)&wr[i * 4];
    const float* wf = (const float*)w;
    float dtb = dt_bias[h];
    float An = -__expf(A_log[h]);
#pragma unroll
    for (int tl = 0; tl < DTB; ++tl) {
        int tok = tok0 + tl;
        const u16* xr = xn + (size_t)tok * CIN + part * 32;
        u16x8 xv0 = *(const u16x8*)&xr[0];
        u16x8 xv1 = *(const u16x8*)&xr[8];
        u16x8 xv2 = *(const u16x8*)&xr[16];
        u16x8 xv3 = *(const u16x8*)&xr[24];
        float s = 0.f;
#pragma unroll
        for (int i = 0; i < 8; ++i) s += bf2f(xv0[i]) * wf[i];
#pragma unroll
        for (int i = 0; i < 8; ++i) s += bf2f(xv1[i]) * wf[8 + i];
#pragma unroll
        for (int i = 0; i < 8; ++i) s += bf2f(xv2[i]) * wf[16 + i];
#pragma unroll
        for (int i = 0; i < 8; ++i) s += bf2f(xv3[i]) * wf[24 + i];
        s += __shfl_xor(s, 1, 64);
        s += __shfl_xor(s, 2, 64);
        s += __shfl_xor(s, 4, 64);
        s += __shfl_xor(s, 8, 64);
        if (part == 0) {
            float si = s + dtb;
            float dtv = si > 15.f ? si : __logf(1.f + __expf(si));
            float2 dd; dd.x = dtv; dd.y = dtv * An;
            dtda[(size_t)tok * NHH + h] = dd;
        }
    }
}

// ---------- SSD K1 ----------
__global__ __launch_bounds__(256) void ssd_chunk(const float* __restrict__ Bcb,
                                                 const float* __restrict__ Ccb,
                                                 const u16* __restrict__ xbc,
                                                 const float2* __restrict__ dtda,
                                                 u16* __restrict__ yi,
                                                 u16* __restrict__ DHb,
                                                 u16* __restrict__ C2G,
                                                 float* __restrict__ DC) {
    __shared__ u16 Bt[4096], Ct[4096], XT[4096], BTt[4096], Gt[4096];
    __shared__ float Sar[64], dtvA[64], wA[64], eSA[64];
    int tau = blockIdx.x;
    int b = tau >> 8, h = (tau >> 4) & 15, c = tau & 15;
    int t0g = b * LL + c * QCH;
    int t = threadIdx.x, lane = t & 63, wave = t >> 6;
    int row = t >> 2, q = t & 3;

    {
        const float* bp = Bcb + (size_t)(t0g + row) * DST + q * 16;
        const float* cp = Ccb + (size_t)(t0g + row) * DST + q * 16;
#pragma unroll
        for (int half = 0; half < 2; ++half) {
            float4 v0 = *(const float4*)(bp + half * 8);
            float4 v1 = *(const float4*)(bp + half * 8 + 4);
            u16x8 o;
            o[0] = f2bf(v0.x); o[1] = f2bf(v0.y); o[2] = f2bf(v0.z); o[3] = f2bf(v0.w);
            o[4] = f2bf(v1.x); o[5] = f2bf(v1.y); o[6] = f2bf(v1.z); o[7] = f2bf(v1.w);
            *(u16x8*)&Bt[swz(row, q * 32 + half * 16)] = o;
            float4 c0 = *(const float4*)(cp + half * 8);
            float4 c1 = *(const float4*)(cp + half * 8 + 4);
            u16x8 oc;
            oc[0] = f2bf(c0.x); oc[1] = f2bf(c0.y); oc[2] = f2bf(c0.z); oc[3] = f2bf(c0.w);
            oc[4] = f2bf(c1.x); oc[5] = f2bf(c1.y); oc[6] = f2bf(c1.z); oc[7] = f2bf(c1.w);
            *(u16x8*)&Ct[swz(row, q * 32 + half * 16)] = oc;
        }
        const u16* xp = xbc + (size_t)(t0g + row) * XBCS + h * HDD + q * 16;
        u16x8 x0 = *(const u16x8*)xp;
        u16x8 x1 = *(const u16x8*)(xp + 8);
#pragma unroll
        for (int e = 0; e < 8; ++e) XT[swz(q * 16 + e, row * 2)] = x0[e];
#pragma unroll
        for (int e = 0; e < 8; ++e) XT[swz(q * 16 + 8 + e, row * 2)] = x1[e];
    }
    if (t < 64) {
        float2 dd = dtda[(size_t)(t0g + t) * NHH + h];
        float s = dd.y;
#pragma unroll
        for (int off = 1; off < 64; off <<= 1) {
            float u = __shfl_up(s, off, 64);
            if (t >= off) s += u;
        }
        float SQ = __shfl(s, 63, 64);
        Sar[t] = s; dtvA[t] = dd.x;
        wA[t] = __expf(SQ - s) * dd.x;
        eSA[t] = __expf(s);
        if (t == 0) DC[tau] = __expf(SQ);
    }
    __syncthreads();

    int R = wave >> 1, Cq = wave & 1, rr = lane & 15, sg = lane >> 4;
    f32x4 g[2][2];
#pragma unroll
    for (int mi = 0; mi < 2; ++mi)
#pragma unroll
        for (int ni = 0; ni < 2; ++ni)
#pragma unroll
            for (int r = 0; r < 4; ++r) g[mi][ni][r] = 0.f;
#pragma unroll
    for (int kt = 0; kt < 2; ++kt) {
        int cb = kt * 64 + sg * 16;
        bf16x8 a0 = *(const bf16x8*)&Ct[swz(R * 32 + rr, cb)];
        bf16x8 a1 = *(const bf16x8*)&Ct[swz(R * 32 + 16 + rr, cb)];
        bf16x8 b0 = *(const bf16x8*)&Bt[swz(Cq * 32 + rr, cb)];
        bf16x8 b1 = *(const bf16x8*)&Bt[swz(Cq * 32 + 16 + rr, cb)];
        g[0][0] = __builtin_amdgcn_mfma_f32_16x16x32_bf16(a0, b0, g[0][0], 0, 0, 0);
        g[0][1] = __builtin_amdgcn_mfma_f32_16x16x32_bf16(a0, b1, g[0][1], 0, 0, 0);
        g[1][0] = __builtin_amdgcn_mfma_f32_16x16x32_bf16(a1, b0, g[1][0], 0, 0, 0);
        g[1][1] = __builtin_amdgcn_mfma_f32_16x16x32_bf16(a1, b1, g[1][1], 0, 0, 0);
    }
#pragma unroll
    for (int mi = 0; mi < 2; ++mi)
#pragma unroll
        for (int ni = 0; ni < 2; ++ni)
#pragma unroll
            for (int r = 0; r < 4; ++r) {
                int i = R * 32 + mi * 16 + sg * 4 + r;
                int j = Cq * 32 + ni * 16 + rr;
                float v = (i >= j) ? g[mi][ni][r] * __expf(Sar[i] - Sar[j]) * dtvA[j] : 0.f;
                Gt[swz(i, j * 2)] = f2bf(v);
            }
#pragma unroll
    for (int half = 0; half < 2; ++half) {
        u16x8 cv = *(const u16x8*)&Ct[swz(row, q * 32 + half * 16)];
        u16x8 ov;
#pragma unroll
        for (int e = 0; e < 8; ++e) ov[e] = f2bf(bf2f(cv[e]) * eSA[row]);
        *(u16x8*)&C2G[(size_t)tau * 4096 + row * 64 + q * 16 + half * 8] = ov;
        u16x8 bv = *(const u16x8*)&Bt[swz(row, q * 32 + half * 16)];
#pragma unroll
        for (int e = 0; e < 8; ++e)
            BTt[swz(q * 16 + half * 8 + e, row * 2)] = f2bf(bf2f(bv[e]) * wA[row]);
    }
    __syncthreads();

    f32x4 y[2][2], dh[2][2];
#pragma unroll
    for (int mi = 0; mi < 2; ++mi)
#pragma unroll
        for (int ni = 0; ni < 2; ++ni)
#pragma unroll
            for (int r = 0; r < 4; ++r) { y[mi][ni][r] = 0.f; dh[mi][ni][r] = 0.f; }
#pragma unroll
    for (int kt = 0; kt < 2; ++kt) {
        int cb = kt * 64 + sg * 16;
        bf16x8 xb0 = *(const bf16x8*)&XT[swz(Cq * 32 + rr, cb)];
        bf16x8 xb1 = *(const bf16x8*)&XT[swz(Cq * 32 + 16 + rr, cb)];
        bf16x8 ga0 = *(const bf16x8*)&Gt[swz(R * 32 + rr, cb)];
        bf16x8 ga1 = *(const bf16x8*)&Gt[swz(R * 32 + 16 + rr, cb)];
        bf16x8 ba0 = *(const bf16x8*)&BTt[swz(R * 32 + rr, cb)];
        bf16x8 ba1 = *(const bf16x8*)&BTt[swz(R * 32 + 16 + rr, cb)];
        y[0][0] = __builtin_amdgcn_mfma_f32_16x16x32_bf16(ga0, xb0, y[0][0], 0, 0, 0);
        y[0][1] = __builtin_amdgcn_mfma_f32_16x16x32_bf16(ga0, xb1, y[0][1], 0, 0, 0);
        y[1][0] = __builtin_amdgcn_mfma_f32_16x16x32_bf16(ga1, xb0, y[1][0], 0, 0, 0);
        y[1][1] = __builtin_amdgcn_mfma_f32_16x16x32_bf16(ga1, xb1, y[1][1], 0, 0, 0);
        dh[0][0] = __builtin_amdgcn_mfma_f32_16x16x32_bf16(ba0, xb0, dh[0][0], 0, 0, 0);
        dh[0][1] = __builtin_amdgcn_mfma_f32_16x16x32_bf16(ba0, xb1, dh[0][1], 0, 0, 0);
        dh[1][0] = __builtin_amdgcn_mfma_f32_16x16x32_bf16(ba1, xb0, dh[1][0], 0, 0, 0);
        dh[1][1] = __builtin_amdgcn_mfma_f32_16x16x32_bf16(ba1, xb1, dh[1][1], 0, 0, 0);
    }
#pragma unroll
    for (int mi = 0; mi < 2; ++mi)
#pragma unroll
        for (int ni = 0; ni < 2; ++ni)
#pragma unroll
            for (int r = 0; r < 4; ++r) {
                int i = R * 32 + mi * 16 + sg * 4 + r;
                int p = Cq * 32 + ni * 16 + rr;
                yi[(size_t)(t0g + i) * DIN + h * HDD + p] = f2bf(y[mi][ni][r]);
                DHb[(size_t)tau * 4096 + i * 64 + p] = f2bf(dh[mi][ni][r]);
            }
}

// ---------- SSD K2 ----------
__global__ __launch_bounds__(256) void ssd_carry(const u16* __restrict__ DHb,
                                                 const float* __restrict__ DC,
                                                 u16* __restrict__ HPREV) {
    int bid = blockIdx.x;
    int bh = bid >> 1, ph = bid & 1;
    int t = threadIdx.x;
    int s = t >> 2, p0 = ph * 32 + (t & 3) * 8;
    size_t base = (size_t)bh * NCHUNK * 4096 + s * 64 + p0;
    float Hv[8] = {0.f, 0.f, 0.f, 0.f, 0.f, 0.f, 0.f, 0.f};
    for (int c = 0; c < NCHUNK; ++c) {
        size_t off = base + (size_t)c * 4096;
        u16x8 hp;
#pragma unroll
        for (int e = 0; e < 8; ++e) hp[e] = f2bf(Hv[e]);
        *(u16x8*)&HPREV[off] = hp;
        float d = DC[bh * NCHUNK + c];
        u16x8 dv = *(const u16x8*)&DHb[off];
#pragma unroll
        for (int e = 0; e < 8; ++e) Hv[e] = d * Hv[e] + bf2f(dv[e]);
    }
}

// ---------- SSD K3 ----------
__global__ __launch_bounds__(256) void ssd_final(const u16* __restrict__ C2G,
                                                 const u16* __restrict__ HPREV,
                                                 const u16* __restrict__ xbc,
                                                 const u16* __restrict__ zx,
                                                 const float* __restrict__ Dp,
                                                 u16* __restrict__ yi) {
    __shared__ u16 C2t[4096], HT[4096];
    int tau = blockIdx.x;
    int b = tau >> 8, h = (tau >> 4) & 15, c = tau & 15;
    int t0g = b * LL + c * QCH;
    int t = threadIdx.x, lane = t & 63, wave = t >> 6;
    int row = t >> 2, q = t & 3;
#pragma unroll
    for (int half = 0; half < 2; ++half) {
        u16x8 cv = *(const u16x8*)&C2G[(size_t)tau * 4096 + row * 64 + q * 16 + half * 8];
        *(u16x8*)&C2t[swz(row, q * 32 + half * 16)] = cv;
        u16x8 hv = *(const u16x8*)&HPREV[(size_t)tau * 4096 + row * 64 + q * 16 + half * 8];
#pragma unroll
        for (int e = 0; e < 8; ++e) HT[swz(q * 16 + half * 8 + e, row * 2)] = hv[e];
    }
    __syncthreads();
    int R = wave >> 1, Cq = wave & 1, rr = lane & 15, sg = lane >> 4;
    float Dh = Dp[h];
    f32x4 acc[2][2];
#pragma unroll
    for (int mi = 0; mi < 2; ++mi)
#pragma unroll
        for (int ni = 0; ni < 2; ++ni)
#pragma unroll
            for (int r = 0; r < 4; ++r) {
                int i = R * 32 + mi * 16 + sg * 4 + r;
                int p = Cq * 32 + ni * 16 + rr;
                acc[mi][ni][r] = bf2f(yi[(size_t)(t0g + i) * DIN + h * HDD + p]);
            }
#pragma unroll
    for (int kt = 0; kt < 2; ++kt) {
        int cb = kt * 64 + sg * 16;
        bf16x8 a0 = *(const bf16x8*)&C2t[swz(R * 32 + rr, cb)];
        bf16x8 a1 = *(const bf16x8*)&C2t[swz(R * 32 + 16 + rr, cb)];
        bf16x8 b0 = *(const bf16x8*)&HT[swz(Cq * 32 + rr, cb)];
        bf16x8 b1 = *(const bf16x8*)&HT[swz(Cq * 32 + 16 + rr, cb)];
        acc[0][0] = __builtin_amdgcn_mfma_f32_16x16x32_bf16(a0, b0, acc[0][0], 0, 0, 0);
        acc[0][1] = __builtin_amdgcn_mfma_f32_16x16x32_bf16(a0, b1, acc[0][1], 0, 0, 0);
        acc[1][0] = __builtin_amdgcn_mfma_f32_16x16x32_bf16(a1, b0, acc[1][0], 0, 0, 0);
        acc[1][1] = __builtin_amdgcn_mfma_f32_16x16x32_bf16(a1, b1, acc[1][1], 0, 0, 0);
    }
#pragma unroll
    for (int mi = 0; mi < 2; ++mi)
#pragma unroll
        for (int ni = 0; ni < 2; ++ni)
#pragma unroll
            for (int r = 0; r < 4; ++r) {
                int i = R * 32 + mi * 16 + sg * 4 + r;
                int p = Cq * 32 + ni * 16 + rr;
                size_t tok = t0g + i;
                int col = h * HDD + p;
                float xf = bf2f(xbc[tok * XBCS + col]);
                float zf = bf2f(zx[tok * NPADW + col]);
                float yo = (acc[mi][ni][r] + Dh * xf) * (zf / (1.f + __expf(-zf)));
                yi[tok * DIN + col] = f2bf(yo);
            }
}

// ---------- per-token RMS scale: rs = rsqrt(mean(y^2)+eps) ----------
__global__ __launch_bounds__(256) void rs_kernel(const u16* __restrict__ y,
                                                 float* __restrict__ rs) {
    int row = blockIdx.x, t = threadIdx.x;
    ushort4 uv = *(const ushort4*)&y[(size_t)row * DIN + t * 4];
    float v0 = bf2f(uv.x), v1 = bf2f(uv.y), v2 = bf2f(uv.z), v3 = bf2f(uv.w);
    float ss = v0 * v0 + v1 * v1 + v2 * v2 + v3 * v3;
#pragma unroll
    for (int o = 1; o < 64; o <<= 1) ss += __shfl_xor(ss, o, 64);
    __shared__ float ps[4];
    if ((t & 63) == 0) ps[t >> 6] = ss;
    __syncthreads();
    if (t == 0) {
        float tot = ps[0] + ps[1] + ps[2] + ps[3];
        rs[row] = rsqrtf(tot * (1.f / DIN) + 1e-5f);
    }
}

extern "C" void kernel_launch(void* const* d_in, const int* in_sizes, int n_in,
                              void* d_out, int out_size, void* d_ws, size_t ws_size,
                              hipStream_t stream) {
    const float* x         = (const float*)d_in[0];
    const float* ln_w      = (const float*)d_in[1];
    const float* ln_b      = (const float*)d_in[2];
    const float* in_proj_w = (const float*)d_in[3];
    const float* conv1d_w  = (const float*)d_in[4];
    const float* conv1d_b  = (const float*)d_in[5];
    const float* dt_bias   = (const float*)d_in[6];
    const float* A_log     = (const float*)d_in[7];
    const float* Dp        = (const float*)d_in[8];
    const float* rms_w     = (const float*)d_in[9];
    const float* out_proj_w= (const float*)d_in[10];
    const float* conv2d_w  = (const float*)d_in[11];
    const float* conv2d_b  = (const float*)d_in[12];
    const float* bn_g      = (const float*)d_in[13];
    const float* bn_b      = (const float*)d_in[14];
    const float* bn_mean   = (const float*)d_in[15];
    const float* bn_var    = (const float*)d_in[16];

    const int TOK = NB * LL;  // 8192
    const int NTAU = NB * NHH * NCHUNK;  // 2048
    char* ws = (char*)d_ws;
    size_t off = 0;
    auto alloc = [&](size_t bytes) {
        void* p = ws + off;
        off += (bytes + 255) & ~(size_t)255;
        return p;
    };
    u16*   Win   = (u16*)alloc((size_t)NPADW * CIN * 2);
    u16*   WoutT = (u16*)alloc((size_t)DIN * CIN * 2);
    u16*   Wc2   = (u16*)alloc((size_t)CIN * CIN * 2);
    u16*   WCMB  = (u16*)alloc((size_t)CIN * DIN * 2);
    u16*   XN    = (u16*)alloc((size_t)TOK * CIN * 2);
    u16*   ZX    = (u16*)alloc((size_t)TOK * NPADW * 2);
    u16*   XBC   = (u16*)alloc((size_t)TOK * XBCS * 2);
    float* Bcb   = (float*)alloc((size_t)TOK * DST * 4);
    float* Ccb   = (float*)alloc((size_t)TOK * DST * 4);
    float2* DTDA = (float2*)alloc((size_t)TOK * NHH * 8);
    u16*   YI    = (u16*)alloc((size_t)TOK * DIN * 2);
    u16*   DHb   = (u16*)alloc((size_t)NTAU * 4096 * 2);
    u16*   C2G   = (u16*)alloc((size_t)NTAU * 4096 * 2);
    u16*   HPREV = (u16*)alloc((size_t)NTAU * 4096 * 2);
    float* DC    = (float*)alloc((size_t)NTAU * 4);
    float* RS    = (float*)alloc((size_t)TOK * 4);
    float* BNSC  = (float*)alloc(CIN * 4);
    float* BNSH  = (float*)alloc(CIN * 4);

    // weight prep
    f2bf_pad<<<(NPADW * CIN + 255) / 256, 256, 0, stream>>>(in_proj_w, Win, DPROJ * CIN, NPADW * CIN);
    woutT_conv<<<128, 256, 0, stream>>>(out_proj_w, rms_w, WoutT);
    f2bf_kernel<<<(CIN * CIN + 255) / 256, 256, 0, stream>>>(conv2d_w, Wc2, CIN * CIN);
    bn_prep<<<2, 256, 0, stream>>>(conv2d_b, bn_g, bn_b, bn_mean, bn_var, BNSC, BNSH);
    // W_comb[o][d] = sum_c Wc2[o][c] * WoutT[d][c]   (M=512, N=1024, K=512)
    gemm_bt<0><<<(CIN / 128) * (DIN / 128), 256, 0, stream>>>(Wc2, WoutT, WCMB, CIN, DIN, CIN, DIN,
                                                              DIN / 128, nullptr, nullptr, nullptr);

    ln_kernel<<<256, 256, 0, stream>>>(x, ln_w, ln_b, XN);

    gemm_bt<0><<<(TOK / 128) * (NPADW / 128), 256, 0, stream>>>(XN, Win, ZX, TOK, NPADW, CIN, NPADW,
                                                                NPADW / 128, nullptr, nullptr, nullptr);

    conv1d_fused<<<NB * (LL / CTT), 288, 0, stream>>>(ZX, conv1d_w, conv1d_b, XBC, Bcb, Ccb);
    dt_gemv<<<TOK / DTB, 256, 0, stream>>>(XN, in_proj_w, dt_bias, A_log, DTDA);

    ssd_chunk<<<NTAU, 256, 0, stream>>>(Bcb, Ccb, XBC, DTDA, YI, DHb, C2G, DC);
    ssd_carry<<<256, 256, 0, stream>>>(DHb, DC, HPREV);
    ssd_final<<<NTAU, 256, 0, stream>>>(C2G, HPREV, XBC, ZX, Dp, YI);

    rs_kernel<<<TOK, 256, 0, stream>>>(YI, RS);

    // fused out_proj + conv2d + BN + ReLU:  d_out[o,tok] = relu(BN(rs[tok] * sum_d WCMB[o,d]*y[tok,d]))
    gemm_bt<1><<<(CIN / 128) * (TOK / 128), 256, 0, stream>>>(WCMB, YI, d_out, CIN, TOK, DIN, 0,
                                                              TOK / 128, BNSC, BNSH, RS);
}

// Round 10
// 161.493 us; speedup vs baseline: 4.5227x; 1.0351x over previous
//
#include <hip/hip_runtime.h>
#include <hip/hip_bf16.h>

// Problem constants
#define NB 8
#define LL 1024        // H*W tokens per batch
#define CIN 512
#define DIN 1024       // d_inner
#define DXBC 1152      // d_inner + 2*d_state
#define DPROJ 2192     // actual in_proj rows
#define NPADW 2304     // padded to 18*128 for GEMM tiles
#define NHH 16
#define HDD 64
#define DST 64
#define NCHUNK 16
#define QCH 64         // chunk length
#define XBCS 1024      // XBC stored stride (x-part only)
#define CTT 8          // conv tokens per block
#define DTB 16         // dt tokens per block

typedef unsigned short u16;
typedef unsigned int u32;
typedef __bf16 bf16x8 __attribute__((ext_vector_type(8)));
typedef float f32x4 __attribute__((ext_vector_type(4)));
typedef u16 u16x8 __attribute__((ext_vector_type(8)));

__device__ __forceinline__ float bf2f(u16 u) {
    u32 x = ((u32)u) << 16; float f; __builtin_memcpy(&f, &x, 4); return f;
}
__device__ __forceinline__ u16 f2bf(float f) {
    u32 x; __builtin_memcpy(&x, &f, 4);
    u32 r = x + 0x7fff + ((x >> 16) & 1);
    return (u16)(r >> 16);
}

__device__ __forceinline__ void gload16(const u16* g, u16* l) {
    __builtin_amdgcn_global_load_lds((__attribute__((address_space(1))) void*)(g),
                                     (__attribute__((address_space(3))) void*)(l), 16, 0, 0);
}

// swizzled u16 index into a [64][64] bf16 LDS tile (128B rows, 16B-slot XOR swizzle)
__device__ __forceinline__ int swz(int row, int cb) {
    return row * 64 + ((cb ^ ((row & 7) << 4)) >> 1);
}

// ---------- weight converts ----------
__global__ void f2bf_kernel(const float* __restrict__ s, u16* __restrict__ d, int n) {
    int i = blockIdx.x * 256 + threadIdx.x;
    if (i < n) d[i] = f2bf(s[i]);
}
__global__ void f2bf_pad(const float* __restrict__ s, u16* __restrict__ d, int nsrc, int ndst) {
    int i = blockIdx.x * 256 + threadIdx.x;
    if (i < ndst) d[i] = (i < nsrc) ? f2bf(s[i]) : (u16)0;
}
// WoutT[d][c] = out_proj_w[c][d] * rms_w[d]   (LDS-tiled transpose, 64x64 tiles)
__global__ __launch_bounds__(256) void woutT_conv(const float* __restrict__ s,
                                                  const float* __restrict__ rw,
                                                  u16* __restrict__ dt) {
    __shared__ float tile[64][65];
    int bc = blockIdx.x & 7, bd = blockIdx.x >> 3;   // c-tile (512/64=8), d-tile (1024/64=16)
    int c0 = bc * 64, d0 = bd * 64;
    int t = threadIdx.x;
    int r4 = t >> 6, cc = t & 63;
#pragma unroll
    for (int rr = 0; rr < 16; ++rr) {
        int row = r4 * 16 + rr;
        tile[row][cc] = s[(size_t)(c0 + row) * DIN + d0 + cc];
    }
    __syncthreads();
#pragma unroll
    for (int rr = 0; rr < 16; ++rr) {
        int row = r4 * 16 + rr;   // d within tile
        dt[(size_t)(d0 + row) * CIN + c0 + cc] = f2bf(tile[cc][row] * rw[d0 + row]);
    }
}
__global__ void bn_prep(const float* __restrict__ cb, const float* __restrict__ g,
                        const float* __restrict__ bb, const float* __restrict__ mean,
                        const float* __restrict__ var, float* __restrict__ scale,
                        float* __restrict__ shift) {
    int i = blockIdx.x * 256 + threadIdx.x;
    if (i < CIN) {
        float rs = rsqrtf(var[i] + 1e-5f);
        float sc = g[i] * rs;
        scale[i] = sc;
        shift[i] = (cb[i] - mean[i]) * sc + bb[i];
    }
}

// ---------- LayerNorm over channels + transpose (B,C,HW) -> (tok, C) bf16 ----------
__global__ __launch_bounds__(256) void ln_kernel(const float* __restrict__ x,
                                                 const float* __restrict__ lw,
                                                 const float* __restrict__ lb,
                                                 u16* __restrict__ xn) {
    __shared__ u16 tile[CIN * 33];
    __shared__ float psum[8][32], psq[8][32], muA[32], rsA[32];
    int bid = blockIdx.x;
    int b = bid >> 5, hw0 = (bid & 31) * 32;
    int t = threadIdx.x;
    int hw = t & 31, cg = t >> 5;
    const float* xb = x + (size_t)b * CIN * LL + hw0 + hw;
    float s = 0.f, sq = 0.f;
    for (int r = 0; r < CIN / 8; ++r) {
        int c = r * 8 + cg;
        float v = xb[(size_t)c * LL];
        s += v; sq += v * v;
        tile[c * 33 + hw] = f2bf(v);
    }
    psum[cg][hw] = s; psq[cg][hw] = sq;
    __syncthreads();
    if (t < 32) {
        float ss = 0.f, qq = 0.f;
        for (int g = 0; g < 8; ++g) { ss += psum[g][t]; qq += psq[g][t]; }
        float mu = ss * (1.f / CIN);
        float var = qq * (1.f / CIN) - mu * mu;
        muA[t] = mu; rsA[t] = rsqrtf(var + 1e-5f);
    }
    __syncthreads();
    for (int r = 0; r < 64; ++r) {
        int idx = r * 256 + t;
        int c = idx & (CIN - 1);
        int hh = idx >> 9;
        float v = (bf2f(tile[c * 33 + hh]) - muA[hh]) * rsA[hh] * lw[c] + lb[c];
        xn[((size_t)(b * LL + hw0 + hh)) * CIN + c] = f2bf(v);
    }
}

// ---------- bf16 MFMA GEMM: BK=64, XOR-swizzled LDS, 2-phase dbuf with COUNTED vmcnt ----------
// EPI 0: bf16 store row-major ldc.
// EPI 1: v*rsc[col] -> BN(scale/shift[row]) -> ReLU -> remapped f32 store (d_out layout).
template <int EPI>
__global__ __launch_bounds__(256) void gemm_bt(const u16* __restrict__ A, const u16* __restrict__ Bw,
                                               void* __restrict__ Cout, int M, int N, int K, int ldc,
                                               int nx,
                                               const float* __restrict__ scale,
                                               const float* __restrict__ shift,
                                               const float* __restrict__ rsc) {
    __shared__ u16 As[2][128 * 64], Bs[2][128 * 64];
    int t = threadIdx.x;
    int lane = t & 63, wave = t >> 6;
    // bijective XCD swizzle (m204)
    int nblk = gridDim.x;
    int qq = nblk >> 3, rm = nblk & 7;
    int xcd = blockIdx.x & 7, idx = blockIdx.x >> 3;
    int swzb = (xcd < rm ? xcd * (qq + 1) : rm * (qq + 1) + (xcd - rm) * qq) + idx;
    int m0 = (swzb / nx) * 128, n0 = (swzb % nx) * 128;
    int wr = wave >> 1, wc = wave & 1;
    f32x4 acc[4][4];
    for (int m = 0; m < 4; ++m)
        for (int n = 0; n < 4; ++n)
            for (int q = 0; q < 4; ++q) acc[m][n][q] = 0.f;

    const u16* Arow = A + (size_t)m0 * K;
    const u16* Brow = Bw + (size_t)n0 * K;
    int s4 = lane >> 4;
    int rr = lane & 15;

    auto STAGE = [&](int buf, int k0) {
#pragma unroll
        for (int j = 0; j < 4; ++j) {
            int e = j * 256 + t;          // 16B-slot id, 8 slots per row
            int r = e >> 3, sr = e & 7;
            int src = (sr ^ (r & 7)) * 8; // inverse XOR permutation on source
            gload16(Arow + (size_t)r * K + k0 + src, &As[buf][e * 8]);
            gload16(Brow + (size_t)r * K + k0 + src, &Bs[buf][e * 8]);
        }
    };

    STAGE(0, 0);                       // 8 loads/thread in flight
    int NK = K >> 6, cur = 0;
    for (int kt = 0; kt < NK; ++kt) {
        if (kt + 1 < NK) {
            STAGE(cur ^ 1, (kt + 1) << 6);             // +8 loads (next tile)
            asm volatile("s_waitcnt vmcnt(8)" ::: "memory");  // cur tile's 8 done; next 8 fly
        } else {
            asm volatile("s_waitcnt vmcnt(0)" ::: "memory");
        }
        __builtin_amdgcn_s_barrier();   // all waves' cur-tile loads landed
        __builtin_amdgcn_sched_barrier(0);
#pragma unroll
        for (int kk = 0; kk < 2; ++kk) {
            bf16x8 af[4], bfr[4];
#pragma unroll
            for (int m = 0; m < 4; ++m) {
                int row = wr * 64 + m * 16 + rr;
                int ss = (kk * 4 + s4) ^ (row & 7);
                af[m] = *(const bf16x8*)&As[cur][row * 64 + ss * 8];
            }
#pragma unroll
            for (int n = 0; n < 4; ++n) {
                int row = wc * 64 + n * 16 + rr;
                int ss = (kk * 4 + s4) ^ (row & 7);
                bfr[n] = *(const bf16x8*)&Bs[cur][row * 64 + ss * 8];
            }
#pragma unroll
            for (int m = 0; m < 4; ++m)
#pragma unroll
                for (int n = 0; n < 4; ++n)
                    acc[m][n] = __builtin_amdgcn_mfma_f32_16x16x32_bf16(af[m], bfr[n], acc[m][n], 0, 0, 0);
        }
        __builtin_amdgcn_s_barrier();   // protect buf[cur] before next iter's STAGE overwrites it
        cur ^= 1;
    }
    int fq = lane >> 4, fr = lane & 15;
#pragma unroll
    for (int m = 0; m < 4; ++m) {
#pragma unroll
        for (int n = 0; n < 4; ++n) {
            int col = n0 + wc * 64 + n * 16 + fr;
#pragma unroll
            for (int q = 0; q < 4; ++q) {
                int row = m0 + wr * 64 + m * 16 + fq * 4 + q;
                float v = acc[m][n][q];
                if (EPI == 0) {
                    ((u16*)Cout)[(size_t)row * ldc + col] = f2bf(v);
                } else {
                    v = v * rsc[col];
                    v = v * scale[row] + shift[row];
                    v = v > 0.f ? v : 0.f;
                    // row = out-channel o, col = token (b*1024+hw)
                    ((float*)Cout)[((size_t)(col >> 10)) * (CIN * LL) + (size_t)row * LL + (col & 1023)] = v;
                }
            }
        }
    }
}

// ---------- depthwise causal conv1d + SiLU, register sliding window ----------
__global__ __launch_bounds__(288) void conv1d_fused(const u16* __restrict__ zx,
                                                    const float* __restrict__ w,
                                                    const float* __restrict__ bias,
                                                    u16* __restrict__ xbc,
                                                    float* __restrict__ Bc, float* __restrict__ Cc) {
    int bid = blockIdx.x;
    int b = bid >> 7;
    int l0 = (bid & 127) * CTT;
    int t = threadIdx.x;
    bool isX = t < 256;
    int ch = isX ? t * 4 : 1024 + (t - 256) * 4;

    float4 wv0 = *(const float4*)&w[(ch + 0) * 4];
    float4 wv1 = *(const float4*)&w[(ch + 1) * 4];
    float4 wv2 = *(const float4*)&w[(ch + 2) * 4];
    float4 wv3 = *(const float4*)&w[(ch + 3) * 4];
    float4 bv = *(const float4*)&bias[ch];

    ushort4 xin[CTT + 3];
    const u16* src = zx + (size_t)(b * LL + l0 - 3) * NPADW + DIN + ch;
#pragma unroll
    for (int i = 0; i < CTT + 3; ++i) {
        ushort4 v = {0, 0, 0, 0};
        if (l0 + i - 3 >= 0) v = *(const ushort4*)(src + (size_t)i * NPADW);
        xin[i] = v;
    }
#pragma unroll
    for (int i = 0; i < CTT; ++i) {
        int tok = b * LL + l0 + i;
        float a0 = bv.x + bf2f(xin[i].x) * wv0.x + bf2f(xin[i + 1].x) * wv0.y +
                   bf2f(xin[i + 2].x) * wv0.z + bf2f(xin[i + 3].x) * wv0.w;
        float a1 = bv.y + bf2f(xin[i].y) * wv1.x + bf2f(xin[i + 1].y) * wv1.y +
                   bf2f(xin[i + 2].y) * wv1.z + bf2f(xin[i + 3].y) * wv1.w;
        float a2 = bv.z + bf2f(xin[i].z) * wv2.x + bf2f(xin[i + 1].z) * wv2.y +
                   bf2f(xin[i + 2].z) * wv2.z + bf2f(xin[i + 3].z) * wv2.w;
        float a3 = bv.w + bf2f(xin[i].w) * wv3.x + bf2f(xin[i + 1].w) * wv3.y +
                   bf2f(xin[i + 2].w) * wv3.z + bf2f(xin[i + 3].w) * wv3.w;
        float s0 = a0 / (1.f + __expf(-a0));
        float s1 = a1 / (1.f + __expf(-a1));
        float s2 = a2 / (1.f + __expf(-a2));
        float s3 = a3 / (1.f + __expf(-a3));
        if (isX) {
            ushort4 o;
            o.x = f2bf(s0); o.y = f2bf(s1); o.z = f2bf(s2); o.w = f2bf(s3);
            *(ushort4*)&xbc[(size_t)tok * XBCS + ch] = o;
        } else {
            int s = ch - 1024;
            float4 o4; o4.x = s0; o4.y = s1; o4.z = s2; o4.w = s3;
            if (s < DST) *(float4*)&Bc[(size_t)tok * DST + s] = o4;
            else         *(float4*)&Cc[(size_t)tok * DST + (s - DST)] = o4;
        }
    }
}

// ---------- dt GEMV: weights in registers, DTB tokens per block ----------
__global__ __launch_bounds__(256) void dt_gemv(const u16* __restrict__ xn,
                                               const float* __restrict__ wproj,
                                               const float* __restrict__ dt_bias,
                                               const float* __restrict__ A_log,
                                               float2* __restrict__ dtda) {
    int t = threadIdx.x;
    int h = t >> 4, part = t & 15;
    int tok0 = blockIdx.x * DTB;
    const float* wr = wproj + (size_t)(DIN + DXBC + h) * CIN + part * 32;
    float4 w[8];
#pragma unroll
    for (int i = 0; i < 8; ++i) w[i] = *(const float4*)&wr[i * 4];
    const float* wf = (const float*)w;
    float dtb = dt_bias[h];
    float An = -__expf(A_log[h]);
#pragma unroll
    for (int tl = 0; tl < DTB; ++tl) {
        int tok = tok0 + tl;
        const u16* xr = xn + (size_t)tok * CIN + part * 32;
        u16x8 xv0 = *(const u16x8*)&xr[0];
        u16x8 xv1 = *(const u16x8*)&xr[8];
        u16x8 xv2 = *(const u16x8*)&xr[16];
        u16x8 xv3 = *(const u16x8*)&xr[24];
        float s = 0.f;
#pragma unroll
        for (int i = 0; i < 8; ++i) s += bf2f(xv0[i]) * wf[i];
#pragma unroll
        for (int i = 0; i < 8; ++i) s += bf2f(xv1[i]) * wf[8 + i];
#pragma unroll
        for (int i = 0; i < 8; ++i) s += bf2f(xv2[i]) * wf[16 + i];
#pragma unroll
        for (int i = 0; i < 8; ++i) s += bf2f(xv3[i]) * wf[24 + i];
        s += __shfl_xor(s, 1, 64);
        s += __shfl_xor(s, 2, 64);
        s += __shfl_xor(s, 4, 64);
        s += __shfl_xor(s, 8, 64);
        if (part == 0) {
            float si = s + dtb;
            float dtv = si > 15.f ? si : __logf(1.f + __expf(si));
            float2 dd; dd.x = dtv; dd.y = dtv * An;
            dtda[(size_t)tok * NHH + h] = dd;
        }
    }
}

// ---------- SSD K1: G̃, Y_intra(bf16), ΔH(bf16), ESA, d_c  (C2 no longer materialized) ----------
__global__ __launch_bounds__(256) void ssd_chunk(const float* __restrict__ Bcb,
                                                 const float* __restrict__ Ccb,
                                                 const u16* __restrict__ xbc,
                                                 const float2* __restrict__ dtda,
                                                 u16* __restrict__ yi,
                                                 u16* __restrict__ DHb,
                                                 float* __restrict__ ESA,
                                                 float* __restrict__ DC) {
    __shared__ u16 Bt[4096], Ct[4096], XT[4096], BTt[4096], Gt[4096];
    __shared__ float Sar[64], dtvA[64], wA[64];
    int tau = blockIdx.x;
    int b = tau >> 8, h = (tau >> 4) & 15, c = tau & 15;
    int t0g = b * LL + c * QCH;
    int t = threadIdx.x, lane = t & 63, wave = t >> 6;
    int row = t >> 2, q = t & 3;

    {
        const float* bp = Bcb + (size_t)(t0g + row) * DST + q * 16;
        const float* cp = Ccb + (size_t)(t0g + row) * DST + q * 16;
#pragma unroll
        for (int half = 0; half < 2; ++half) {
            float4 v0 = *(const float4*)(bp + half * 8);
            float4 v1 = *(const float4*)(bp + half * 8 + 4);
            u16x8 o;
            o[0] = f2bf(v0.x); o[1] = f2bf(v0.y); o[2] = f2bf(v0.z); o[3] = f2bf(v0.w);
            o[4] = f2bf(v1.x); o[5] = f2bf(v1.y); o[6] = f2bf(v1.z); o[7] = f2bf(v1.w);
            *(u16x8*)&Bt[swz(row, q * 32 + half * 16)] = o;
            float4 c0 = *(const float4*)(cp + half * 8);
            float4 c1 = *(const float4*)(cp + half * 8 + 4);
            u16x8 oc;
            oc[0] = f2bf(c0.x); oc[1] = f2bf(c0.y); oc[2] = f2bf(c0.z); oc[3] = f2bf(c0.w);
            oc[4] = f2bf(c1.x); oc[5] = f2bf(c1.y); oc[6] = f2bf(c1.z); oc[7] = f2bf(c1.w);
            *(u16x8*)&Ct[swz(row, q * 32 + half * 16)] = oc;
        }
        const u16* xp = xbc + (size_t)(t0g + row) * XBCS + h * HDD + q * 16;
        u16x8 x0 = *(const u16x8*)xp;
        u16x8 x1 = *(const u16x8*)(xp + 8);
#pragma unroll
        for (int e = 0; e < 8; ++e) XT[swz(q * 16 + e, row * 2)] = x0[e];
#pragma unroll
        for (int e = 0; e < 8; ++e) XT[swz(q * 16 + 8 + e, row * 2)] = x1[e];
    }
    if (t < 64) {
        float2 dd = dtda[(size_t)(t0g + t) * NHH + h];
        float s = dd.y;
#pragma unroll
        for (int off = 1; off < 64; off <<= 1) {
            float u = __shfl_up(s, off, 64);
            if (t >= off) s += u;
        }
        float SQ = __shfl(s, 63, 64);
        Sar[t] = s; dtvA[t] = dd.x;
        wA[t] = __expf(SQ - s) * dd.x;
        ESA[(size_t)tau * 64 + t] = __expf(s);
        if (t == 0) DC[tau] = __expf(SQ);
    }
    __syncthreads();

    int R = wave >> 1, Cq = wave & 1, rr = lane & 15, sg = lane >> 4;
    f32x4 g[2][2];
#pragma unroll
    for (int mi = 0; mi < 2; ++mi)
#pragma unroll
        for (int ni = 0; ni < 2; ++ni)
#pragma unroll
            for (int r = 0; r < 4; ++r) g[mi][ni][r] = 0.f;
#pragma unroll
    for (int kt = 0; kt < 2; ++kt) {
        int cb = kt * 64 + sg * 16;
        bf16x8 a0 = *(const bf16x8*)&Ct[swz(R * 32 + rr, cb)];
        bf16x8 a1 = *(const bf16x8*)&Ct[swz(R * 32 + 16 + rr, cb)];
        bf16x8 b0 = *(const bf16x8*)&Bt[swz(Cq * 32 + rr, cb)];
        bf16x8 b1 = *(const bf16x8*)&Bt[swz(Cq * 32 + 16 + rr, cb)];
        g[0][0] = __builtin_amdgcn_mfma_f32_16x16x32_bf16(a0, b0, g[0][0], 0, 0, 0);
        g[0][1] = __builtin_amdgcn_mfma_f32_16x16x32_bf16(a0, b1, g[0][1], 0, 0, 0);
        g[1][0] = __builtin_amdgcn_mfma_f32_16x16x32_bf16(a1, b0, g[1][0], 0, 0, 0);
        g[1][1] = __builtin_amdgcn_mfma_f32_16x16x32_bf16(a1, b1, g[1][1], 0, 0, 0);
    }
#pragma unroll
    for (int mi = 0; mi < 2; ++mi)
#pragma unroll
        for (int ni = 0; ni < 2; ++ni)
#pragma unroll
            for (int r = 0; r < 4; ++r) {
                int i = R * 32 + mi * 16 + sg * 4 + r;
                int j = Cq * 32 + ni * 16 + rr;
                float v = (i >= j) ? g[mi][ni][r] * __expf(Sar[i] - Sar[j]) * dtvA[j] : 0.f;
                Gt[swz(i, j * 2)] = f2bf(v);
            }
    // B~T (LDS, transposed, scaled by wA)
#pragma unroll
    for (int half = 0; half < 2; ++half) {
        u16x8 bv = *(const u16x8*)&Bt[swz(row, q * 32 + half * 16)];
#pragma unroll
        for (int e = 0; e < 8; ++e)
            BTt[swz(q * 16 + half * 8 + e, row * 2)] = f2bf(bf2f(bv[e]) * wA[row]);
    }
    __syncthreads();

    f32x4 y[2][2], dh[2][2];
#pragma unroll
    for (int mi = 0; mi < 2; ++mi)
#pragma unroll
        for (int ni = 0; ni < 2; ++ni)
#pragma unroll
            for (int r = 0; r < 4; ++r) { y[mi][ni][r] = 0.f; dh[mi][ni][r] = 0.f; }
#pragma unroll
    for (int kt = 0; kt < 2; ++kt) {
        int cb = kt * 64 + sg * 16;
        bf16x8 xb0 = *(const bf16x8*)&XT[swz(Cq * 32 + rr, cb)];
        bf16x8 xb1 = *(const bf16x8*)&XT[swz(Cq * 32 + 16 + rr, cb)];
        bf16x8 ga0 = *(const bf16x8*)&Gt[swz(R * 32 + rr, cb)];
        bf16x8 ga1 = *(const bf16x8*)&Gt[swz(R * 32 + 16 + rr, cb)];
        bf16x8 ba0 = *(const bf16x8*)&BTt[swz(R * 32 + rr, cb)];
        bf16x8 ba1 = *(const bf16x8*)&BTt[swz(R * 32 + 16 + rr, cb)];
        y[0][0] = __builtin_amdgcn_mfma_f32_16x16x32_bf16(ga0, xb0, y[0][0], 0, 0, 0);
        y[0][1] = __builtin_amdgcn_mfma_f32_16x16x32_bf16(ga0, xb1, y[0][1], 0, 0, 0);
        y[1][0] = __builtin_amdgcn_mfma_f32_16x16x32_bf16(ga1, xb0, y[1][0], 0, 0, 0);
        y[1][1] = __builtin_amdgcn_mfma_f32_16x16x32_bf16(ga1, xb1, y[1][1], 0, 0, 0);
        dh[0][0] = __builtin_amdgcn_mfma_f32_16x16x32_bf16(ba0, xb0, dh[0][0], 0, 0, 0);
        dh[0][1] = __builtin_amdgcn_mfma_f32_16x16x32_bf16(ba0, xb1, dh[0][1], 0, 0, 0);
        dh[1][0] = __builtin_amdgcn_mfma_f32_16x16x32_bf16(ba1, xb0, dh[1][0], 0, 0, 0);
        dh[1][1] = __builtin_amdgcn_mfma_f32_16x16x32_bf16(ba1, xb1, dh[1][1], 0, 0, 0);
    }
#pragma unroll
    for (int mi = 0; mi < 2; ++mi)
#pragma unroll
        for (int ni = 0; ni < 2; ++ni)
#pragma unroll
            for (int r = 0; r < 4; ++r) {
                int i = R * 32 + mi * 16 + sg * 4 + r;
                int p = Cq * 32 + ni * 16 + rr;
                yi[(size_t)(t0g + i) * DIN + h * HDD + p] = f2bf(y[mi][ni][r]);
                DHb[(size_t)tau * 4096 + i * 64 + p] = f2bf(dh[mi][ni][r]);
            }
}

// ---------- SSD K2 ----------
__global__ __launch_bounds__(256) void ssd_carry(const u16* __restrict__ DHb,
                                                 const float* __restrict__ DC,
                                                 u16* __restrict__ HPREV) {
    int bid = blockIdx.x;
    int bh = bid >> 1, ph = bid & 1;
    int t = threadIdx.x;
    int s = t >> 2, p0 = ph * 32 + (t & 3) * 8;
    size_t base = (size_t)bh * NCHUNK * 4096 + s * 64 + p0;
    float Hv[8] = {0.f, 0.f, 0.f, 0.f, 0.f, 0.f, 0.f, 0.f};
    for (int c = 0; c < NCHUNK; ++c) {
        size_t off = base + (size_t)c * 4096;
        u16x8 hp;
#pragma unroll
        for (int e = 0; e < 8; ++e) hp[e] = f2bf(Hv[e]);
        *(u16x8*)&HPREV[off] = hp;
        float d = DC[bh * NCHUNK + c];
        u16x8 dv = *(const u16x8*)&DHb[off];
#pragma unroll
        for (int e = 0; e < 8; ++e) Hv[e] = d * Hv[e] + bf2f(dv[e]);
    }
}

// ---------- SSD K3: Y = Y_intra + (C·eS)·Hprev; fuse D·x, z-gate; emit per-tau y² partials ----------
__global__ __launch_bounds__(256) void ssd_final(const float* __restrict__ Ccb,
                                                 const float* __restrict__ ESA,
                                                 const u16* __restrict__ HPREV,
                                                 const u16* __restrict__ xbc,
                                                 const u16* __restrict__ zx,
                                                 const float* __restrict__ Dp,
                                                 u16* __restrict__ yi,
                                                 float* __restrict__ PS) {
    __shared__ u16 C2t[4096], HT[4096];
    __shared__ float smem_ps[2][64];
    int tau = blockIdx.x;
    int b = tau >> 8, h = (tau >> 4) & 15, c = tau & 15;
    int t0g = b * LL + c * QCH;
    int t = threadIdx.x, lane = t & 63, wave = t >> 6;
    int row = t >> 2, q = t & 3;
    {
        float esa = ESA[(size_t)tau * 64 + row];
        const float* cp = Ccb + (size_t)(t0g + row) * DST + q * 16;
#pragma unroll
        for (int half = 0; half < 2; ++half) {
            float4 c0 = *(const float4*)(cp + half * 8);
            float4 c1 = *(const float4*)(cp + half * 8 + 4);
            u16x8 oc;
            oc[0] = f2bf(c0.x * esa); oc[1] = f2bf(c0.y * esa);
            oc[2] = f2bf(c0.z * esa); oc[3] = f2bf(c0.w * esa);
            oc[4] = f2bf(c1.x * esa); oc[5] = f2bf(c1.y * esa);
            oc[6] = f2bf(c1.z * esa); oc[7] = f2bf(c1.w * esa);
            *(u16x8*)&C2t[swz(row, q * 32 + half * 16)] = oc;
            u16x8 hv = *(const u16x8*)&HPREV[(size_t)tau * 4096 + row * 64 + q * 16 + half * 8];
#pragma unroll
            for (int e = 0; e < 8; ++e) HT[swz(q * 16 + half * 8 + e, row * 2)] = hv[e];
        }
    }
    __syncthreads();
    int R = wave >> 1, Cq = wave & 1, rr = lane & 15, sg = lane >> 4;
    float Dh = Dp[h];
    f32x4 acc[2][2];
#pragma unroll
    for (int mi = 0; mi < 2; ++mi)
#pragma unroll
        for (int ni = 0; ni < 2; ++ni)
#pragma unroll
            for (int r = 0; r < 4; ++r) {
                int i = R * 32 + mi * 16 + sg * 4 + r;
                int p = Cq * 32 + ni * 16 + rr;
                acc[mi][ni][r] = bf2f(yi[(size_t)(t0g + i) * DIN + h * HDD + p]);
            }
#pragma unroll
    for (int kt = 0; kt < 2; ++kt) {
        int cb = kt * 64 + sg * 16;
        bf16x8 a0 = *(const bf16x8*)&C2t[swz(R * 32 + rr, cb)];
        bf16x8 a1 = *(const bf16x8*)&C2t[swz(R * 32 + 16 + rr, cb)];
        bf16x8 b0 = *(const bf16x8*)&HT[swz(Cq * 32 + rr, cb)];
        bf16x8 b1 = *(const bf16x8*)&HT[swz(Cq * 32 + 16 + rr, cb)];
        acc[0][0] = __builtin_amdgcn_mfma_f32_16x16x32_bf16(a0, b0, acc[0][0], 0, 0, 0);
        acc[0][1] = __builtin_amdgcn_mfma_f32_16x16x32_bf16(a0, b1, acc[0][1], 0, 0, 0);
        acc[1][0] = __builtin_amdgcn_mfma_f32_16x16x32_bf16(a1, b0, acc[1][0], 0, 0, 0);
        acc[1][1] = __builtin_amdgcn_mfma_f32_16x16x32_bf16(a1, b1, acc[1][1], 0, 0, 0);
    }
    float ps[2][4];
#pragma unroll
    for (int mi = 0; mi < 2; ++mi)
#pragma unroll
        for (int r = 0; r < 4; ++r) ps[mi][r] = 0.f;
#pragma unroll
    for (int mi = 0; mi < 2; ++mi)
#pragma unroll
        for (int ni = 0; ni < 2; ++ni)
#pragma unroll
            for (int r = 0; r < 4; ++r) {
                int i = R * 32 + mi * 16 + sg * 4 + r;
                int p = Cq * 32 + ni * 16 + rr;
                size_t tok = t0g + i;
                int col = h * HDD + p;
                float xf = bf2f(xbc[tok * XBCS + col]);
                float zf = bf2f(zx[tok * NPADW + col]);
                float yo = (acc[mi][ni][r] + Dh * xf) * (zf / (1.f + __expf(-zf)));
                yi[tok * DIN + col] = f2bf(yo);
                ps[mi][r] += yo * yo;
            }
    // deterministic per-token y^2 reduce: 16-lane group shfl + unique-writer LDS
#pragma unroll
    for (int mi = 0; mi < 2; ++mi)
#pragma unroll
        for (int r = 0; r < 4; ++r) {
            float s2 = ps[mi][r];
            s2 += __shfl_xor(s2, 1, 64);
            s2 += __shfl_xor(s2, 2, 64);
            s2 += __shfl_xor(s2, 4, 64);
            s2 += __shfl_xor(s2, 8, 64);
            if (rr == 0) smem_ps[Cq][R * 32 + mi * 16 + sg * 4 + r] = s2;
        }
    __syncthreads();
    if (t < 64) PS[(size_t)tau * 64 + t] = smem_ps[0][t] + smem_ps[1][t];
}

// ---------- RS from per-tau partials: rs[tok] = rsqrt(sum_h PS / DIN + eps) ----------
__global__ __launch_bounds__(256) void rs_from_ps(const float* __restrict__ PS,
                                                  float* __restrict__ RS) {
    int tok = blockIdx.x * 256 + threadIdx.x;
    int b = tok >> 10, rem = tok & 1023;
    int c = rem >> 6, i = rem & 63;
    float s = 0.f;
#pragma unroll
    for (int h = 0; h < NHH; ++h)
        s += PS[(size_t)(((b << 4) + h) * 16 + c) * 64 + i];
    RS[tok] = rsqrtf(s * (1.f / DIN) + 1e-5f);
}

extern "C" void kernel_launch(void* const* d_in, const int* in_sizes, int n_in,
                              void* d_out, int out_size, void* d_ws, size_t ws_size,
                              hipStream_t stream) {
    const float* x         = (const float*)d_in[0];
    const float* ln_w      = (const float*)d_in[1];
    const float* ln_b      = (const float*)d_in[2];
    const float* in_proj_w = (const float*)d_in[3];
    const float* conv1d_w  = (const float*)d_in[4];
    const float* conv1d_b  = (const float*)d_in[5];
    const float* dt_bias   = (const float*)d_in[6];
    const float* A_log     = (const float*)d_in[7];
    const float* Dp        = (const float*)d_in[8];
    const float* rms_w     = (const float*)d_in[9];
    const float* out_proj_w= (const float*)d_in[10];
    const float* conv2d_w  = (const float*)d_in[11];
    const float* conv2d_b  = (const float*)d_in[12];
    const float* bn_g      = (const float*)d_in[13];
    const float* bn_b      = (const float*)d_in[14];
    const float* bn_mean   = (const float*)d_in[15];
    const float* bn_var    = (const float*)d_in[16];

    const int TOK = NB * LL;  // 8192
    const int NTAU = NB * NHH * NCHUNK;  // 2048
    char* ws = (char*)d_ws;
    size_t off = 0;
    auto alloc = [&](size_t bytes) {
        void* p = ws + off;
        off += (bytes + 255) & ~(size_t)255;
        return p;
    };
    u16*   Win   = (u16*)alloc((size_t)NPADW * CIN * 2);
    u16*   WoutT = (u16*)alloc((size_t)DIN * CIN * 2);
    u16*   Wc2   = (u16*)alloc((size_t)CIN * CIN * 2);
    u16*   WCMB  = (u16*)alloc((size_t)CIN * DIN * 2);
    u16*   XN    = (u16*)alloc((size_t)TOK * CIN * 2);
    u16*   ZX    = (u16*)alloc((size_t)TOK * NPADW * 2);
    u16*   XBC   = (u16*)alloc((size_t)TOK * XBCS * 2);
    float* Bcb   = (float*)alloc((size_t)TOK * DST * 4);
    float* Ccb   = (float*)alloc((size_t)TOK * DST * 4);
    float2* DTDA = (float2*)alloc((size_t)TOK * NHH * 8);
    u16*   YI    = (u16*)alloc((size_t)TOK * DIN * 2);
    u16*   DHb   = (u16*)alloc((size_t)NTAU * 4096 * 2);
    u16*   HPREV = (u16*)alloc((size_t)NTAU * 4096 * 2);
    float* ESA   = (float*)alloc((size_t)NTAU * 64 * 4);
    float* PS    = (float*)alloc((size_t)NTAU * 64 * 4);
    float* DC    = (float*)alloc((size_t)NTAU * 4);
    float* RS    = (float*)alloc((size_t)TOK * 4);
    float* BNSC  = (float*)alloc(CIN * 4);
    float* BNSH  = (float*)alloc(CIN * 4);

    // weight prep
    f2bf_pad<<<(NPADW * CIN + 255) / 256, 256, 0, stream>>>(in_proj_w, Win, DPROJ * CIN, NPADW * CIN);
    woutT_conv<<<128, 256, 0, stream>>>(out_proj_w, rms_w, WoutT);
    f2bf_kernel<<<(CIN * CIN + 255) / 256, 256, 0, stream>>>(conv2d_w, Wc2, CIN * CIN);
    bn_prep<<<2, 256, 0, stream>>>(conv2d_b, bn_g, bn_b, bn_mean, bn_var, BNSC, BNSH);
    // W_comb[o][d] = sum_c Wc2[o][c] * WoutT[d][c]   (M=512, N=1024, K=512)
    gemm_bt<0><<<(CIN / 128) * (DIN / 128), 256, 0, stream>>>(Wc2, WoutT, WCMB, CIN, DIN, CIN, DIN,
                                                              DIN / 128, nullptr, nullptr, nullptr);

    ln_kernel<<<256, 256, 0, stream>>>(x, ln_w, ln_b, XN);

    gemm_bt<0><<<(TOK / 128) * (NPADW / 128), 256, 0, stream>>>(XN, Win, ZX, TOK, NPADW, CIN, NPADW,
                                                                NPADW / 128, nullptr, nullptr, nullptr);

    conv1d_fused<<<NB * (LL / CTT), 288, 0, stream>>>(ZX, conv1d_w, conv1d_b, XBC, Bcb, Ccb);
    dt_gemv<<<TOK / DTB, 256, 0, stream>>>(XN, in_proj_w, dt_bias, A_log, DTDA);

    ssd_chunk<<<NTAU, 256, 0, stream>>>(Bcb, Ccb, XBC, DTDA, YI, DHb, ESA, DC);
    ssd_carry<<<256, 256, 0, stream>>>(DHb, DC, HPREV);
    ssd_final<<<NTAU, 256, 0, stream>>>(Ccb, ESA, HPREV, XBC, ZX, Dp, YI, PS);

    rs_from_ps<<<TOK / 256, 256, 0, stream>>>(PS, RS);

    // fused out_proj + conv2d + BN + ReLU:  d_out[o,tok] = relu(BN(rs[tok] * sum_d WCMB[o,d]*y[tok,d]))
    gemm_bt<1><<<(CIN / 128) * (TOK / 128), 256, 0, stream>>>(WCMB, YI, d_out, CIN, TOK, DIN, 0,
                                                              TOK / 128, BNSC, BNSH, RS);
}

// Round 11
// 152.430 us; speedup vs baseline: 4.7916x; 1.0595x over previous
//
#include <hip/hip_runtime.h>
#include <hip/hip_bf16.h>

// Problem constants
#define NB 8
#define LL 1024        // H*W tokens per batch
#define CIN 512
#define DIN 1024       // d_inner
#define DXBC 1152      // d_inner + 2*d_state
#define DPROJ 2192     // actual in_proj rows
#define NPADW 2304     // padded to 18*128 for GEMM tiles
#define NHH 16
#define HDD 64
#define DST 64
#define NCHUNK 16
#define QCH 64         // chunk length
#define XBCS 1024      // XBC stored stride (x-part only)
#define CTT 8          // conv tokens per block
#define DTB 16         // dt tokens per block

typedef unsigned short u16;
typedef unsigned int u32;
typedef __bf16 bf16x8 __attribute__((ext_vector_type(8)));
typedef float f32x4 __attribute__((ext_vector_type(4)));
typedef u16 u16x8 __attribute__((ext_vector_type(8)));

__device__ __forceinline__ float bf2f(u16 u) {
    u32 x = ((u32)u) << 16; float f; __builtin_memcpy(&f, &x, 4); return f;
}
__device__ __forceinline__ u16 f2bf(float f) {
    u32 x; __builtin_memcpy(&x, &f, 4);
    u32 r = x + 0x7fff + ((x >> 16) & 1);
    return (u16)(r >> 16);
}

__device__ __forceinline__ void gload16(const u16* g, u16* l) {
    __builtin_amdgcn_global_load_lds((__attribute__((address_space(1))) void*)(g),
                                     (__attribute__((address_space(3))) void*)(l), 16, 0, 0);
}

// swizzled u16 index into a [64][64] bf16 LDS tile (128B rows, 16B-slot XOR swizzle)
__device__ __forceinline__ int swz(int row, int cb) {
    return row * 64 + ((cb ^ ((row & 7) << 4)) >> 1);
}

// ---------- weight converts ----------
__global__ void f2bf_kernel(const float* __restrict__ s, u16* __restrict__ d, int n) {
    int i = blockIdx.x * 256 + threadIdx.x;
    if (i < n) d[i] = f2bf(s[i]);
}
__global__ void f2bf_pad(const float* __restrict__ s, u16* __restrict__ d, int nsrc, int ndst) {
    int i = blockIdx.x * 256 + threadIdx.x;
    if (i < ndst) d[i] = (i < nsrc) ? f2bf(s[i]) : (u16)0;
}
// WoutT[d][c] = out_proj_w[c][d] * rms_w[d]   (LDS-tiled transpose, 64x64 tiles)
__global__ __launch_bounds__(256) void woutT_conv(const float* __restrict__ s,
                                                  const float* __restrict__ rw,
                                                  u16* __restrict__ dt) {
    __shared__ float tile[64][65];
    int bc = blockIdx.x & 7, bd = blockIdx.x >> 3;
    int c0 = bc * 64, d0 = bd * 64;
    int t = threadIdx.x;
    int r4 = t >> 6, cc = t & 63;
#pragma unroll
    for (int rr = 0; rr < 16; ++rr) {
        int row = r4 * 16 + rr;
        tile[row][cc] = s[(size_t)(c0 + row) * DIN + d0 + cc];
    }
    __syncthreads();
#pragma unroll
    for (int rr = 0; rr < 16; ++rr) {
        int row = r4 * 16 + rr;
        dt[(size_t)(d0 + row) * CIN + c0 + cc] = f2bf(tile[cc][row] * rw[d0 + row]);
    }
}
__global__ void bn_prep(const float* __restrict__ cb, const float* __restrict__ g,
                        const float* __restrict__ bb, const float* __restrict__ mean,
                        const float* __restrict__ var, float* __restrict__ scale,
                        float* __restrict__ shift) {
    int i = blockIdx.x * 256 + threadIdx.x;
    if (i < CIN) {
        float rs = rsqrtf(var[i] + 1e-5f);
        float sc = g[i] * rs;
        scale[i] = sc;
        shift[i] = (cb[i] - mean[i]) * sc + bb[i];
    }
}

// ---------- LayerNorm over channels + transpose (B,C,HW) -> (tok, C) bf16 ----------
__global__ __launch_bounds__(256) void ln_kernel(const float* __restrict__ x,
                                                 const float* __restrict__ lw,
                                                 const float* __restrict__ lb,
                                                 u16* __restrict__ xn) {
    __shared__ u16 tile[CIN * 33];
    __shared__ float psum[8][32], psq[8][32], muA[32], rsA[32];
    int bid = blockIdx.x;
    int b = bid >> 5, hw0 = (bid & 31) * 32;
    int t = threadIdx.x;
    int hw = t & 31, cg = t >> 5;
    const float* xb = x + (size_t)b * CIN * LL + hw0 + hw;
    float s = 0.f, sq = 0.f;
    for (int r = 0; r < CIN / 8; ++r) {
        int c = r * 8 + cg;
        float v = xb[(size_t)c * LL];
        s += v; sq += v * v;
        tile[c * 33 + hw] = f2bf(v);
    }
    psum[cg][hw] = s; psq[cg][hw] = sq;
    __syncthreads();
    if (t < 32) {
        float ss = 0.f, qq = 0.f;
        for (int g = 0; g < 8; ++g) { ss += psum[g][t]; qq += psq[g][t]; }
        float mu = ss * (1.f / CIN);
        float var = qq * (1.f / CIN) - mu * mu;
        muA[t] = mu; rsA[t] = rsqrtf(var + 1e-5f);
    }
    __syncthreads();
    for (int r = 0; r < 64; ++r) {
        int idx = r * 256 + t;
        int c = idx & (CIN - 1);
        int hh = idx >> 9;
        float v = (bf2f(tile[c * 33 + hh]) - muA[hh]) * rsA[hh] * lw[c] + lb[c];
        xn[((size_t)(b * LL + hw0 + hh)) * CIN + c] = f2bf(v);
    }
}

// ---------- bf16 MFMA GEMM: 128x64 tile, BK=64, XOR-swizzled LDS, 2-phase counted vmcnt ----------
// 48 KB LDS -> 3 blocks/CU (12 waves).  4 waves: wr=wave>>1 (M half), wc=wave&1 (N half).
// EPI 0: bf16 store row-major ldc.
// EPI 1: v*rsc[col] -> BN(scale/shift[row]) -> ReLU -> remapped f32 store (d_out layout).
template <int EPI>
__global__ __launch_bounds__(256) void gemm_bt(const u16* __restrict__ A, const u16* __restrict__ Bw,
                                               void* __restrict__ Cout, int M, int N, int K, int ldc,
                                               int nx,
                                               const float* __restrict__ scale,
                                               const float* __restrict__ shift,
                                               const float* __restrict__ rsc) {
    __shared__ u16 As[2][128 * 64], Bs[2][64 * 64];
    int t = threadIdx.x;
    int lane = t & 63, wave = t >> 6;
    // bijective XCD swizzle (m204)
    int nblk = gridDim.x;
    int qq = nblk >> 3, rm = nblk & 7;
    int xcd = blockIdx.x & 7, idx = blockIdx.x >> 3;
    int swzb = (xcd < rm ? xcd * (qq + 1) : rm * (qq + 1) + (xcd - rm) * qq) + idx;
    int m0 = (swzb / nx) * 128, n0 = (swzb % nx) * 64;
    int wr = wave >> 1, wc = wave & 1;
    f32x4 acc[4][2];
    for (int m = 0; m < 4; ++m)
        for (int n = 0; n < 2; ++n)
            for (int q = 0; q < 4; ++q) acc[m][n][q] = 0.f;

    const u16* Arow = A + (size_t)m0 * K;
    const u16* Brow = Bw + (size_t)n0 * K;
    int s4 = lane >> 4;
    int rr = lane & 15;

    auto STAGE = [&](int buf, int k0) {
#pragma unroll
        for (int j = 0; j < 4; ++j) {
            int e = j * 256 + t;          // A: 1024 16B-slots, 8 per row
            int r = e >> 3, sr = e & 7;
            int src = (sr ^ (r & 7)) * 8;
            gload16(Arow + (size_t)r * K + k0 + src, &As[buf][e * 8]);
        }
#pragma unroll
        for (int j = 0; j < 2; ++j) {
            int e = j * 256 + t;          // B: 512 16B-slots
            int r = e >> 3, sr = e & 7;
            int src = (sr ^ (r & 7)) * 8;
            gload16(Brow + (size_t)r * K + k0 + src, &Bs[buf][e * 8]);
        }
    };

    STAGE(0, 0);                       // 6 loads/thread in flight
    int NK = K >> 6, cur = 0;
    for (int kt = 0; kt < NK; ++kt) {
        if (kt + 1 < NK) {
            STAGE(cur ^ 1, (kt + 1) << 6);             // +6 loads (next tile)
            asm volatile("s_waitcnt vmcnt(6)" ::: "memory");  // cur tile's 6 done; next 6 fly
        } else {
            asm volatile("s_waitcnt vmcnt(0)" ::: "memory");
        }
        __builtin_amdgcn_s_barrier();   // all waves' cur-tile loads landed
        __builtin_amdgcn_sched_barrier(0);
#pragma unroll
        for (int kk = 0; kk < 2; ++kk) {
            bf16x8 af[4], bfr[2];
#pragma unroll
            for (int m = 0; m < 4; ++m) {
                int row = wr * 64 + m * 16 + rr;
                int ss = (kk * 4 + s4) ^ (row & 7);
                af[m] = *(const bf16x8*)&As[cur][row * 64 + ss * 8];
            }
#pragma unroll
            for (int n = 0; n < 2; ++n) {
                int row = wc * 32 + n * 16 + rr;
                int ss = (kk * 4 + s4) ^ (row & 7);
                bfr[n] = *(const bf16x8*)&Bs[cur][row * 64 + ss * 8];
            }
#pragma unroll
            for (int m = 0; m < 4; ++m)
#pragma unroll
                for (int n = 0; n < 2; ++n)
                    acc[m][n] = __builtin_amdgcn_mfma_f32_16x16x32_bf16(af[m], bfr[n], acc[m][n], 0, 0, 0);
        }
        __builtin_amdgcn_s_barrier();   // protect buf[cur] before next iter's STAGE overwrites it
        cur ^= 1;
    }
    int fq = lane >> 4, fr = lane & 15;
#pragma unroll
    for (int m = 0; m < 4; ++m) {
#pragma unroll
        for (int n = 0; n < 2; ++n) {
            int col = n0 + wc * 32 + n * 16 + fr;
#pragma unroll
            for (int q = 0; q < 4; ++q) {
                int row = m0 + wr * 64 + m * 16 + fq * 4 + q;
                float v = acc[m][n][q];
                if (EPI == 0) {
                    ((u16*)Cout)[(size_t)row * ldc + col] = f2bf(v);
                } else {
                    v = v * rsc[col];
                    v = v * scale[row] + shift[row];
                    v = v > 0.f ? v : 0.f;
                    // row = out-channel o, col = token (b*1024+hw)
                    ((float*)Cout)[((size_t)(col >> 10)) * (CIN * LL) + (size_t)row * LL + (col & 1023)] = v;
                }
            }
        }
    }
}

// ---------- depthwise causal conv1d + SiLU, register sliding window; B/C out as bf16 ----------
__global__ __launch_bounds__(288) void conv1d_fused(const u16* __restrict__ zx,
                                                    const float* __restrict__ w,
                                                    const float* __restrict__ bias,
                                                    u16* __restrict__ xbc,
                                                    u16* __restrict__ Bc, u16* __restrict__ Cc) {
    int bid = blockIdx.x;
    int b = bid >> 7;
    int l0 = (bid & 127) * CTT;
    int t = threadIdx.x;
    bool isX = t < 256;
    int ch = isX ? t * 4 : 1024 + (t - 256) * 4;

    float4 wv0 = *(const float4*)&w[(ch + 0) * 4];
    float4 wv1 = *(const float4*)&w[(ch + 1) * 4];
    float4 wv2 = *(const float4*)&w[(ch + 2) * 4];
    float4 wv3 = *(const float4*)&w[(ch + 3) * 4];
    float4 bv = *(const float4*)&bias[ch];

    ushort4 xin[CTT + 3];
    const u16* src = zx + (size_t)(b * LL + l0 - 3) * NPADW + DIN + ch;
#pragma unroll
    for (int i = 0; i < CTT + 3; ++i) {
        ushort4 v = {0, 0, 0, 0};
        if (l0 + i - 3 >= 0) v = *(const ushort4*)(src + (size_t)i * NPADW);
        xin[i] = v;
    }
#pragma unroll
    for (int i = 0; i < CTT; ++i) {
        int tok = b * LL + l0 + i;
        float a0 = bv.x + bf2f(xin[i].x) * wv0.x + bf2f(xin[i + 1].x) * wv0.y +
                   bf2f(xin[i + 2].x) * wv0.z + bf2f(xin[i + 3].x) * wv0.w;
        float a1 = bv.y + bf2f(xin[i].y) * wv1.x + bf2f(xin[i + 1].y) * wv1.y +
                   bf2f(xin[i + 2].y) * wv1.z + bf2f(xin[i + 3].y) * wv1.w;
        float a2 = bv.z + bf2f(xin[i].z) * wv2.x + bf2f(xin[i + 1].z) * wv2.y +
                   bf2f(xin[i + 2].z) * wv2.z + bf2f(xin[i + 3].z) * wv2.w;
        float a3 = bv.w + bf2f(xin[i].w) * wv3.x + bf2f(xin[i + 1].w) * wv3.y +
                   bf2f(xin[i + 2].w) * wv3.z + bf2f(xin[i + 3].w) * wv3.w;
        float s0 = a0 / (1.f + __expf(-a0));
        float s1 = a1 / (1.f + __expf(-a1));
        float s2 = a2 / (1.f + __expf(-a2));
        float s3 = a3 / (1.f + __expf(-a3));
        ushort4 o;
        o.x = f2bf(s0); o.y = f2bf(s1); o.z = f2bf(s2); o.w = f2bf(s3);
        if (isX) {
            *(ushort4*)&xbc[(size_t)tok * XBCS + ch] = o;
        } else {
            int s = ch - 1024;
            if (s < DST) *(ushort4*)&Bc[(size_t)tok * DST + s] = o;
            else         *(ushort4*)&Cc[(size_t)tok * DST + (s - DST)] = o;
        }
    }
}

// ---------- dt GEMV: weights in registers, DTB tokens per block ----------
__global__ __launch_bounds__(256) void dt_gemv(const u16* __restrict__ xn,
                                               const float* __restrict__ wproj,
                                               const float* __restrict__ dt_bias,
                                               const float* __restrict__ A_log,
                                               float2* __restrict__ dtda) {
    int t = threadIdx.x;
    int h = t >> 4, part = t & 15;
    int tok0 = blockIdx.x * DTB;
    const float* wr = wproj + (size_t)(DIN + DXBC + h) * CIN + part * 32;
    float4 w[8];
#pragma unroll
    for (int i = 0; i < 8; ++i) w[i] = *(const float4*)&wr[i * 4];
    const float* wf = (const float*)w;
    float dtb = dt_bias[h];
    float An = -__expf(A_log[h]);
#pragma unroll
    for (int tl = 0; tl < DTB; ++tl) {
        int tok = tok0 + tl;
        const u16* xr = xn + (size_t)tok * CIN + part * 32;
        u16x8 xv0 = *(const u16x8*)&xr[0];
        u16x8 xv1 = *(const u16x8*)&xr[8];
        u16x8 xv2 = *(const u16x8*)&xr[16];
        u16x8 xv3 = *(const u16x8*)&xr[24];
        float s = 0.f;
#pragma unroll
        for (int i = 0; i < 8; ++i) s += bf2f(xv0[i]) * wf[i];
#pragma unroll
        for (int i = 0; i < 8; ++i) s += bf2f(xv1[i]) * wf[8 + i];
#pragma unroll
        for (int i = 0; i < 8; ++i) s += bf2f(xv2[i]) * wf[16 + i];
#pragma unroll
        for (int i = 0; i < 8; ++i) s += bf2f(xv3[i]) * wf[24 + i];
        s += __shfl_xor(s, 1, 64);
        s += __shfl_xor(s, 2, 64);
        s += __shfl_xor(s, 4, 64);
        s += __shfl_xor(s, 8, 64);
        if (part == 0) {
            float si = s + dtb;
            float dtv = si > 15.f ? si : __logf(1.f + __expf(si));
            float2 dd; dd.x = dtv; dd.y = dtv * An;
            dtda[(size_t)tok * NHH + h] = dd;
        }
    }
}

// ---------- SSD K1: G̃, Y_intra(bf16), ΔH(bf16), ESA, d_c ----------
__global__ __launch_bounds__(256) void ssd_chunk(const u16* __restrict__ Bcb,
                                                 const u16* __restrict__ Ccb,
                                                 const u16* __restrict__ xbc,
                                                 const float2* __restrict__ dtda,
                                                 u16* __restrict__ yi,
                                                 u16* __restrict__ DHb,
                                                 float* __restrict__ ESA,
                                                 float* __restrict__ DC) {
    __shared__ u16 Bt[4096], Ct[4096], XT[4096], BTt[4096], Gt[4096];
    __shared__ float Sar[64], dtvA[64], wA[64];
    int tau = blockIdx.x;
    int b = tau >> 8, h = (tau >> 4) & 15, c = tau & 15;
    int t0g = b * LL + c * QCH;
    int t = threadIdx.x, lane = t & 63, wave = t >> 6;
    int row = t >> 2, q = t & 3;

    {
        const u16* bp = Bcb + (size_t)(t0g + row) * DST + q * 16;
        const u16* cp = Ccb + (size_t)(t0g + row) * DST + q * 16;
        u16x8 b0v = *(const u16x8*)bp;
        u16x8 b1v = *(const u16x8*)(bp + 8);
        *(u16x8*)&Bt[swz(row, q * 32)] = b0v;
        *(u16x8*)&Bt[swz(row, q * 32 + 16)] = b1v;
        u16x8 c0v = *(const u16x8*)cp;
        u16x8 c1v = *(const u16x8*)(cp + 8);
        *(u16x8*)&Ct[swz(row, q * 32)] = c0v;
        *(u16x8*)&Ct[swz(row, q * 32 + 16)] = c1v;
        const u16* xp = xbc + (size_t)(t0g + row) * XBCS + h * HDD + q * 16;
        u16x8 x0 = *(const u16x8*)xp;
        u16x8 x1 = *(const u16x8*)(xp + 8);
#pragma unroll
        for (int e = 0; e < 8; ++e) XT[swz(q * 16 + e, row * 2)] = x0[e];
#pragma unroll
        for (int e = 0; e < 8; ++e) XT[swz(q * 16 + 8 + e, row * 2)] = x1[e];
    }
    if (t < 64) {
        float2 dd = dtda[(size_t)(t0g + t) * NHH + h];
        float s = dd.y;
#pragma unroll
        for (int off = 1; off < 64; off <<= 1) {
            float u = __shfl_up(s, off, 64);
            if (t >= off) s += u;
        }
        float SQ = __shfl(s, 63, 64);
        Sar[t] = s; dtvA[t] = dd.x;
        wA[t] = __expf(SQ - s) * dd.x;
        ESA[(size_t)tau * 64 + t] = __expf(s);
        if (t == 0) DC[tau] = __expf(SQ);
    }
    __syncthreads();

    int R = wave >> 1, Cq = wave & 1, rr = lane & 15, sg = lane >> 4;
    f32x4 g[2][2];
#pragma unroll
    for (int mi = 0; mi < 2; ++mi)
#pragma unroll
        for (int ni = 0; ni < 2; ++ni)
#pragma unroll
            for (int r = 0; r < 4; ++r) g[mi][ni][r] = 0.f;
#pragma unroll
    for (int kt = 0; kt < 2; ++kt) {
        int cb = kt * 64 + sg * 16;
        bf16x8 a0 = *(const bf16x8*)&Ct[swz(R * 32 + rr, cb)];
        bf16x8 a1 = *(const bf16x8*)&Ct[swz(R * 32 + 16 + rr, cb)];
        bf16x8 b0 = *(const bf16x8*)&Bt[swz(Cq * 32 + rr, cb)];
        bf16x8 b1 = *(const bf16x8*)&Bt[swz(Cq * 32 + 16 + rr, cb)];
        g[0][0] = __builtin_amdgcn_mfma_f32_16x16x32_bf16(a0, b0, g[0][0], 0, 0, 0);
        g[0][1] = __builtin_amdgcn_mfma_f32_16x16x32_bf16(a0, b1, g[0][1], 0, 0, 0);
        g[1][0] = __builtin_amdgcn_mfma_f32_16x16x32_bf16(a1, b0, g[1][0], 0, 0, 0);
        g[1][1] = __builtin_amdgcn_mfma_f32_16x16x32_bf16(a1, b1, g[1][1], 0, 0, 0);
    }
#pragma unroll
    for (int mi = 0; mi < 2; ++mi)
#pragma unroll
        for (int ni = 0; ni < 2; ++ni)
#pragma unroll
            for (int r = 0; r < 4; ++r) {
                int i = R * 32 + mi * 16 + sg * 4 + r;
                int j = Cq * 32 + ni * 16 + rr;
                float v = (i >= j) ? g[mi][ni][r] * __expf(Sar[i] - Sar[j]) * dtvA[j] : 0.f;
                Gt[swz(i, j * 2)] = f2bf(v);
            }
    // B~T (LDS, transposed, scaled by wA)
#pragma unroll
    for (int half = 0; half < 2; ++half) {
        u16x8 bv = *(const u16x8*)&Bt[swz(row, q * 32 + half * 16)];
#pragma unroll
        for (int e = 0; e < 8; ++e)
            BTt[swz(q * 16 + half * 8 + e, row * 2)] = f2bf(bf2f(bv[e]) * wA[row]);
    }
    __syncthreads();

    f32x4 y[2][2], dh[2][2];
#pragma unroll
    for (int mi = 0; mi < 2; ++mi)
#pragma unroll
        for (int ni = 0; ni < 2; ++ni)
#pragma unroll
            for (int r = 0; r < 4; ++r) { y[mi][ni][r] = 0.f; dh[mi][ni][r] = 0.f; }
#pragma unroll
    for (int kt = 0; kt < 2; ++kt) {
        int cb = kt * 64 + sg * 16;
        bf16x8 xb0 = *(const bf16x8*)&XT[swz(Cq * 32 + rr, cb)];
        bf16x8 xb1 = *(const bf16x8*)&XT[swz(Cq * 32 + 16 + rr, cb)];
        bf16x8 ga0 = *(const bf16x8*)&Gt[swz(R * 32 + rr, cb)];
        bf16x8 ga1 = *(const bf16x8*)&Gt[swz(R * 32 + 16 + rr, cb)];
        bf16x8 ba0 = *(const bf16x8*)&BTt[swz(R * 32 + rr, cb)];
        bf16x8 ba1 = *(const bf16x8*)&BTt[swz(R * 32 + 16 + rr, cb)];
        y[0][0] = __builtin_amdgcn_mfma_f32_16x16x32_bf16(ga0, xb0, y[0][0], 0, 0, 0);
        y[0][1] = __builtin_amdgcn_mfma_f32_16x16x32_bf16(ga0, xb1, y[0][1], 0, 0, 0);
        y[1][0] = __builtin_amdgcn_mfma_f32_16x16x32_bf16(ga1, xb0, y[1][0], 0, 0, 0);
        y[1][1] = __builtin_amdgcn_mfma_f32_16x16x32_bf16(ga1, xb1, y[1][1], 0, 0, 0);
        dh[0][0] = __builtin_amdgcn_mfma_f32_16x16x32_bf16(ba0, xb0, dh[0][0], 0, 0, 0);
        dh[0][1] = __builtin_amdgcn_mfma_f32_16x16x32_bf16(ba0, xb1, dh[0][1], 0, 0, 0);
        dh[1][0] = __builtin_amdgcn_mfma_f32_16x16x32_bf16(ba1, xb0, dh[1][0], 0, 0, 0);
        dh[1][1] = __builtin_amdgcn_mfma_f32_16x16x32_bf16(ba1, xb1, dh[1][1], 0, 0, 0);
    }
#pragma unroll
    for (int mi = 0; mi < 2; ++mi)
#pragma unroll
        for (int ni = 0; ni < 2; ++ni)
#pragma unroll
            for (int r = 0; r < 4; ++r) {
                int i = R * 32 + mi * 16 + sg * 4 + r;
                int p = Cq * 32 + ni * 16 + rr;
                yi[(size_t)(t0g + i) * DIN + h * HDD + p] = f2bf(y[mi][ni][r]);
                DHb[(size_t)tau * 4096 + i * 64 + p] = f2bf(dh[mi][ni][r]);
            }
}

// ---------- SSD K2 ----------
__global__ __launch_bounds__(256) void ssd_carry(const u16* __restrict__ DHb,
                                                 const float* __restrict__ DC,
                                                 u16* __restrict__ HPREV) {
    int bid = blockIdx.x;
    int bh = bid >> 1, ph = bid & 1;
    int t = threadIdx.x;
    int s = t >> 2, p0 = ph * 32 + (t & 3) * 8;
    size_t base = (size_t)bh * NCHUNK * 4096 + s * 64 + p0;
    float Hv[8] = {0.f, 0.f, 0.f, 0.f, 0.f, 0.f, 0.f, 0.f};
    for (int c = 0; c < NCHUNK; ++c) {
        size_t off = base + (size_t)c * 4096;
        u16x8 hp;
#pragma unroll
        for (int e = 0; e < 8; ++e) hp[e] = f2bf(Hv[e]);
        *(u16x8*)&HPREV[off] = hp;
        float d = DC[bh * NCHUNK + c];
        u16x8 dv = *(const u16x8*)&DHb[off];
#pragma unroll
        for (int e = 0; e < 8; ++e) Hv[e] = d * Hv[e] + bf2f(dv[e]);
    }
}

// ---------- SSD K3: Y = Y_intra + (C·eS)·Hprev; fuse D·x, z-gate; emit per-tau y² partials ----------
__global__ __launch_bounds__(256) void ssd_final(const u16* __restrict__ Ccb,
                                                 const float* __restrict__ ESA,
                                                 const u16* __restrict__ HPREV,
                                                 const u16* __restrict__ xbc,
                                                 const u16* __restrict__ zx,
                                                 const float* __restrict__ Dp,
                                                 u16* __restrict__ yi,
                                                 float* __restrict__ PS) {
    __shared__ u16 C2t[4096], HT[4096];
    __shared__ float smem_ps[2][64];
    int tau = blockIdx.x;
    int b = tau >> 8, h = (tau >> 4) & 15, c = tau & 15;
    int t0g = b * LL + c * QCH;
    int t = threadIdx.x, lane = t & 63, wave = t >> 6;
    int row = t >> 2, q = t & 3;
    {
        float esa = ESA[(size_t)tau * 64 + row];
        const u16* cp = Ccb + (size_t)(t0g + row) * DST + q * 16;
#pragma unroll
        for (int half = 0; half < 2; ++half) {
            u16x8 cv = *(const u16x8*)(cp + half * 8);
            u16x8 oc;
#pragma unroll
            for (int e = 0; e < 8; ++e) oc[e] = f2bf(bf2f(cv[e]) * esa);
            *(u16x8*)&C2t[swz(row, q * 32 + half * 16)] = oc;
            u16x8 hv = *(const u16x8*)&HPREV[(size_t)tau * 4096 + row * 64 + q * 16 + half * 8];
#pragma unroll
            for (int e = 0; e < 8; ++e) HT[swz(q * 16 + half * 8 + e, row * 2)] = hv[e];
        }
    }
    __syncthreads();
    int R = wave >> 1, Cq = wave & 1, rr = lane & 15, sg = lane >> 4;
    float Dh = Dp[h];
    f32x4 acc[2][2];
#pragma unroll
    for (int mi = 0; mi < 2; ++mi)
#pragma unroll
        for (int ni = 0; ni < 2; ++ni)
#pragma unroll
            for (int r = 0; r < 4; ++r) {
                int i = R * 32 + mi * 16 + sg * 4 + r;
                int p = Cq * 32 + ni * 16 + rr;
                acc[mi][ni][r] = bf2f(yi[(size_t)(t0g + i) * DIN + h * HDD + p]);
            }
#pragma unroll
    for (int kt = 0; kt < 2; ++kt) {
        int cb = kt * 64 + sg * 16;
        bf16x8 a0 = *(const bf16x8*)&C2t[swz(R * 32 + rr, cb)];
        bf16x8 a1 = *(const bf16x8*)&C2t[swz(R * 32 + 16 + rr, cb)];
        bf16x8 b0 = *(const bf16x8*)&HT[swz(Cq * 32 + rr, cb)];
        bf16x8 b1 = *(const bf16x8*)&HT[swz(Cq * 32 + 16 + rr, cb)];
        acc[0][0] = __builtin_amdgcn_mfma_f32_16x16x32_bf16(a0, b0, acc[0][0], 0, 0, 0);
        acc[0][1] = __builtin_amdgcn_mfma_f32_16x16x32_bf16(a0, b1, acc[0][1], 0, 0, 0);
        acc[1][0] = __builtin_amdgcn_mfma_f32_16x16x32_bf16(a1, b0, acc[1][0], 0, 0, 0);
        acc[1][1] = __builtin_amdgcn_mfma_f32_16x16x32_bf16(a1, b1, acc[1][1], 0, 0, 0);
    }
    float ps[2][4];
#pragma unroll
    for (int mi = 0; mi < 2; ++mi)
#pragma unroll
        for (int r = 0; r < 4; ++r) ps[mi][r] = 0.f;
#pragma unroll
    for (int mi = 0; mi < 2; ++mi)
#pragma unroll
        for (int ni = 0; ni < 2; ++ni)
#pragma unroll
            for (int r = 0; r < 4; ++r) {
                int i = R * 32 + mi * 16 + sg * 4 + r;
                int p = Cq * 32 + ni * 16 + rr;
                size_t tok = t0g + i;
                int col = h * HDD + p;
                float xf = bf2f(xbc[tok * XBCS + col]);
                float zf = bf2f(zx[tok * NPADW + col]);
                float yo = (acc[mi][ni][r] + Dh * xf) * (zf / (1.f + __expf(-zf)));
                yi[tok * DIN + col] = f2bf(yo);
                ps[mi][r] += yo * yo;
            }
#pragma unroll
    for (int mi = 0; mi < 2; ++mi)
#pragma unroll
        for (int r = 0; r < 4; ++r) {
            float s2 = ps[mi][r];
            s2 += __shfl_xor(s2, 1, 64);
            s2 += __shfl_xor(s2, 2, 64);
            s2 += __shfl_xor(s2, 4, 64);
            s2 += __shfl_xor(s2, 8, 64);
            if (rr == 0) smem_ps[Cq][R * 32 + mi * 16 + sg * 4 + r] = s2;
        }
    __syncthreads();
    if (t < 64) PS[(size_t)tau * 64 + t] = smem_ps[0][t] + smem_ps[1][t];
}

// ---------- RS from per-tau partials ----------
__global__ __launch_bounds__(256) void rs_from_ps(const float* __restrict__ PS,
                                                  float* __restrict__ RS) {
    int tok = blockIdx.x * 256 + threadIdx.x;
    int b = tok >> 10, rem = tok & 1023;
    int c = rem >> 6, i = rem & 63;
    float s = 0.f;
#pragma unroll
    for (int h = 0; h < NHH; ++h)
        s += PS[(size_t)(((b << 4) + h) * 16 + c) * 64 + i];
    RS[tok] = rsqrtf(s * (1.f / DIN) + 1e-5f);
}

extern "C" void kernel_launch(void* const* d_in, const int* in_sizes, int n_in,
                              void* d_out, int out_size, void* d_ws, size_t ws_size,
                              hipStream_t stream) {
    const float* x         = (const float*)d_in[0];
    const float* ln_w      = (const float*)d_in[1];
    const float* ln_b      = (const float*)d_in[2];
    const float* in_proj_w = (const float*)d_in[3];
    const float* conv1d_w  = (const float*)d_in[4];
    const float* conv1d_b  = (const float*)d_in[5];
    const float* dt_bias   = (const float*)d_in[6];
    const float* A_log     = (const float*)d_in[7];
    const float* Dp        = (const float*)d_in[8];
    const float* rms_w     = (const float*)d_in[9];
    const float* out_proj_w= (const float*)d_in[10];
    const float* conv2d_w  = (const float*)d_in[11];
    const float* conv2d_b  = (const float*)d_in[12];
    const float* bn_g      = (const float*)d_in[13];
    const float* bn_b      = (const float*)d_in[14];
    const float* bn_mean   = (const float*)d_in[15];
    const float* bn_var    = (const float*)d_in[16];

    const int TOK = NB * LL;  // 8192
    const int NTAU = NB * NHH * NCHUNK;  // 2048
    char* ws = (char*)d_ws;
    size_t off = 0;
    auto alloc = [&](size_t bytes) {
        void* p = ws + off;
        off += (bytes + 255) & ~(size_t)255;
        return p;
    };
    u16*   Win   = (u16*)alloc((size_t)NPADW * CIN * 2);
    u16*   WoutT = (u16*)alloc((size_t)DIN * CIN * 2);
    u16*   Wc2   = (u16*)alloc((size_t)CIN * CIN * 2);
    u16*   WCMB  = (u16*)alloc((size_t)CIN * DIN * 2);
    u16*   XN    = (u16*)alloc((size_t)TOK * CIN * 2);
    u16*   ZX    = (u16*)alloc((size_t)TOK * NPADW * 2);
    u16*   XBC   = (u16*)alloc((size_t)TOK * XBCS * 2);
    u16*   Bcb   = (u16*)alloc((size_t)TOK * DST * 2);
    u16*   Ccb   = (u16*)alloc((size_t)TOK * DST * 2);
    float2* DTDA = (float2*)alloc((size_t)TOK * NHH * 8);
    u16*   YI    = (u16*)alloc((size_t)TOK * DIN * 2);
    u16*   DHb   = (u16*)alloc((size_t)NTAU * 4096 * 2);
    u16*   HPREV = (u16*)alloc((size_t)NTAU * 4096 * 2);
    float* ESA   = (float*)alloc((size_t)NTAU * 64 * 4);
    float* PS    = (float*)alloc((size_t)NTAU * 64 * 4);
    float* DC    = (float*)alloc((size_t)NTAU * 4);
    float* RS    = (float*)alloc((size_t)TOK * 4);
    float* BNSC  = (float*)alloc(CIN * 4);
    float* BNSH  = (float*)alloc(CIN * 4);

    // weight prep
    f2bf_pad<<<(NPADW * CIN + 255) / 256, 256, 0, stream>>>(in_proj_w, Win, DPROJ * CIN, NPADW * CIN);
    woutT_conv<<<128, 256, 0, stream>>>(out_proj_w, rms_w, WoutT);
    f2bf_kernel<<<(CIN * CIN + 255) / 256, 256, 0, stream>>>(conv2d_w, Wc2, CIN * CIN);
    bn_prep<<<2, 256, 0, stream>>>(conv2d_b, bn_g, bn_b, bn_mean, bn_var, BNSC, BNSH);
    // W_comb[o][d] = sum_c Wc2[o][c] * WoutT[d][c]   (M=512, N=1024, K=512)
    gemm_bt<0><<<(CIN / 128) * (DIN / 64), 256, 0, stream>>>(Wc2, WoutT, WCMB, CIN, DIN, CIN, DIN,
                                                             DIN / 64, nullptr, nullptr, nullptr);

    ln_kernel<<<256, 256, 0, stream>>>(x, ln_w, ln_b, XN);

    gemm_bt<0><<<(TOK / 128) * (NPADW / 64), 256, 0, stream>>>(XN, Win, ZX, TOK, NPADW, CIN, NPADW,
                                                               NPADW / 64, nullptr, nullptr, nullptr);

    conv1d_fused<<<NB * (LL / CTT), 288, 0, stream>>>(ZX, conv1d_w, conv1d_b, XBC, Bcb, Ccb);
    dt_gemv<<<TOK / DTB, 256, 0, stream>>>(XN, in_proj_w, dt_bias, A_log, DTDA);

    ssd_chunk<<<NTAU, 256, 0, stream>>>(Bcb, Ccb, XBC, DTDA, YI, DHb, ESA, DC);
    ssd_carry<<<256, 256, 0, stream>>>(DHb, DC, HPREV);
    ssd_final<<<NTAU, 256, 0, stream>>>(Ccb, ESA, HPREV, XBC, ZX, Dp, YI, PS);

    rs_from_ps<<<TOK / 256, 256, 0, stream>>>(PS, RS);

    // fused out_proj + conv2d + BN + ReLU
    gemm_bt<1><<<(CIN / 128) * (TOK / 64), 256, 0, stream>>>(WCMB, YI, d_out, CIN, TOK, DIN, 0,
                                                             TOK / 64, BNSC, BNSH, RS);
}